// Round 6
// baseline (891.515 us; speedup 1.0000x reference)
//
#include <hip/hip_runtime.h>
#include <stdint.h>

#define NND 40000
#define NE  640000
#define NG  128
#define DIM 128
#define HID 64
#define ADJ_BLOCKS 640
#define NOISY_BLOCKS 5000   // NND*32/256
#define NSCB ((NND + 255) / 256)   // 157 scan blocks
#define EMB_SPLIT 8

// ---------------- threefry2x32 (20 rounds), JAX-compatible ----------------
__host__ __device__ inline uint32_t rotl32(uint32_t v, uint32_t r) {
    return (v << r) | (v >> (32u - r));
}

__host__ __device__ inline void threefry2x32(uint32_t k0, uint32_t k1,
                                             uint32_t& x0, uint32_t& x1) {
    uint32_t k2 = k0 ^ k1 ^ 0x1BD11BDAu;
    x0 += k0; x1 += k1;
#define TFR(r) { x0 += x1; x1 = rotl32(x1, r); x1 ^= x0; }
    TFR(13u) TFR(15u) TFR(26u) TFR(6u)
    x0 += k1; x1 += k2 + 1u;
    TFR(17u) TFR(29u) TFR(16u) TFR(24u)
    x0 += k2; x1 += k0 + 2u;
    TFR(13u) TFR(15u) TFR(26u) TFR(6u)
    x0 += k0; x1 += k1 + 3u;
    TFR(17u) TFR(29u) TFR(16u) TFR(24u)
    x0 += k1; x1 += k2 + 4u;
    TFR(13u) TFR(15u) TFR(26u) TFR(6u)
    x0 += k2; x1 += k0 + 5u;
#undef TFR
}

// partitionable-mode random bits -> uniform [0,1)
__device__ inline float rbits_u01(uint32_t k0, uint32_t k1, uint32_t idx) {
    uint32_t x0 = 0u, x1 = idx;
    threefry2x32(k0, k1, x0, x1);
    uint32_t b = x0 ^ x1;
    return __uint_as_float((b >> 9) | 0x3f800000u) - 1.0f;
}

// ---------------- CSR build ----------------
__global__ __launch_bounds__(256) void hist_kernel(const int* __restrict__ dst,
                                                   int* __restrict__ deg) {
    int e = blockIdx.x * 256 + threadIdx.x;
    if (e < NE) atomicAdd(&deg[dst[e]], 1);
}

// hierarchical scan, step 1: per-block sums (coalesced)
__global__ __launch_bounds__(256) void scan_bsum_kernel(const int* __restrict__ deg,
                                                        int* __restrict__ bsum) {
    int t = threadIdx.x;
    int i = blockIdx.x * 256 + t;
    int v = (i < NND) ? deg[i] : 0;
    __shared__ int sh[256];
    sh[t] = v;
    __syncthreads();
#pragma unroll
    for (int s = 128; s > 0; s >>= 1) {
        if (t < s) sh[t] += sh[t + s];
        __syncthreads();
    }
    if (t == 0) bsum[blockIdx.x] = sh[0];
}

// step 2: single small block scans the 157 block sums -> exclusive block offsets
__global__ __launch_bounds__(256) void scan_boff_kernel(const int* __restrict__ bsum,
                                                        int* __restrict__ boff,
                                                        int* __restrict__ offv) {
    int t = threadIdx.x;
    int v = (t < NSCB) ? bsum[t] : 0;
    __shared__ int sh[256];
    sh[t] = v;
    __syncthreads();
    for (int d = 1; d < 256; d <<= 1) {
        int u = (t >= d) ? sh[t - d] : 0;
        __syncthreads();
        sh[t] += u;
        __syncthreads();
    }
    if (t < NSCB) boff[t] = sh[t] - v;   // exclusive
    if (t == NSCB - 1) offv[NND] = sh[t];
}

// step 3: block-local exclusive scan + block offset -> offv/cursor (coalesced)
__global__ __launch_bounds__(256) void scan_final_kernel(const int* __restrict__ deg,
                                                         const int* __restrict__ boff,
                                                         int* __restrict__ offv,
                                                         int* __restrict__ cursor) {
    int t = threadIdx.x;
    int i = blockIdx.x * 256 + t;
    int v = (i < NND) ? deg[i] : 0;
    __shared__ int sh[256];
    sh[t] = v;
    __syncthreads();
    for (int d = 1; d < 256; d <<= 1) {
        int u = (t >= d) ? sh[t - d] : 0;
        __syncthreads();
        sh[t] += u;
        __syncthreads();
    }
    int off = boff[blockIdx.x] + sh[t] - v;   // exclusive prefix
    if (i < NND) { offv[i] = off; cursor[i] = off; }
}

__global__ __launch_bounds__(256) void build_kernel(const int* __restrict__ src,
                                                    const int* __restrict__ dst,
                                                    int* __restrict__ cursor,
                                                    int* __restrict__ elist) {
    int e = blockIdx.x * 256 + threadIdx.x;
    if (e < NE) {
        int p = atomicAdd(&cursor[dst[e]], 1);
        elist[p] = src[e];
    }
}

// agg[n] = sum over in-edges of feat[src]; full overwrite (no zero-init needed)
__global__ __launch_bounds__(256) void gather_kernel(const float* __restrict__ feat,
                                                     const int* __restrict__ offv,
                                                     const int* __restrict__ elist,
                                                     float* __restrict__ agg) {
    int gt = blockIdx.x * 256 + threadIdx.x;
    int n = gt >> 5, c4 = gt & 31;
    int o0 = offv[n], o1 = offv[n + 1];
    float4 acc = make_float4(0.f, 0.f, 0.f, 0.f);
    for (int i = o0; i < o1; i++) {
        int s = elist[i];
        float4 v = *(const float4*)(feat + (size_t)s * DIM + c4 * 4);
        acc.x += v.x; acc.y += v.y; acc.z += v.z; acc.w += v.w;
    }
    *(float4*)(agg + (size_t)n * DIM + c4 * 4) = acc;
}

// ---------------- fused GEMM: out = ACT((A [+ A2]) @ W [+ bias]); optional col stats
// K-chunked LDS (BK=32), swizzled sW layout (8-float col groups strided by 10 -> no
// bank conflicts), ~29.7KB LDS -> 4-5 blocks/CU.
// ACT: 0=none, 1=relu, 2=tanh.  STATS: per-block col sum/sumsq partials to sscr.
template <int K, int M, int ACT, int STATS>
__global__ __launch_bounds__(256, 4) void gemm_kernel(const float* __restrict__ A,
                                                      const float* A2,
                                                      const float* __restrict__ W,
                                                      const float* __restrict__ bias,
                                                      float* out,
                                                      float* __restrict__ sscr,
                                                      int nrows) {
    constexpr int CG  = M / 8;          // column groups (8 cols each)
    constexpr int RG  = 256 / CG;       // row groups
    constexpr int RPB = RG * 4;         // rows per block
    constexpr int BK  = 32;             // K chunk
    constexpr int NC  = K / BK;         // chunks
    constexpr int WS  = M + (M / 8) * 2;  // sW row stride: col group cg at cg*10
    constexpr int AS  = BK + 4;         // sA row stride
    __shared__ __align__(16) float sW[BK * WS];
    __shared__ __align__(16) float sA[RPB * AS];

    const int t = threadIdx.x;
    const int row0 = blockIdx.x * RPB;
    const int cg = t % CG, rg = t / CG;

    float acc[4][8];
#pragma unroll
    for (int i = 0; i < 4; i++)
#pragma unroll
        for (int j = 0; j < 8; j++) acc[i][j] = 0.f;

    for (int kc = 0; kc < NC; kc++) {
        // stage W chunk (swizzled columns)
        constexpr int W4 = M / 4;
        for (int i = t; i < BK * W4; i += 256) {
            int k = i / W4, c4 = i % W4;
            float4 v = ((const float4*)(W + (size_t)(kc * BK + k) * M))[c4];
            *(float4*)(sW + k * WS + (c4 >> 1) * 10 + (c4 & 1) * 4) = v;
        }
        // stage A chunk
        constexpr int A4 = BK / 4;
        for (int i = t; i < RPB * A4; i += 256) {
            int r = i / A4, k4 = i % A4;
            int gr = row0 + r;
            float4 v = make_float4(0.f, 0.f, 0.f, 0.f);
            if (gr < nrows) {
                v = ((const float4*)(A + (size_t)gr * K + kc * BK))[k4];
                if (A2) {
                    float4 w2 = ((const float4*)(A2 + (size_t)gr * K + kc * BK))[k4];
                    v.x += w2.x; v.y += w2.y; v.z += w2.z; v.w += w2.w;
                }
            }
            *(float4*)(sA + r * AS + k4 * 4) = v;
        }
        __syncthreads();

        const float* sWr = sW + cg * 10;
        const float* sAr = sA + (rg * 4) * AS;
#pragma unroll 4
        for (int k = 0; k < BK; k++) {
            float4 wA = *(const float4*)(sWr + k * WS);
            float4 wB = *(const float4*)(sWr + k * WS + 4);
            float wv[8] = {wA.x, wA.y, wA.z, wA.w, wB.x, wB.y, wB.z, wB.w};
            float sv[4] = {sAr[k], sAr[AS + k], sAr[2 * AS + k], sAr[3 * AS + k]};
#pragma unroll
            for (int i = 0; i < 4; i++)
#pragma unroll
                for (int j = 0; j < 8; j++) acc[i][j] = fmaf(sv[i], wv[j], acc[i][j]);
        }
        __syncthreads();
    }

    float bv[8];
#pragma unroll
    for (int j = 0; j < 8; j++) bv[j] = bias ? bias[cg * 8 + j] : 0.f;

    float ps[8], pq[8];
#pragma unroll
    for (int j = 0; j < 8; j++) { ps[j] = 0.f; pq[j] = 0.f; }

#pragma unroll
    for (int i = 0; i < 4; i++) {
        int gr = row0 + rg * 4 + i;
        if (gr < nrows) {
            float o[8];
#pragma unroll
            for (int j = 0; j < 8; j++) {
                float v = acc[i][j] + bv[j];
                if (ACT == 1) v = fmaxf(v, 0.f);
                if (ACT == 2) v = tanhf(v);
                o[j] = v;
                ps[j] += v; pq[j] += v * v;
            }
            float4* o4 = (float4*)(out + (size_t)gr * M + cg * 8);
            o4[0] = make_float4(o[0], o[1], o[2], o[3]);
            o4[1] = make_float4(o[4], o[5], o[6], o[7]);
        }
    }

    if (STATS) {
        // reuse sA (sum) and sW (sumsq) as reduction scratch; both >= RG*M floats
        __syncthreads();
#pragma unroll
        for (int j = 0; j < 8; j++) {
            sA[rg * M + cg * 8 + j] = ps[j];
            sW[rg * M + cg * 8 + j] = pq[j];
        }
        __syncthreads();
        if (t < M) {
            float s = 0.f, q = 0.f;
#pragma unroll
            for (int i = 0; i < RG; i++) { s += sA[i * M + t]; q += sW[i * M + t]; }
            sscr[(size_t)blockIdx.x * 2 * M + t]     = s;
            sscr[(size_t)blockIdx.x * 2 * M + M + t] = q;
        }
    }
}

// parallel reduce: sscr[nblk][2M] -> cs[2M]; grid = 2M/8 blocks x 256 threads.
template <int M>
__global__ __launch_bounds__(256) void stats_reduce_kernel(const float* __restrict__ sscr,
                                                           int nblk,
                                                           float* __restrict__ cs) {
    const int cols = 2 * M;
    const int t = threadIdx.x;
    const int c = blockIdx.x * 8 + (t & 7);   // global column
    const int rl = t >> 3;                    // row lane 0..31
    float s = 0.f;
    for (int r = rl; r < nblk; r += 32)
        s += sscr[(size_t)r * cols + c];
    __shared__ float sh[256];
    sh[t] = s;
    __syncthreads();
#pragma unroll
    for (int st = 128; st >= 8; st >>= 1) {
        if (t < st) sh[t] += sh[t + st];
        __syncthreads();
    }
    if (t < 8) cs[c] = sh[t];
}

// ---------------- in-place batchnorm apply (stats finalized inline) ----------------
template <int NC, int RELU>
__global__ __launch_bounds__(256) void bn_apply_kernel(float* buf,
                                                       const float* __restrict__ cs,
                                                       const float* __restrict__ g,
                                                       const float* __restrict__ b) {
    int i = blockIdx.x * 256 + threadIdx.x;
    const int total4 = NND * NC / 4;
    if (i >= total4) return;
    int c = (i * 4) % NC;
    const float invN = 1.0f / (float)NND;
    float4 v = ((float4*)buf)[i];
    float o[4] = {v.x, v.y, v.z, v.w};
#pragma unroll
    for (int j = 0; j < 4; j++) {
        float mu = cs[c + j] * invN;
        float var = fmaxf(cs[NC + c + j] * invN - mu * mu, 0.f);
        float rs = rsqrtf(var + 1e-5f);
        float A = g[c + j] * rs;
        float B = b[c + j] - mu * A;
        float y = fmaf(o[j], A, B);
        if (RELU) y = fmaxf(y, 0.f);
        o[j] = y;
    }
    ((float4*)buf)[i] = make_float4(o[0], o[1], o[2], o[3]);
}

// ---------------- assignment / gumbel-softmax lambdas ----------------
__global__ __launch_bounds__(256) void assign_kernel(const float* __restrict__ a1,
                                                     const float* __restrict__ Wfc2,
                                                     const float* __restrict__ bfc2,
                                                     float* __restrict__ assn,
                                                     float* __restrict__ lam,
                                                     uint32_t kg0, uint32_t kg1) {
    __shared__ float w[DIM * 2];
    int t = threadIdx.x;
    w[t] = Wfc2[t];  // 256 threads, 256 values
    __syncthreads();
    int n = blockIdx.x * 256 + t;
    if (n >= NND) return;

    float d0 = bfc2[0], d1 = bfc2[1];
    const float4* row4 = (const float4*)(a1 + (size_t)n * DIM);
#pragma unroll 8
    for (int k4 = 0; k4 < DIM / 4; k4++) {
        float4 v = row4[k4];
        d0 = fmaf(v.x, w[8 * k4 + 0], d0); d1 = fmaf(v.x, w[8 * k4 + 1], d1);
        d0 = fmaf(v.y, w[8 * k4 + 2], d0); d1 = fmaf(v.y, w[8 * k4 + 3], d1);
        d0 = fmaf(v.z, w[8 * k4 + 4], d0); d1 = fmaf(v.z, w[8 * k4 + 5], d1);
        d0 = fmaf(v.w, w[8 * k4 + 6], d0); d1 = fmaf(v.w, w[8 * k4 + 7], d1);
    }
    float m = fmaxf(d0, d1);
    float e0 = expf(d0 - m), e1 = expf(d1 - m);
    float inv = 1.f / (e0 + e1);
    float as0 = e0 * inv, as1 = e1 * inv;
    assn[2 * n] = as0; assn[2 * n + 1] = as1;

    float uf0 = rbits_u01(kg0, kg1, (uint32_t)(2 * n));
    float uf1 = rbits_u01(kg0, kg1, (uint32_t)(2 * n + 1));
    float u0 = fmaxf(1e-10f, uf0 + 1e-10f);
    float u1 = fmaxf(1e-10f, uf1 + 1e-10f);
    float gu0 = -logf(-logf(u0));
    float gu1 = -logf(-logf(u1));
    float y0 = as0 + gu0, y1 = as1 + gu1;
    float mm = fmaxf(y0, y1);
    float f0 = expf(y0 - mm), f1 = expf(y1 - mm);
    float iv = 1.f / (f0 + f1);
    lam[2 * n] = f0 * iv; lam[2 * n + 1] = f1 * iv;
}

// ---------------- noisy features + kl partial sums (per-block, no atomics) ------
__global__ __launch_bounds__(256) void noisy_kernel(const float* __restrict__ nfeat,
                                                    const float* __restrict__ lam,
                                                    const float* __restrict__ cs3,
                                                    float* __restrict__ noisy,
                                                    float* __restrict__ kpart,
                                                    uint32_t kn0, uint32_t kn1) {
    int gt = blockIdx.x * 256 + threadIdx.x;
    int n = gt >> 5, c4 = gt & 31, d = c4 * 4;
    const float invN = 1.0f / (float)NND;
    float la0 = lam[2 * n], la1 = lam[2 * n + 1];
    float4 xv = *(const float4*)(nfeat + (size_t)n * DIM + d);
    float xa[4] = {xv.x, xv.y, xv.z, xv.w};
    float t1 = 0.f, t2 = 0.f, o[4];
#pragma unroll
    for (int j = 0; j < 4; j++) {
        float mu = cs3[d + j] * invN;
        float q = cs3[DIM + d + j];
        float var1 = fmaxf(q - (float)NND * mu * mu, 0.f) / (float)(NND - 1);
        float sd = sqrtf(var1);
        float r = rbits_u01(kn0, kn1, (uint32_t)(n * DIM + d + j));
        float nm = la0 * xa[j] + la1 * mu;
        float ns = la1 * sd;
        o[j] = fmaf(r, ns, nm);
        float inv = 1.0f / (sd + 1e-7f);
        float z1 = ns * inv;            t1 += z1 * z1;
        float z2 = (nm - mu) * inv;     t2 += z2 * z2;
    }
    *(float4*)(noisy + (size_t)n * DIM + d) = make_float4(o[0], o[1], o[2], o[3]);

    __shared__ float s1[256], s2[256];
    int t = threadIdx.x;
    s1[t] = t1; s2[t] = t2;
    __syncthreads();
    for (int s = 128; s > 0; s >>= 1) {
        if (t < s) { s1[t] += s1[t + s]; s2[t] += s2[t + s]; }
        __syncthreads();
    }
    if (t == 0) { kpart[2 * blockIdx.x] = s1[0]; kpart[2 * blockIdx.x + 1] = s2[0]; }
}

// ---------------- graph segment starts (batch is sorted) ----------------
__global__ __launch_bounds__(256) void gstart_kernel(const int* __restrict__ batch,
                                                     int* __restrict__ gstart) {
    int i = blockIdx.x * 256 + threadIdx.x;
    if (i >= NND) return;
    int b = batch[i];
    int prev = (i == 0) ? -1 : batch[i - 1];
    for (int g = prev + 1; g <= b; g++) gstart[g] = i;
    if (i == NND - 1)
        for (int g = b + 1; g <= NG; g++) gstart[g] = NND;
}

// ---------------- graph mean pooling: split each graph across EMB_SPLIT blocks ----
__global__ __launch_bounds__(128) void graph_emb_part_kernel(const float* __restrict__ noisy,
                                                             const int* __restrict__ gstart,
                                                             float* __restrict__ gpart) {
    int g = blockIdx.x / EMB_SPLIT;
    int sidx = blockIdx.x % EMB_SPLIT;
    int c = threadIdx.x;
    int s = gstart[g], e = gstart[g + 1];
    int len = e - s;
    int chunk = (len + EMB_SPLIT - 1) / EMB_SPLIT;
    int r0 = s + sidx * chunk;
    int r1 = min(r0 + chunk, e);
    float acc = 0.f;
    for (int r = r0; r < r1; r++) acc += noisy[(size_t)r * DIM + c];
    gpart[((size_t)g * EMB_SPLIT + sidx) * DIM + c] = acc;
}

__global__ __launch_bounds__(128) void graph_emb_reduce_kernel(const float* __restrict__ gpart,
                                                               const int* __restrict__ gstart,
                                                               float* __restrict__ emb) {
    int g = blockIdx.x, c = threadIdx.x;
    float acc = 0.f;
#pragma unroll
    for (int si = 0; si < EMB_SPLIT; si++)
        acc += gpart[((size_t)g * EMB_SPLIT + si) * DIM + c];
    float cnt = (float)(gstart[g + 1] - gstart[g]);
    emb[(size_t)g * DIM + c] = acc / fmaxf(cnt, 1.f);
}

// ---------------- proto distances + final head (one wave per graph) ----------------
__global__ __launch_bounds__(64) void head_kernel(const float* __restrict__ emb,
                                                  const float* __restrict__ protos,
                                                  const float* __restrict__ Wlast,
                                                  float* __restrict__ out_logits,
                                                  float* __restrict__ out_probs,
                                                  float* __restrict__ out_sim,
                                                  float* __restrict__ out_dist) {
    int g = blockIdx.x, l = threadIdx.x;
    float ge0 = emb[(size_t)g * DIM + l];
    float ge1 = emb[(size_t)g * DIM + l + 64];
    float gn = ge0 * ge0 + ge1 * ge1;
    float dj[10], pj[10];
#pragma unroll
    for (int j = 0; j < 10; j++) {
        float pa = protos[j * DIM + l], pb = protos[j * DIM + l + 64];
        dj[j] = ge0 * pa + ge1 * pb;
        pj[j] = pa * pa + pb * pb;
    }
    float wl0 = ge0 * Wlast[10 + l] + ge1 * Wlast[10 + l + 64];
    float wl1 = ge0 * Wlast[138 + 10 + l] + ge1 * Wlast[138 + 10 + l + 64];
#pragma unroll
    for (int s = 32; s > 0; s >>= 1) {
        gn += __shfl_xor(gn, s);
        wl0 += __shfl_xor(wl0, s);
        wl1 += __shfl_xor(wl1, s);
#pragma unroll
        for (int j = 0; j < 10; j++) {
            dj[j] += __shfl_xor(dj[j], s);
            pj[j] += __shfl_xor(pj[j], s);
        }
    }
    if (l == 0) {
        float lg0 = wl0, lg1 = wl1;
#pragma unroll
        for (int j = 0; j < 10; j++) {
            float dist = -2.f * dj[j] + gn + pj[j];
            float sv = logf((dist + 1.0f) / (dist + 1e-4f));
            out_dist[g * 10 + j] = dist;
            out_sim[g * 10 + j] = sv;
            lg0 = fmaf(Wlast[j], sv, lg0);
            lg1 = fmaf(Wlast[138 + j], sv, lg1);
        }
        out_logits[2 * g] = lg0; out_logits[2 * g + 1] = lg1;
        float m = fmaxf(lg0, lg1);
        float e0 = expf(lg0 - m), e1 = expf(lg1 - m);
        float iv = 1.f / (e0 + e1);
        out_probs[2 * g] = e0 * iv; out_probs[2 * g + 1] = e1 * iv;
    }
}

// ---------------- 2x2 adjacency accumulation (per-block partials) ----------------
__global__ __launch_bounds__(256) void adj_kernel(const float* __restrict__ assn,
                                                  const int* __restrict__ src,
                                                  const int* __restrict__ dst,
                                                  float* __restrict__ adjp) {
    int t = threadIdx.x;
    float p00 = 0.f, p01 = 0.f, p10 = 0.f, p11 = 0.f;
    for (int e = blockIdx.x * 256 + t; e < NE; e += ADJ_BLOCKS * 256) {
        float2 a = *(const float2*)(assn + 2 * (size_t)src[e]);
        float2 b = *(const float2*)(assn + 2 * (size_t)dst[e]);
        p00 += a.x * b.x; p01 += a.x * b.y; p10 += a.y * b.x; p11 += a.y * b.y;
    }
    __shared__ float s0[256], s1[256], s2[256], s3[256];
    s0[t] = p00; s1[t] = p01; s2[t] = p10; s3[t] = p11;
    __syncthreads();
    for (int s = 128; s > 0; s >>= 1) {
        if (t < s) { s0[t] += s0[t + s]; s1[t] += s1[t + s]; s2[t] += s2[t + s]; s3[t] += s3[t + s]; }
        __syncthreads();
    }
    if (t == 0) {
        float4* o = (float4*)(adjp + 4 * (size_t)blockIdx.x);
        *o = make_float4(s0[0], s1[0], s2[0], s3[0]);
    }
}

// ---------------- final scalars: reduce kl + adj partials ----------------
__global__ __launch_bounds__(256) void final_scalar_kernel(const float* __restrict__ kpart,
                                                           const float* __restrict__ adjp,
                                                           float* __restrict__ out) {
    __shared__ float sh[6 * 256];
    int t = threadIdx.x;
    float k1 = 0.f, k2 = 0.f, a0 = 0.f, a1 = 0.f, a2 = 0.f, a3 = 0.f;
    for (int i = t; i < NOISY_BLOCKS; i += 256) {
        float2 v = ((const float2*)kpart)[i];
        k1 += v.x; k2 += v.y;
    }
    for (int i = t; i < ADJ_BLOCKS; i += 256) {
        float4 v = ((const float4*)adjp)[i];
        a0 += v.x; a1 += v.y; a2 += v.z; a3 += v.w;
    }
    sh[t] = k1; sh[256 + t] = k2; sh[512 + t] = a0;
    sh[768 + t] = a1; sh[1024 + t] = a2; sh[1280 + t] = a3;
    __syncthreads();
    for (int s = 128; s > 0; s >>= 1) {
        if (t < s) {
#pragma unroll
            for (int v = 0; v < 6; v++) sh[v * 256 + t] += sh[v * 256 + t + s];
        }
        __syncthreads();
    }
    if (t == 0) {
        float kl = 0.5f / ((float)NND * (float)DIM) * sh[0] + (1.0f / (float)DIM) * sh[256];
        out[16896] = kl;
        float a00 = sh[512], a01 = sh[768], a10 = sh[1024], a11 = sh[1280];
        float r0 = fmaxf(fabsf(a00) + fabsf(a01), 1e-12f);
        float r1 = fmaxf(fabsf(a10) + fabsf(a11), 1e-12f);
        float d0 = a00 / r0 - 1.f, d1 = a11 / r1 - 1.f;
        out[16897] = 0.5f * (d0 * d0 + d1 * d1);
    }
}

// ---------------- launcher ----------------
extern "C" void kernel_launch(void* const* d_in, const int* in_sizes, int n_in,
                              void* d_out, int out_size, void* d_ws, size_t ws_size,
                              hipStream_t stream) {
    (void)in_sizes; (void)n_in; (void)out_size; (void)ws_size;
    const float* x     = (const float*)d_in[0];
    const int*   ei    = (const int*)d_in[1];
    const int*   batch = (const int*)d_in[2];
    const float* W0a   = (const float*)d_in[3];
    const float* W0b   = (const float*)d_in[4];
    const float* g0    = (const float*)d_in[5];
    const float* b0    = (const float*)d_in[6];
    const float* W1a   = (const float*)d_in[7];
    const float* W1b   = (const float*)d_in[8];
    const float* g1    = (const float*)d_in[9];
    const float* b1    = (const float*)d_in[10];
    const float* Wm0   = (const float*)d_in[11];
    const float* bm0   = (const float*)d_in[12];
    const float* gm    = (const float*)d_in[13];
    const float* bm    = (const float*)d_in[14];
    const float* Wm1   = (const float*)d_in[15];
    const float* bm1   = (const float*)d_in[16];
    const float* Wfc1  = (const float*)d_in[17];
    const float* bfc1  = (const float*)d_in[18];
    const float* Wfc2  = (const float*)d_in[19];
    const float* bfc2  = (const float*)d_in[20];
    const float* protos= (const float*)d_in[21];
    const float* Wlast = (const float*)d_in[22];
    const int* src = ei;
    const int* dst = ei + NE;
    float* out = (float*)d_out;

    float* ws   = (float*)d_ws;
    float* agg  = ws;                               // N*128
    float* tA   = agg + (size_t)NND * DIM;          // N*128
    float* t5   = tA + (size_t)NND * DIM;           // N*64
    float* lam  = t5 + (size_t)NND * HID;           // N*2
    float* assn = lam + (size_t)NND * 2;            // N*2
    float* cs   = assn + (size_t)NND * 2;           // 1024 (4 stat segments)
    float* kpart= cs + 1024;                        // NOISY_BLOCKS*2
    float* adjp = kpart + NOISY_BLOCKS * 2;         // ADJ_BLOCKS*4
    float* sscr = adjp + ADJ_BLOCKS * 4;            // 625*256 stats partials
    float* gpart= sscr + 625 * 256;                 // NG*EMB_SPLIT*DIM
    int* ib     = (int*)(gpart + NG * EMB_SPLIT * DIM);  // int region
    int* deg    = ib;                               // N
    int* offv   = deg + NND;                        // N+1
    int* cursor = offv + NND + 1;                   // N
    int* elist  = cursor + NND;                     // E
    int* gstart = elist + NE;                       // NG+1
    int* bsum   = gstart + NG + 1;                  // NSCB
    int* boff   = bsum + NSCB;                      // NSCB

    // threefry keys on host: key(42) = (0,42); partitionable fold-like split
    uint32_t kg0 = 0u, kg1 = 0u; threefry2x32(0u, 42u, kg0, kg1);  // ctr (0,0)
    uint32_t kn0 = 0u, kn1 = 1u; threefry2x32(0u, 42u, kn0, kn1);  // ctr (0,1)

    hipMemsetAsync(deg, 0, NND * sizeof(int), stream);

    // CSR (shared by both GIN layers)
    hist_kernel<<<(NE + 255) / 256, 256, 0, stream>>>(dst, deg);
    scan_bsum_kernel<<<NSCB, 256, 0, stream>>>(deg, bsum);
    scan_boff_kernel<<<1, 256, 0, stream>>>(bsum, boff, offv);
    scan_final_kernel<<<NSCB, 256, 0, stream>>>(deg, boff, offv, cursor);
    build_kernel<<<(NE + 255) / 256, 256, 0, stream>>>(src, dst, cursor, elist);

    // GIN layer 1
    gather_kernel<<<(NND * 32) / 256, 256, 0, stream>>>(x, offv, elist, agg);
    gemm_kernel<128,128,1,0><<<625, 256, 0, stream>>>(x, agg, W0a, nullptr, agg, nullptr, NND);
    gemm_kernel<128,128,1,1><<<625, 256, 0, stream>>>(agg, nullptr, W0b, nullptr, tA, sscr, NND);
    stats_reduce_kernel<128><<<32, 256, 0, stream>>>(sscr, 625, cs + 0);
    bn_apply_kernel<128,1><<<5000, 256, 0, stream>>>(tA, cs + 0, g0, b0);      // nf1

    // GIN layer 2
    gather_kernel<<<(NND * 32) / 256, 256, 0, stream>>>(tA, offv, elist, agg);
    gemm_kernel<128,128,1,0><<<625, 256, 0, stream>>>(tA, agg, W1a, nullptr, agg, nullptr, NND);
    gemm_kernel<128,128,1,1><<<625, 256, 0, stream>>>(agg, nullptr, W1b, nullptr, tA, sscr, NND);
    stats_reduce_kernel<128><<<32, 256, 0, stream>>>(sscr, 625, cs + 256);
    bn_apply_kernel<128,0><<<5000, 256, 0, stream>>>(tA, cs + 256, g1, b1);    // nf2

    // bottleneck MLP
    gemm_kernel<128,64,0,1><<<313, 256, 0, stream>>>(tA, nullptr, Wm0, bm0, t5, sscr, NND);
    stats_reduce_kernel<64><<<16, 256, 0, stream>>>(sscr, 313, cs + 512);
    bn_apply_kernel<64,1><<<2500, 256, 0, stream>>>(t5, cs + 512, gm, bm);     // h
    gemm_kernel<64,128,0,1><<<625, 256, 0, stream>>>(t5, nullptr, Wm1, bm1, agg, sscr, NND); // node_feature
    stats_reduce_kernel<128><<<32, 256, 0, stream>>>(sscr, 625, cs + 640);
    gemm_kernel<128,128,2,0><<<625, 256, 0, stream>>>(agg, nullptr, Wfc1, bfc1, tA, nullptr, NND); // a1

    // assignment + gumbel
    assign_kernel<<<(NND + 255) / 256, 256, 0, stream>>>(tA, Wfc2, bfc2, assn, lam, kg0, kg1);

    // noisy features (into tA) + kl partials
    noisy_kernel<<<NOISY_BLOCKS, 256, 0, stream>>>(agg, lam, cs + 640, tA, kpart, kn0, kn1);

    // graph pooling + head
    gstart_kernel<<<(NND + 255) / 256, 256, 0, stream>>>(batch, gstart);
    graph_emb_part_kernel<<<NG * EMB_SPLIT, 128, 0, stream>>>(tA, gstart, gpart);
    graph_emb_reduce_kernel<<<NG, 128, 0, stream>>>(gpart, gstart, out + 512);
    head_kernel<<<NG, 64, 0, stream>>>(out + 512, protos, Wlast,
                                       out, out + 256, out + 16898, out + 18178);

    // penalties
    adj_kernel<<<ADJ_BLOCKS, 256, 0, stream>>>(assn, src, dst, adjp);
    final_scalar_kernel<<<1, 256, 0, stream>>>(kpart, adjp, out);
}

// Round 7
// 573.130 us; speedup vs baseline: 1.5555x; 1.5555x over previous
//
#include <hip/hip_runtime.h>
#include <stdint.h>

#define NND 40000
#define NE  640000
#define NG  128
#define DIM 128
#define HID 64
#define ADJ_BLOCKS 640
#define NOISY_BLOCKS 5000   // NND*32/256
#define NSCB ((NND + 255) / 256)   // 157 scan blocks
#define EMB_SPLIT 8

// ---------------- threefry2x32 (20 rounds), JAX-compatible ----------------
__host__ __device__ inline uint32_t rotl32(uint32_t v, uint32_t r) {
    return (v << r) | (v >> (32u - r));
}

__host__ __device__ inline void threefry2x32(uint32_t k0, uint32_t k1,
                                             uint32_t& x0, uint32_t& x1) {
    uint32_t k2 = k0 ^ k1 ^ 0x1BD11BDAu;
    x0 += k0; x1 += k1;
#define TFR(r) { x0 += x1; x1 = rotl32(x1, r); x1 ^= x0; }
    TFR(13u) TFR(15u) TFR(26u) TFR(6u)
    x0 += k1; x1 += k2 + 1u;
    TFR(17u) TFR(29u) TFR(16u) TFR(24u)
    x0 += k2; x1 += k0 + 2u;
    TFR(13u) TFR(15u) TFR(26u) TFR(6u)
    x0 += k0; x1 += k1 + 3u;
    TFR(17u) TFR(29u) TFR(16u) TFR(24u)
    x0 += k1; x1 += k2 + 4u;
    TFR(13u) TFR(15u) TFR(26u) TFR(6u)
    x0 += k2; x1 += k0 + 5u;
#undef TFR
}

// partitionable-mode random bits -> uniform [0,1)
__device__ inline float rbits_u01(uint32_t k0, uint32_t k1, uint32_t idx) {
    uint32_t x0 = 0u, x1 = idx;
    threefry2x32(k0, k1, x0, x1);
    uint32_t b = x0 ^ x1;
    return __uint_as_float((b >> 9) | 0x3f800000u) - 1.0f;
}

// ---------------- CSR build ----------------
__global__ __launch_bounds__(256) void hist_kernel(const int* __restrict__ dst,
                                                   int* __restrict__ deg) {
    int e = blockIdx.x * 256 + threadIdx.x;
    if (e < NE) atomicAdd(&deg[dst[e]], 1);
}

// hierarchical scan, step 1: per-block sums (coalesced)
__global__ __launch_bounds__(256) void scan_bsum_kernel(const int* __restrict__ deg,
                                                        int* __restrict__ bsum) {
    int t = threadIdx.x;
    int i = blockIdx.x * 256 + t;
    int v = (i < NND) ? deg[i] : 0;
    __shared__ int sh[256];
    sh[t] = v;
    __syncthreads();
#pragma unroll
    for (int s = 128; s > 0; s >>= 1) {
        if (t < s) sh[t] += sh[t + s];
        __syncthreads();
    }
    if (t == 0) bsum[blockIdx.x] = sh[0];
}

// step 2: single small block scans the 157 block sums -> exclusive block offsets
__global__ __launch_bounds__(256) void scan_boff_kernel(const int* __restrict__ bsum,
                                                        int* __restrict__ boff,
                                                        int* __restrict__ offv) {
    int t = threadIdx.x;
    int v = (t < NSCB) ? bsum[t] : 0;
    __shared__ int sh[256];
    sh[t] = v;
    __syncthreads();
    for (int d = 1; d < 256; d <<= 1) {
        int u = (t >= d) ? sh[t - d] : 0;
        __syncthreads();
        sh[t] += u;
        __syncthreads();
    }
    if (t < NSCB) boff[t] = sh[t] - v;   // exclusive
    if (t == NSCB - 1) offv[NND] = sh[t];
}

// step 3: block-local exclusive scan + block offset -> offv/cursor (coalesced)
__global__ __launch_bounds__(256) void scan_final_kernel(const int* __restrict__ deg,
                                                         const int* __restrict__ boff,
                                                         int* __restrict__ offv,
                                                         int* __restrict__ cursor) {
    int t = threadIdx.x;
    int i = blockIdx.x * 256 + t;
    int v = (i < NND) ? deg[i] : 0;
    __shared__ int sh[256];
    sh[t] = v;
    __syncthreads();
    for (int d = 1; d < 256; d <<= 1) {
        int u = (t >= d) ? sh[t - d] : 0;
        __syncthreads();
        sh[t] += u;
        __syncthreads();
    }
    int off = boff[blockIdx.x] + sh[t] - v;   // exclusive prefix
    if (i < NND) { offv[i] = off; cursor[i] = off; }
}

__global__ __launch_bounds__(256) void build_kernel(const int* __restrict__ src,
                                                    const int* __restrict__ dst,
                                                    int* __restrict__ cursor,
                                                    int* __restrict__ elist) {
    int e = blockIdx.x * 256 + threadIdx.x;
    if (e < NE) {
        int p = atomicAdd(&cursor[dst[e]], 1);
        elist[p] = src[e];
    }
}

// agg[n] = sum over in-edges of feat[src]; full overwrite (no zero-init needed)
__global__ __launch_bounds__(256) void gather_kernel(const float* __restrict__ feat,
                                                     const int* __restrict__ offv,
                                                     const int* __restrict__ elist,
                                                     float* __restrict__ agg) {
    int gt = blockIdx.x * 256 + threadIdx.x;
    int n = gt >> 5, c4 = gt & 31;
    int o0 = offv[n], o1 = offv[n + 1];
    float4 acc = make_float4(0.f, 0.f, 0.f, 0.f);
    for (int i = o0; i < o1; i++) {
        int s = elist[i];
        float4 v = *(const float4*)(feat + (size_t)s * DIM + c4 * 4);
        acc.x += v.x; acc.y += v.y; acc.z += v.z; acc.w += v.w;
    }
    *(float4*)(agg + (size_t)n * DIM + c4 * 4) = acc;
}

// ---------------- fused GEMM v3: W in LDS (split halves, conflict-free), A from
// global (wave-broadcast within rg-groups, L1/L2 hit), 8x8 register tile.
// out = ACT((A [+ A2]) @ W [+ bias]); ACT: 0=none,1=relu,2=tanh.
// STATS: per-block col sum/sumsq partials to sscr.
template <int K, int M, int ACT, int STATS>
__global__ __launch_bounds__(256, 2) void gemm_kernel(const float* __restrict__ A,
                                                      const float* A2,
                                                      const float* __restrict__ W,
                                                      const float* __restrict__ bias,
                                                      float* out,
                                                      float* __restrict__ sscr,
                                                      int nrows) {
    constexpr int CG  = M / 8;        // column groups (8 cols each): 16 or 8
    constexpr int RG  = 256 / CG;     // row groups: 16 or 32
    constexpr int RPB = RG * 8;       // rows per block: 128 or 256
    constexpr int MH  = M / 2;        // half-row stride
    constexpr int K4  = K / 4;
    __shared__ __align__(16) float sWa[K * MH];
    __shared__ __align__(16) float sWb[K * MH];

    const int t = threadIdx.x;
    const int row0 = blockIdx.x * RPB;
    const int cg = t % CG, rg = t / CG;

    // stage W split into halves: sWa holds cols cg*8..+3, sWb cols cg*8+4..+7,
    // each at float-offset k*MH + cg*4  (bank starts spread 2-way -> free reads)
    constexpr int W4 = M / 4;
    for (int i = t; i < K * W4; i += 256) {
        int k = i / W4, c4 = i % W4;
        float4 v = ((const float4*)W)[i];
        float* dstp = ((c4 & 1) == 0 ? sWa : sWb) + k * MH + (c4 >> 1) * 4;
        *(float4*)dstp = v;
    }
    __syncthreads();

    // per-thread row indices (clamped; OOB rows masked at epilogue)
    size_t roff[8];
#pragma unroll
    for (int i = 0; i < 8; i++) {
        int gr = row0 + rg * 8 + i;
        roff[i] = (size_t)min(gr, nrows - 1) * K4;
    }

    float acc[8][8];
#pragma unroll
    for (int i = 0; i < 8; i++)
#pragma unroll
        for (int j = 0; j < 8; j++) acc[i][j] = 0.f;

    const float4* A4 = (const float4*)A;
    const float4* B4 = (const float4*)A2;

    for (int kc = 0; kc < K4; kc++) {
        float4 a[8];
#pragma unroll
        for (int i = 0; i < 8; i++) {
            a[i] = A4[roff[i] + kc];
            if (A2) {
                float4 w2 = B4[roff[i] + kc];
                a[i].x += w2.x; a[i].y += w2.y; a[i].z += w2.z; a[i].w += w2.w;
            }
        }
#pragma unroll
        for (int kk = 0; kk < 4; kk++) {
            int k = kc * 4 + kk;
            float4 wA = *(const float4*)(sWa + k * MH + cg * 4);
            float4 wB = *(const float4*)(sWb + k * MH + cg * 4);
            float wv[8] = {wA.x, wA.y, wA.z, wA.w, wB.x, wB.y, wB.z, wB.w};
#pragma unroll
            for (int i = 0; i < 8; i++) {
                float av = ((const float*)&a[i])[kk];
#pragma unroll
                for (int j = 0; j < 8; j++) acc[i][j] = fmaf(av, wv[j], acc[i][j]);
            }
        }
    }

    float bv[8];
#pragma unroll
    for (int j = 0; j < 8; j++) bv[j] = bias ? bias[cg * 8 + j] : 0.f;

    float ps[8], pq[8];
#pragma unroll
    for (int j = 0; j < 8; j++) { ps[j] = 0.f; pq[j] = 0.f; }

#pragma unroll
    for (int i = 0; i < 8; i++) {
        int gr = row0 + rg * 8 + i;
        if (gr < nrows) {
            float o[8];
#pragma unroll
            for (int j = 0; j < 8; j++) {
                float v = acc[i][j] + bv[j];
                if (ACT == 1) v = fmaxf(v, 0.f);
                if (ACT == 2) v = tanhf(v);
                o[j] = v;
                ps[j] += v; pq[j] += v * v;
            }
            float4* o4 = (float4*)(out + (size_t)gr * M + cg * 8);
            o4[0] = make_float4(o[0], o[1], o[2], o[3]);
            o4[1] = make_float4(o[4], o[5], o[6], o[7]);
        }
    }

    if (STATS) {
        // reuse sWa (sum) / sWb (sumsq) as reduction scratch: RG*M <= K*MH
        __syncthreads();
#pragma unroll
        for (int j = 0; j < 8; j++) {
            sWa[rg * M + cg * 8 + j] = ps[j];
            sWb[rg * M + cg * 8 + j] = pq[j];
        }
        __syncthreads();
        if (t < M) {
            float s = 0.f, q = 0.f;
#pragma unroll
            for (int i = 0; i < RG; i++) { s += sWa[i * M + t]; q += sWb[i * M + t]; }
            sscr[(size_t)blockIdx.x * 2 * M + t]     = s;
            sscr[(size_t)blockIdx.x * 2 * M + M + t] = q;
        }
    }
}

// parallel reduce: sscr[nblk][2M] -> cs[2M]; grid = 2M/8 blocks x 256 threads.
template <int M>
__global__ __launch_bounds__(256) void stats_reduce_kernel(const float* __restrict__ sscr,
                                                           int nblk,
                                                           float* __restrict__ cs) {
    const int cols = 2 * M;
    const int t = threadIdx.x;
    const int c = blockIdx.x * 8 + (t & 7);   // global column
    const int rl = t >> 3;                    // row lane 0..31
    float s = 0.f;
    for (int r = rl; r < nblk; r += 32)
        s += sscr[(size_t)r * cols + c];
    __shared__ float sh[256];
    sh[t] = s;
    __syncthreads();
#pragma unroll
    for (int st = 128; st >= 8; st >>= 1) {
        if (t < st) sh[t] += sh[t + st];
        __syncthreads();
    }
    if (t < 8) cs[c] = sh[t];
}

// ---------------- in-place batchnorm apply (stats finalized inline) ----------------
template <int NC, int RELU>
__global__ __launch_bounds__(256) void bn_apply_kernel(float* buf,
                                                       const float* __restrict__ cs,
                                                       const float* __restrict__ g,
                                                       const float* __restrict__ b) {
    int i = blockIdx.x * 256 + threadIdx.x;
    const int total4 = NND * NC / 4;
    if (i >= total4) return;
    int c = (i * 4) % NC;
    const float invN = 1.0f / (float)NND;
    float4 v = ((float4*)buf)[i];
    float o[4] = {v.x, v.y, v.z, v.w};
#pragma unroll
    for (int j = 0; j < 4; j++) {
        float mu = cs[c + j] * invN;
        float var = fmaxf(cs[NC + c + j] * invN - mu * mu, 0.f);
        float rs = rsqrtf(var + 1e-5f);
        float A = g[c + j] * rs;
        float B = b[c + j] - mu * A;
        float y = fmaf(o[j], A, B);
        if (RELU) y = fmaxf(y, 0.f);
        o[j] = y;
    }
    ((float4*)buf)[i] = make_float4(o[0], o[1], o[2], o[3]);
}

// ---------------- assignment / gumbel-softmax lambdas ----------------
__global__ __launch_bounds__(256) void assign_kernel(const float* __restrict__ a1,
                                                     const float* __restrict__ Wfc2,
                                                     const float* __restrict__ bfc2,
                                                     float* __restrict__ assn,
                                                     float* __restrict__ lam,
                                                     uint32_t kg0, uint32_t kg1) {
    __shared__ float w[DIM * 2];
    int t = threadIdx.x;
    w[t] = Wfc2[t];  // 256 threads, 256 values
    __syncthreads();
    int n = blockIdx.x * 256 + t;
    if (n >= NND) return;

    float d0 = bfc2[0], d1 = bfc2[1];
    const float4* row4 = (const float4*)(a1 + (size_t)n * DIM);
#pragma unroll 8
    for (int k4 = 0; k4 < DIM / 4; k4++) {
        float4 v = row4[k4];
        d0 = fmaf(v.x, w[8 * k4 + 0], d0); d1 = fmaf(v.x, w[8 * k4 + 1], d1);
        d0 = fmaf(v.y, w[8 * k4 + 2], d0); d1 = fmaf(v.y, w[8 * k4 + 3], d1);
        d0 = fmaf(v.z, w[8 * k4 + 4], d0); d1 = fmaf(v.z, w[8 * k4 + 5], d1);
        d0 = fmaf(v.w, w[8 * k4 + 6], d0); d1 = fmaf(v.w, w[8 * k4 + 7], d1);
    }
    float m = fmaxf(d0, d1);
    float e0 = expf(d0 - m), e1 = expf(d1 - m);
    float inv = 1.f / (e0 + e1);
    float as0 = e0 * inv, as1 = e1 * inv;
    assn[2 * n] = as0; assn[2 * n + 1] = as1;

    float uf0 = rbits_u01(kg0, kg1, (uint32_t)(2 * n));
    float uf1 = rbits_u01(kg0, kg1, (uint32_t)(2 * n + 1));
    float u0 = fmaxf(1e-10f, uf0 + 1e-10f);
    float u1 = fmaxf(1e-10f, uf1 + 1e-10f);
    float gu0 = -logf(-logf(u0));
    float gu1 = -logf(-logf(u1));
    float y0 = as0 + gu0, y1 = as1 + gu1;
    float mm = fmaxf(y0, y1);
    float f0 = expf(y0 - mm), f1 = expf(y1 - mm);
    float iv = 1.f / (f0 + f1);
    lam[2 * n] = f0 * iv; lam[2 * n + 1] = f1 * iv;
}

// ---------------- noisy features + kl partial sums (per-block, no atomics) ------
__global__ __launch_bounds__(256) void noisy_kernel(const float* __restrict__ nfeat,
                                                    const float* __restrict__ lam,
                                                    const float* __restrict__ cs3,
                                                    float* __restrict__ noisy,
                                                    float* __restrict__ kpart,
                                                    uint32_t kn0, uint32_t kn1) {
    int gt = blockIdx.x * 256 + threadIdx.x;
    int n = gt >> 5, c4 = gt & 31, d = c4 * 4;
    const float invN = 1.0f / (float)NND;
    float la0 = lam[2 * n], la1 = lam[2 * n + 1];
    float4 xv = *(const float4*)(nfeat + (size_t)n * DIM + d);
    float xa[4] = {xv.x, xv.y, xv.z, xv.w};
    float t1 = 0.f, t2 = 0.f, o[4];
#pragma unroll
    for (int j = 0; j < 4; j++) {
        float mu = cs3[d + j] * invN;
        float q = cs3[DIM + d + j];
        float var1 = fmaxf(q - (float)NND * mu * mu, 0.f) / (float)(NND - 1);
        float sd = sqrtf(var1);
        float r = rbits_u01(kn0, kn1, (uint32_t)(n * DIM + d + j));
        float nm = la0 * xa[j] + la1 * mu;
        float ns = la1 * sd;
        o[j] = fmaf(r, ns, nm);
        float inv = 1.0f / (sd + 1e-7f);
        float z1 = ns * inv;            t1 += z1 * z1;
        float z2 = (nm - mu) * inv;     t2 += z2 * z2;
    }
    *(float4*)(noisy + (size_t)n * DIM + d) = make_float4(o[0], o[1], o[2], o[3]);

    __shared__ float s1[256], s2[256];
    int t = threadIdx.x;
    s1[t] = t1; s2[t] = t2;
    __syncthreads();
    for (int s = 128; s > 0; s >>= 1) {
        if (t < s) { s1[t] += s1[t + s]; s2[t] += s2[t + s]; }
        __syncthreads();
    }
    if (t == 0) { kpart[2 * blockIdx.x] = s1[0]; kpart[2 * blockIdx.x + 1] = s2[0]; }
}

// ---------------- graph segment starts (batch is sorted) ----------------
__global__ __launch_bounds__(256) void gstart_kernel(const int* __restrict__ batch,
                                                     int* __restrict__ gstart) {
    int i = blockIdx.x * 256 + threadIdx.x;
    if (i >= NND) return;
    int b = batch[i];
    int prev = (i == 0) ? -1 : batch[i - 1];
    for (int g = prev + 1; g <= b; g++) gstart[g] = i;
    if (i == NND - 1)
        for (int g = b + 1; g <= NG; g++) gstart[g] = NND;
}

// ---------------- graph mean pooling: split each graph across EMB_SPLIT blocks ----
__global__ __launch_bounds__(128) void graph_emb_part_kernel(const float* __restrict__ noisy,
                                                             const int* __restrict__ gstart,
                                                             float* __restrict__ gpart) {
    int g = blockIdx.x / EMB_SPLIT;
    int sidx = blockIdx.x % EMB_SPLIT;
    int c = threadIdx.x;
    int s = gstart[g], e = gstart[g + 1];
    int len = e - s;
    int chunk = (len + EMB_SPLIT - 1) / EMB_SPLIT;
    int r0 = s + sidx * chunk;
    int r1 = min(r0 + chunk, e);
    float acc = 0.f;
    for (int r = r0; r < r1; r++) acc += noisy[(size_t)r * DIM + c];
    gpart[((size_t)g * EMB_SPLIT + sidx) * DIM + c] = acc;
}

__global__ __launch_bounds__(128) void graph_emb_reduce_kernel(const float* __restrict__ gpart,
                                                               const int* __restrict__ gstart,
                                                               float* __restrict__ emb) {
    int g = blockIdx.x, c = threadIdx.x;
    float acc = 0.f;
#pragma unroll
    for (int si = 0; si < EMB_SPLIT; si++)
        acc += gpart[((size_t)g * EMB_SPLIT + si) * DIM + c];
    float cnt = (float)(gstart[g + 1] - gstart[g]);
    emb[(size_t)g * DIM + c] = acc / fmaxf(cnt, 1.f);
}

// ---------------- proto distances + final head (one wave per graph) ----------------
__global__ __launch_bounds__(64) void head_kernel(const float* __restrict__ emb,
                                                  const float* __restrict__ protos,
                                                  const float* __restrict__ Wlast,
                                                  float* __restrict__ out_logits,
                                                  float* __restrict__ out_probs,
                                                  float* __restrict__ out_sim,
                                                  float* __restrict__ out_dist) {
    int g = blockIdx.x, l = threadIdx.x;
    float ge0 = emb[(size_t)g * DIM + l];
    float ge1 = emb[(size_t)g * DIM + l + 64];
    float gn = ge0 * ge0 + ge1 * ge1;
    float dj[10], pj[10];
#pragma unroll
    for (int j = 0; j < 10; j++) {
        float pa = protos[j * DIM + l], pb = protos[j * DIM + l + 64];
        dj[j] = ge0 * pa + ge1 * pb;
        pj[j] = pa * pa + pb * pb;
    }
    float wl0 = ge0 * Wlast[10 + l] + ge1 * Wlast[10 + l + 64];
    float wl1 = ge0 * Wlast[138 + 10 + l] + ge1 * Wlast[138 + 10 + l + 64];
#pragma unroll
    for (int s = 32; s > 0; s >>= 1) {
        gn += __shfl_xor(gn, s);
        wl0 += __shfl_xor(wl0, s);
        wl1 += __shfl_xor(wl1, s);
#pragma unroll
        for (int j = 0; j < 10; j++) {
            dj[j] += __shfl_xor(dj[j], s);
            pj[j] += __shfl_xor(pj[j], s);
        }
    }
    if (l == 0) {
        float lg0 = wl0, lg1 = wl1;
#pragma unroll
        for (int j = 0; j < 10; j++) {
            float dist = -2.f * dj[j] + gn + pj[j];
            float sv = logf((dist + 1.0f) / (dist + 1e-4f));
            out_dist[g * 10 + j] = dist;
            out_sim[g * 10 + j] = sv;
            lg0 = fmaf(Wlast[j], sv, lg0);
            lg1 = fmaf(Wlast[138 + j], sv, lg1);
        }
        out_logits[2 * g] = lg0; out_logits[2 * g + 1] = lg1;
        float m = fmaxf(lg0, lg1);
        float e0 = expf(lg0 - m), e1 = expf(lg1 - m);
        float iv = 1.f / (e0 + e1);
        out_probs[2 * g] = e0 * iv; out_probs[2 * g + 1] = e1 * iv;
    }
}

// ---------------- 2x2 adjacency accumulation (per-block partials) ----------------
__global__ __launch_bounds__(256) void adj_kernel(const float* __restrict__ assn,
                                                  const int* __restrict__ src,
                                                  const int* __restrict__ dst,
                                                  float* __restrict__ adjp) {
    int t = threadIdx.x;
    float p00 = 0.f, p01 = 0.f, p10 = 0.f, p11 = 0.f;
    for (int e = blockIdx.x * 256 + t; e < NE; e += ADJ_BLOCKS * 256) {
        float2 a = *(const float2*)(assn + 2 * (size_t)src[e]);
        float2 b = *(const float2*)(assn + 2 * (size_t)dst[e]);
        p00 += a.x * b.x; p01 += a.x * b.y; p10 += a.y * b.x; p11 += a.y * b.y;
    }
    __shared__ float s0[256], s1[256], s2[256], s3[256];
    s0[t] = p00; s1[t] = p01; s2[t] = p10; s3[t] = p11;
    __syncthreads();
    for (int s = 128; s > 0; s >>= 1) {
        if (t < s) { s0[t] += s0[t + s]; s1[t] += s1[t + s]; s2[t] += s2[t + s]; s3[t] += s3[t + s]; }
        __syncthreads();
    }
    if (t == 0) {
        float4* o = (float4*)(adjp + 4 * (size_t)blockIdx.x);
        *o = make_float4(s0[0], s1[0], s2[0], s3[0]);
    }
}

// ---------------- final scalars: reduce kl + adj partials ----------------
__global__ __launch_bounds__(256) void final_scalar_kernel(const float* __restrict__ kpart,
                                                           const float* __restrict__ adjp,
                                                           float* __restrict__ out) {
    __shared__ float sh[6 * 256];
    int t = threadIdx.x;
    float k1 = 0.f, k2 = 0.f, a0 = 0.f, a1 = 0.f, a2 = 0.f, a3 = 0.f;
    for (int i = t; i < NOISY_BLOCKS; i += 256) {
        float2 v = ((const float2*)kpart)[i];
        k1 += v.x; k2 += v.y;
    }
    for (int i = t; i < ADJ_BLOCKS; i += 256) {
        float4 v = ((const float4*)adjp)[i];
        a0 += v.x; a1 += v.y; a2 += v.z; a3 += v.w;
    }
    sh[t] = k1; sh[256 + t] = k2; sh[512 + t] = a0;
    sh[768 + t] = a1; sh[1024 + t] = a2; sh[1280 + t] = a3;
    __syncthreads();
    for (int s = 128; s > 0; s >>= 1) {
        if (t < s) {
#pragma unroll
            for (int v = 0; v < 6; v++) sh[v * 256 + t] += sh[v * 256 + t + s];
        }
        __syncthreads();
    }
    if (t == 0) {
        float kl = 0.5f / ((float)NND * (float)DIM) * sh[0] + (1.0f / (float)DIM) * sh[256];
        out[16896] = kl;
        float a00 = sh[512], a01 = sh[768], a10 = sh[1024], a11 = sh[1280];
        float r0 = fmaxf(fabsf(a00) + fabsf(a01), 1e-12f);
        float r1 = fmaxf(fabsf(a10) + fabsf(a11), 1e-12f);
        float d0 = a00 / r0 - 1.f, d1 = a11 / r1 - 1.f;
        out[16897] = 0.5f * (d0 * d0 + d1 * d1);
    }
}

// ---------------- launcher ----------------
extern "C" void kernel_launch(void* const* d_in, const int* in_sizes, int n_in,
                              void* d_out, int out_size, void* d_ws, size_t ws_size,
                              hipStream_t stream) {
    (void)in_sizes; (void)n_in; (void)out_size; (void)ws_size;
    const float* x     = (const float*)d_in[0];
    const int*   ei    = (const int*)d_in[1];
    const int*   batch = (const int*)d_in[2];
    const float* W0a   = (const float*)d_in[3];
    const float* W0b   = (const float*)d_in[4];
    const float* g0    = (const float*)d_in[5];
    const float* b0    = (const float*)d_in[6];
    const float* W1a   = (const float*)d_in[7];
    const float* W1b   = (const float*)d_in[8];
    const float* g1    = (const float*)d_in[9];
    const float* b1    = (const float*)d_in[10];
    const float* Wm0   = (const float*)d_in[11];
    const float* bm0   = (const float*)d_in[12];
    const float* gm    = (const float*)d_in[13];
    const float* bm    = (const float*)d_in[14];
    const float* Wm1   = (const float*)d_in[15];
    const float* bm1   = (const float*)d_in[16];
    const float* Wfc1  = (const float*)d_in[17];
    const float* bfc1  = (const float*)d_in[18];
    const float* Wfc2  = (const float*)d_in[19];
    const float* bfc2  = (const float*)d_in[20];
    const float* protos= (const float*)d_in[21];
    const float* Wlast = (const float*)d_in[22];
    const int* src = ei;
    const int* dst = ei + NE;
    float* out = (float*)d_out;

    float* ws   = (float*)d_ws;
    float* agg  = ws;                               // N*128
    float* tA   = agg + (size_t)NND * DIM;          // N*128
    float* t5   = tA + (size_t)NND * DIM;           // N*64
    float* lam  = t5 + (size_t)NND * HID;           // N*2
    float* assn = lam + (size_t)NND * 2;            // N*2
    float* cs   = assn + (size_t)NND * 2;           // 1024 (4 stat segments)
    float* kpart= cs + 1024;                        // NOISY_BLOCKS*2
    float* adjp = kpart + NOISY_BLOCKS * 2;         // ADJ_BLOCKS*4
    float* sscr = adjp + ADJ_BLOCKS * 4;            // 625*256 stats partials
    float* gpart= sscr + 625 * 256;                 // NG*EMB_SPLIT*DIM
    int* ib     = (int*)(gpart + NG * EMB_SPLIT * DIM);  // int region
    int* deg    = ib;                               // N
    int* offv   = deg + NND;                        // N+1
    int* cursor = offv + NND + 1;                   // N
    int* elist  = cursor + NND;                     // E
    int* gstart = elist + NE;                       // NG+1
    int* bsum   = gstart + NG + 1;                  // NSCB
    int* boff   = bsum + NSCB;                      // NSCB

    // threefry keys on host: key(42) = (0,42); partitionable fold-like split
    uint32_t kg0 = 0u, kg1 = 0u; threefry2x32(0u, 42u, kg0, kg1);  // ctr (0,0)
    uint32_t kn0 = 0u, kn1 = 1u; threefry2x32(0u, 42u, kn0, kn1);  // ctr (0,1)

    hipMemsetAsync(deg, 0, NND * sizeof(int), stream);

    // CSR (shared by both GIN layers)
    hist_kernel<<<(NE + 255) / 256, 256, 0, stream>>>(dst, deg);
    scan_bsum_kernel<<<NSCB, 256, 0, stream>>>(deg, bsum);
    scan_boff_kernel<<<1, 256, 0, stream>>>(bsum, boff, offv);
    scan_final_kernel<<<NSCB, 256, 0, stream>>>(deg, boff, offv, cursor);
    build_kernel<<<(NE + 255) / 256, 256, 0, stream>>>(src, dst, cursor, elist);

    // grids: RPB=128 for M=128 (313 blocks), RPB=256 for M=64 (157 blocks)
    const int G128 = (NND + 127) / 128;   // 313
    const int G64  = (NND + 255) / 256;   // 157

    // GIN layer 1
    gather_kernel<<<(NND * 32) / 256, 256, 0, stream>>>(x, offv, elist, agg);
    gemm_kernel<128,128,1,0><<<G128, 256, 0, stream>>>(x, agg, W0a, nullptr, agg, nullptr, NND);
    gemm_kernel<128,128,1,1><<<G128, 256, 0, stream>>>(agg, nullptr, W0b, nullptr, tA, sscr, NND);
    stats_reduce_kernel<128><<<32, 256, 0, stream>>>(sscr, G128, cs + 0);
    bn_apply_kernel<128,1><<<5000, 256, 0, stream>>>(tA, cs + 0, g0, b0);      // nf1

    // GIN layer 2
    gather_kernel<<<(NND * 32) / 256, 256, 0, stream>>>(tA, offv, elist, agg);
    gemm_kernel<128,128,1,0><<<G128, 256, 0, stream>>>(tA, agg, W1a, nullptr, agg, nullptr, NND);
    gemm_kernel<128,128,1,1><<<G128, 256, 0, stream>>>(agg, nullptr, W1b, nullptr, tA, sscr, NND);
    stats_reduce_kernel<128><<<32, 256, 0, stream>>>(sscr, G128, cs + 256);
    bn_apply_kernel<128,0><<<5000, 256, 0, stream>>>(tA, cs + 256, g1, b1);    // nf2

    // bottleneck MLP
    gemm_kernel<128,64,0,1><<<G64, 256, 0, stream>>>(tA, nullptr, Wm0, bm0, t5, sscr, NND);
    stats_reduce_kernel<64><<<16, 256, 0, stream>>>(sscr, G64, cs + 512);
    bn_apply_kernel<64,1><<<2500, 256, 0, stream>>>(t5, cs + 512, gm, bm);     // h
    gemm_kernel<64,128,0,1><<<G128, 256, 0, stream>>>(t5, nullptr, Wm1, bm1, agg, sscr, NND); // node_feature
    stats_reduce_kernel<128><<<32, 256, 0, stream>>>(sscr, G128, cs + 640);
    gemm_kernel<128,128,2,0><<<G128, 256, 0, stream>>>(agg, nullptr, Wfc1, bfc1, tA, nullptr, NND); // a1

    // assignment + gumbel
    assign_kernel<<<(NND + 255) / 256, 256, 0, stream>>>(tA, Wfc2, bfc2, assn, lam, kg0, kg1);

    // noisy features (into tA) + kl partials
    noisy_kernel<<<NOISY_BLOCKS, 256, 0, stream>>>(agg, lam, cs + 640, tA, kpart, kn0, kn1);

    // graph pooling + head
    gstart_kernel<<<(NND + 255) / 256, 256, 0, stream>>>(batch, gstart);
    graph_emb_part_kernel<<<NG * EMB_SPLIT, 128, 0, stream>>>(tA, gstart, gpart);
    graph_emb_reduce_kernel<<<NG, 128, 0, stream>>>(gpart, gstart, out + 512);
    head_kernel<<<NG, 64, 0, stream>>>(out + 512, protos, Wlast,
                                       out, out + 256, out + 16898, out + 18178);

    // penalties
    adj_kernel<<<ADJ_BLOCKS, 256, 0, stream>>>(assn, src, dst, adjp);
    final_scalar_kernel<<<1, 256, 0, stream>>>(kpart, adjp, out);
}

// Round 8
// 489.038 us; speedup vs baseline: 1.8230x; 1.1720x over previous
//
#include <hip/hip_runtime.h>
#include <stdint.h>

#define NND 40000
#define NE  640000
#define NG  128
#define DIM 128
#define HID 64
#define ADJ_BLOCKS 640
#define NOISY_BLOCKS 5000   // NND*32/256
#define NSCB ((NND + 255) / 256)   // 157 scan blocks
#define EMB_SPLIT 8

// ---------------- threefry2x32 (20 rounds), JAX-compatible ----------------
__host__ __device__ inline uint32_t rotl32(uint32_t v, uint32_t r) {
    return (v << r) | (v >> (32u - r));
}

__host__ __device__ inline void threefry2x32(uint32_t k0, uint32_t k1,
                                             uint32_t& x0, uint32_t& x1) {
    uint32_t k2 = k0 ^ k1 ^ 0x1BD11BDAu;
    x0 += k0; x1 += k1;
#define TFR(r) { x0 += x1; x1 = rotl32(x1, r); x1 ^= x0; }
    TFR(13u) TFR(15u) TFR(26u) TFR(6u)
    x0 += k1; x1 += k2 + 1u;
    TFR(17u) TFR(29u) TFR(16u) TFR(24u)
    x0 += k2; x1 += k0 + 2u;
    TFR(13u) TFR(15u) TFR(26u) TFR(6u)
    x0 += k0; x1 += k1 + 3u;
    TFR(17u) TFR(29u) TFR(16u) TFR(24u)
    x0 += k1; x1 += k2 + 4u;
    TFR(13u) TFR(15u) TFR(26u) TFR(6u)
    x0 += k2; x1 += k0 + 5u;
#undef TFR
}

// partitionable-mode random bits -> uniform [0,1)
__device__ inline float rbits_u01(uint32_t k0, uint32_t k1, uint32_t idx) {
    uint32_t x0 = 0u, x1 = idx;
    threefry2x32(k0, k1, x0, x1);
    uint32_t b = x0 ^ x1;
    return __uint_as_float((b >> 9) | 0x3f800000u) - 1.0f;
}

// ---------------- CSR build ----------------
__global__ __launch_bounds__(256) void hist_kernel(const int* __restrict__ dst,
                                                   int* __restrict__ deg) {
    int e = blockIdx.x * 256 + threadIdx.x;
    if (e < NE) atomicAdd(&deg[dst[e]], 1);
}

// hierarchical scan, step 1: per-block sums (coalesced)
__global__ __launch_bounds__(256) void scan_bsum_kernel(const int* __restrict__ deg,
                                                        int* __restrict__ bsum) {
    int t = threadIdx.x;
    int i = blockIdx.x * 256 + t;
    int v = (i < NND) ? deg[i] : 0;
    __shared__ int sh[256];
    sh[t] = v;
    __syncthreads();
#pragma unroll
    for (int s = 128; s > 0; s >>= 1) {
        if (t < s) sh[t] += sh[t + s];
        __syncthreads();
    }
    if (t == 0) bsum[blockIdx.x] = sh[0];
}

// step 2: single small block scans the 157 block sums -> exclusive block offsets
__global__ __launch_bounds__(256) void scan_boff_kernel(const int* __restrict__ bsum,
                                                        int* __restrict__ boff,
                                                        int* __restrict__ offv) {
    int t = threadIdx.x;
    int v = (t < NSCB) ? bsum[t] : 0;
    __shared__ int sh[256];
    sh[t] = v;
    __syncthreads();
    for (int d = 1; d < 256; d <<= 1) {
        int u = (t >= d) ? sh[t - d] : 0;
        __syncthreads();
        sh[t] += u;
        __syncthreads();
    }
    if (t < NSCB) boff[t] = sh[t] - v;   // exclusive
    if (t == NSCB - 1) offv[NND] = sh[t];
}

// step 3: block-local exclusive scan + block offset -> offv/cursor (coalesced)
__global__ __launch_bounds__(256) void scan_final_kernel(const int* __restrict__ deg,
                                                         const int* __restrict__ boff,
                                                         int* __restrict__ offv,
                                                         int* __restrict__ cursor) {
    int t = threadIdx.x;
    int i = blockIdx.x * 256 + t;
    int v = (i < NND) ? deg[i] : 0;
    __shared__ int sh[256];
    sh[t] = v;
    __syncthreads();
    for (int d = 1; d < 256; d <<= 1) {
        int u = (t >= d) ? sh[t - d] : 0;
        __syncthreads();
        sh[t] += u;
        __syncthreads();
    }
    int off = boff[blockIdx.x] + sh[t] - v;   // exclusive prefix
    if (i < NND) { offv[i] = off; cursor[i] = off; }
}

__global__ __launch_bounds__(256) void build_kernel(const int* __restrict__ src,
                                                    const int* __restrict__ dst,
                                                    int* __restrict__ cursor,
                                                    int* __restrict__ elist) {
    int e = blockIdx.x * 256 + threadIdx.x;
    if (e < NE) {
        int p = atomicAdd(&cursor[dst[e]], 1);
        elist[p] = src[e];
    }
}

// agg[n] = feat[n] + sum over in-edges of feat[src]  (GIN self-term folded in)
__global__ __launch_bounds__(256) void gather_kernel(const float* __restrict__ feat,
                                                     const int* __restrict__ offv,
                                                     const int* __restrict__ elist,
                                                     float* __restrict__ agg) {
    int gt = blockIdx.x * 256 + threadIdx.x;
    int n = gt >> 5, c4 = gt & 31;
    int o0 = offv[n], o1 = offv[n + 1];
    float4 acc = *(const float4*)(feat + (size_t)n * DIM + c4 * 4);  // self
    for (int i = o0; i < o1; i++) {
        int s = elist[i];
        float4 v = *(const float4*)(feat + (size_t)s * DIM + c4 * 4);
        acc.x += v.x; acc.y += v.y; acc.z += v.z; acc.w += v.w;
    }
    *(float4*)(agg + (size_t)n * DIM + c4 * 4) = acc;
}

// ---------------- fused GEMM v4: 128 threads, 128 rows x 64 cols per block,
// 8x8 thread tile. W col-slice in LDS (two half-arrays, conflict-free b128 reads),
// A from global, 2-deep software prefetch. grid = (ceil(N/128), M/64).
// out = ACT(A @ W [+ bias]); ACT: 0=none,1=relu,2=tanh.
// STATS: per-(row-block) col sum/sumsq partials into sscr (col blocks disjoint).
#define GEMM_COMPUTE(buf, kcv)                                               \
    _Pragma("unroll")                                                        \
    for (int kk = 0; kk < 4; kk++) {                                         \
        int k_ = (kcv) * 4 + kk;                                             \
        float4 wA = *(const float4*)(sWa + k_ * 32 + cg * 4);                \
        float4 wB = *(const float4*)(sWb + k_ * 32 + cg * 4);                \
        float wv[8] = {wA.x, wA.y, wA.z, wA.w, wB.x, wB.y, wB.z, wB.w};      \
        _Pragma("unroll")                                                    \
        for (int i = 0; i < 8; i++) {                                        \
            float av = ((const float*)&buf[i])[kk];                          \
            _Pragma("unroll")                                                \
            for (int j = 0; j < 8; j++)                                      \
                acc[i][j] = fmaf(av, wv[j], acc[i][j]);                      \
        }                                                                    \
    }

template <int K, int M, int ACT, int STATS>
__global__ __launch_bounds__(128, 2) void gemm_kernel(const float* __restrict__ A,
                                                      const float* __restrict__ W,
                                                      const float* __restrict__ bias,
                                                      float* __restrict__ out,
                                                      float* __restrict__ sscr,
                                                      int nrows) {
    constexpr int K4 = K / 4;
    __shared__ __align__(16) float sWa[K * 32];
    __shared__ __align__(16) float sWb[K * 32];

    const int t = threadIdx.x;
    const int cg = t & 7;         // 0..7 (8 cols each)
    const int rg = t >> 3;        // 0..15 (8 rows each)
    const int col0 = blockIdx.y * 64;
    const int row0 = blockIdx.x * 128;

    // stage W col-slice [K][64] split into halves (cols cg*8..+3 -> sWa, +4..+7 -> sWb)
    for (int i = t; i < K * 16; i += 128) {
        int k = i >> 4, c4 = i & 15;
        float4 v = *(const float4*)(W + (size_t)k * M + col0 + c4 * 4);
        float* d = ((c4 & 1) ? sWb : sWa) + k * 32 + (c4 >> 1) * 4;
        *(float4*)d = v;
    }
    __syncthreads();

    size_t roff[8];
#pragma unroll
    for (int i = 0; i < 8; i++) {
        int gr = row0 + rg * 8 + i;
        roff[i] = (size_t)min(gr, nrows - 1) * K4;
    }

    float acc[8][8];
#pragma unroll
    for (int i = 0; i < 8; i++)
#pragma unroll
        for (int j = 0; j < 8; j++) acc[i][j] = 0.f;

    const float4* A4 = (const float4*)A;
    float4 pa[8], pb[8];
#pragma unroll
    for (int i = 0; i < 8; i++) pa[i] = A4[roff[i]];

    for (int kc = 0; kc < K4; kc += 2) {
#pragma unroll
        for (int i = 0; i < 8; i++) pb[i] = A4[roff[i] + kc + 1];
        GEMM_COMPUTE(pa, kc)
        if (kc + 2 < K4) {
#pragma unroll
            for (int i = 0; i < 8; i++) pa[i] = A4[roff[i] + kc + 2];
        }
        GEMM_COMPUTE(pb, kc + 1)
    }

    float bv[8];
#pragma unroll
    for (int j = 0; j < 8; j++) bv[j] = bias ? bias[col0 + cg * 8 + j] : 0.f;

    float ps[8], pq[8];
#pragma unroll
    for (int j = 0; j < 8; j++) { ps[j] = 0.f; pq[j] = 0.f; }

#pragma unroll
    for (int i = 0; i < 8; i++) {
        int gr = row0 + rg * 8 + i;
        if (gr < nrows) {
            float o[8];
#pragma unroll
            for (int j = 0; j < 8; j++) {
                float v = acc[i][j] + bv[j];
                if (ACT == 1) v = fmaxf(v, 0.f);
                if (ACT == 2) v = tanhf(v);
                o[j] = v;
                ps[j] += v; pq[j] += v * v;
            }
            float4* o4 = (float4*)(out + (size_t)gr * M + col0 + cg * 8);
            o4[0] = make_float4(o[0], o[1], o[2], o[3]);
            o4[1] = make_float4(o[4], o[5], o[6], o[7]);
        }
    }

    if (STATS) {
        // reuse sWa (sum) / sWb (sumsq): need 16*64=1024 floats <= K*32
        __syncthreads();
#pragma unroll
        for (int j = 0; j < 8; j++) {
            sWa[rg * 64 + cg * 8 + j] = ps[j];
            sWb[rg * 64 + cg * 8 + j] = pq[j];
        }
        __syncthreads();
        if (t < 64) {
            float s = 0.f, q = 0.f;
#pragma unroll
            for (int i = 0; i < 16; i++) { s += sWa[i * 64 + t]; q += sWb[i * 64 + t]; }
            sscr[(size_t)blockIdx.x * 2 * M + col0 + t]     = s;
            sscr[(size_t)blockIdx.x * 2 * M + M + col0 + t] = q;
        }
    }
}

// parallel reduce: sscr[nblk][2M] -> cs[2M]; grid = 2M/8 blocks x 256 threads.
template <int M>
__global__ __launch_bounds__(256) void stats_reduce_kernel(const float* __restrict__ sscr,
                                                           int nblk,
                                                           float* __restrict__ cs) {
    const int cols = 2 * M;
    const int t = threadIdx.x;
    const int c = blockIdx.x * 8 + (t & 7);   // global column
    const int rl = t >> 3;                    // row lane 0..31
    float s = 0.f;
    for (int r = rl; r < nblk; r += 32)
        s += sscr[(size_t)r * cols + c];
    __shared__ float sh[256];
    sh[t] = s;
    __syncthreads();
#pragma unroll
    for (int st = 128; st >= 8; st >>= 1) {
        if (t < st) sh[t] += sh[t + st];
        __syncthreads();
    }
    if (t < 8) cs[c] = sh[t];
}

// ---------------- in-place batchnorm apply (stats finalized inline) ----------------
template <int NC, int RELU>
__global__ __launch_bounds__(256) void bn_apply_kernel(float* buf,
                                                       const float* __restrict__ cs,
                                                       const float* __restrict__ g,
                                                       const float* __restrict__ b) {
    int i = blockIdx.x * 256 + threadIdx.x;
    const int total4 = NND * NC / 4;
    if (i >= total4) return;
    int c = (i * 4) % NC;
    const float invN = 1.0f / (float)NND;
    float4 v = ((float4*)buf)[i];
    float o[4] = {v.x, v.y, v.z, v.w};
#pragma unroll
    for (int j = 0; j < 4; j++) {
        float mu = cs[c + j] * invN;
        float var = fmaxf(cs[NC + c + j] * invN - mu * mu, 0.f);
        float rs = rsqrtf(var + 1e-5f);
        float A = g[c + j] * rs;
        float B = b[c + j] - mu * A;
        float y = fmaf(o[j], A, B);
        if (RELU) y = fmaxf(y, 0.f);
        o[j] = y;
    }
    ((float4*)buf)[i] = make_float4(o[0], o[1], o[2], o[3]);
}

// ---------------- assignment / gumbel-softmax lambdas ----------------
__global__ __launch_bounds__(256) void assign_kernel(const float* __restrict__ a1,
                                                     const float* __restrict__ Wfc2,
                                                     const float* __restrict__ bfc2,
                                                     float* __restrict__ assn,
                                                     float* __restrict__ lam,
                                                     uint32_t kg0, uint32_t kg1) {
    __shared__ float w[DIM * 2];
    int t = threadIdx.x;
    w[t] = Wfc2[t];  // 256 threads, 256 values
    __syncthreads();
    int n = blockIdx.x * 256 + t;
    if (n >= NND) return;

    float d0 = bfc2[0], d1 = bfc2[1];
    const float4* row4 = (const float4*)(a1 + (size_t)n * DIM);
#pragma unroll 8
    for (int k4 = 0; k4 < DIM / 4; k4++) {
        float4 v = row4[k4];
        d0 = fmaf(v.x, w[8 * k4 + 0], d0); d1 = fmaf(v.x, w[8 * k4 + 1], d1);
        d0 = fmaf(v.y, w[8 * k4 + 2], d0); d1 = fmaf(v.y, w[8 * k4 + 3], d1);
        d0 = fmaf(v.z, w[8 * k4 + 4], d0); d1 = fmaf(v.z, w[8 * k4 + 5], d1);
        d0 = fmaf(v.w, w[8 * k4 + 6], d0); d1 = fmaf(v.w, w[8 * k4 + 7], d1);
    }
    float m = fmaxf(d0, d1);
    float e0 = expf(d0 - m), e1 = expf(d1 - m);
    float inv = 1.f / (e0 + e1);
    float as0 = e0 * inv, as1 = e1 * inv;
    assn[2 * n] = as0; assn[2 * n + 1] = as1;

    float uf0 = rbits_u01(kg0, kg1, (uint32_t)(2 * n));
    float uf1 = rbits_u01(kg0, kg1, (uint32_t)(2 * n + 1));
    float u0 = fmaxf(1e-10f, uf0 + 1e-10f);
    float u1 = fmaxf(1e-10f, uf1 + 1e-10f);
    float gu0 = -logf(-logf(u0));
    float gu1 = -logf(-logf(u1));
    float y0 = as0 + gu0, y1 = as1 + gu1;
    float mm = fmaxf(y0, y1);
    float f0 = expf(y0 - mm), f1 = expf(y1 - mm);
    float iv = 1.f / (f0 + f1);
    lam[2 * n] = f0 * iv; lam[2 * n + 1] = f1 * iv;
}

// ---------------- noisy features + kl partial sums (per-block, no atomics) ------
__global__ __launch_bounds__(256) void noisy_kernel(const float* __restrict__ nfeat,
                                                    const float* __restrict__ lam,
                                                    const float* __restrict__ cs3,
                                                    float* __restrict__ noisy,
                                                    float* __restrict__ kpart,
                                                    uint32_t kn0, uint32_t kn1) {
    int gt = blockIdx.x * 256 + threadIdx.x;
    int n = gt >> 5, c4 = gt & 31, d = c4 * 4;
    const float invN = 1.0f / (float)NND;
    float la0 = lam[2 * n], la1 = lam[2 * n + 1];
    float4 xv = *(const float4*)(nfeat + (size_t)n * DIM + d);
    float xa[4] = {xv.x, xv.y, xv.z, xv.w};
    float t1 = 0.f, t2 = 0.f, o[4];
#pragma unroll
    for (int j = 0; j < 4; j++) {
        float mu = cs3[d + j] * invN;
        float q = cs3[DIM + d + j];
        float var1 = fmaxf(q - (float)NND * mu * mu, 0.f) / (float)(NND - 1);
        float sd = sqrtf(var1);
        float r = rbits_u01(kn0, kn1, (uint32_t)(n * DIM + d + j));
        float nm = la0 * xa[j] + la1 * mu;
        float ns = la1 * sd;
        o[j] = fmaf(r, ns, nm);
        float inv = 1.0f / (sd + 1e-7f);
        float z1 = ns * inv;            t1 += z1 * z1;
        float z2 = (nm - mu) * inv;     t2 += z2 * z2;
    }
    *(float4*)(noisy + (size_t)n * DIM + d) = make_float4(o[0], o[1], o[2], o[3]);

    __shared__ float s1[256], s2[256];
    int t = threadIdx.x;
    s1[t] = t1; s2[t] = t2;
    __syncthreads();
    for (int s = 128; s > 0; s >>= 1) {
        if (t < s) { s1[t] += s1[t + s]; s2[t] += s2[t + s]; }
        __syncthreads();
    }
    if (t == 0) { kpart[2 * blockIdx.x] = s1[0]; kpart[2 * blockIdx.x + 1] = s2[0]; }
}

// ---------------- graph segment starts (batch is sorted) ----------------
__global__ __launch_bounds__(256) void gstart_kernel(const int* __restrict__ batch,
                                                     int* __restrict__ gstart) {
    int i = blockIdx.x * 256 + threadIdx.x;
    if (i >= NND) return;
    int b = batch[i];
    int prev = (i == 0) ? -1 : batch[i - 1];
    for (int g = prev + 1; g <= b; g++) gstart[g] = i;
    if (i == NND - 1)
        for (int g = b + 1; g <= NG; g++) gstart[g] = NND;
}

// ---------------- graph mean pooling: split each graph across EMB_SPLIT blocks ----
__global__ __launch_bounds__(128) void graph_emb_part_kernel(const float* __restrict__ noisy,
                                                             const int* __restrict__ gstart,
                                                             float* __restrict__ gpart) {
    int g = blockIdx.x / EMB_SPLIT;
    int sidx = blockIdx.x % EMB_SPLIT;
    int c = threadIdx.x;
    int s = gstart[g], e = gstart[g + 1];
    int len = e - s;
    int chunk = (len + EMB_SPLIT - 1) / EMB_SPLIT;
    int r0 = s + sidx * chunk;
    int r1 = min(r0 + chunk, e);
    float acc = 0.f;
    for (int r = r0; r < r1; r++) acc += noisy[(size_t)r * DIM + c];
    gpart[((size_t)g * EMB_SPLIT + sidx) * DIM + c] = acc;
}

__global__ __launch_bounds__(128) void graph_emb_reduce_kernel(const float* __restrict__ gpart,
                                                               const int* __restrict__ gstart,
                                                               float* __restrict__ emb) {
    int g = blockIdx.x, c = threadIdx.x;
    float acc = 0.f;
#pragma unroll
    for (int si = 0; si < EMB_SPLIT; si++)
        acc += gpart[((size_t)g * EMB_SPLIT + si) * DIM + c];
    float cnt = (float)(gstart[g + 1] - gstart[g]);
    emb[(size_t)g * DIM + c] = acc / fmaxf(cnt, 1.f);
}

// ---------------- proto distances + final head (one wave per graph) ----------------
__global__ __launch_bounds__(64) void head_kernel(const float* __restrict__ emb,
                                                  const float* __restrict__ protos,
                                                  const float* __restrict__ Wlast,
                                                  float* __restrict__ out_logits,
                                                  float* __restrict__ out_probs,
                                                  float* __restrict__ out_sim,
                                                  float* __restrict__ out_dist) {
    int g = blockIdx.x, l = threadIdx.x;
    float ge0 = emb[(size_t)g * DIM + l];
    float ge1 = emb[(size_t)g * DIM + l + 64];
    float gn = ge0 * ge0 + ge1 * ge1;
    float dj[10], pj[10];
#pragma unroll
    for (int j = 0; j < 10; j++) {
        float pa = protos[j * DIM + l], pb = protos[j * DIM + l + 64];
        dj[j] = ge0 * pa + ge1 * pb;
        pj[j] = pa * pa + pb * pb;
    }
    float wl0 = ge0 * Wlast[10 + l] + ge1 * Wlast[10 + l + 64];
    float wl1 = ge0 * Wlast[138 + 10 + l] + ge1 * Wlast[138 + 10 + l + 64];
#pragma unroll
    for (int s = 32; s > 0; s >>= 1) {
        gn += __shfl_xor(gn, s);
        wl0 += __shfl_xor(wl0, s);
        wl1 += __shfl_xor(wl1, s);
#pragma unroll
        for (int j = 0; j < 10; j++) {
            dj[j] += __shfl_xor(dj[j], s);
            pj[j] += __shfl_xor(pj[j], s);
        }
    }
    if (l == 0) {
        float lg0 = wl0, lg1 = wl1;
#pragma unroll
        for (int j = 0; j < 10; j++) {
            float dist = -2.f * dj[j] + gn + pj[j];
            float sv = logf((dist + 1.0f) / (dist + 1e-4f));
            out_dist[g * 10 + j] = dist;
            out_sim[g * 10 + j] = sv;
            lg0 = fmaf(Wlast[j], sv, lg0);
            lg1 = fmaf(Wlast[138 + j], sv, lg1);
        }
        out_logits[2 * g] = lg0; out_logits[2 * g + 1] = lg1;
        float m = fmaxf(lg0, lg1);
        float e0 = expf(lg0 - m), e1 = expf(lg1 - m);
        float iv = 1.f / (e0 + e1);
        out_probs[2 * g] = e0 * iv; out_probs[2 * g + 1] = e1 * iv;
    }
}

// ---------------- 2x2 adjacency accumulation (per-block partials) ----------------
__global__ __launch_bounds__(256) void adj_kernel(const float* __restrict__ assn,
                                                  const int* __restrict__ src,
                                                  const int* __restrict__ dst,
                                                  float* __restrict__ adjp) {
    int t = threadIdx.x;
    float p00 = 0.f, p01 = 0.f, p10 = 0.f, p11 = 0.f;
    for (int e = blockIdx.x * 256 + t; e < NE; e += ADJ_BLOCKS * 256) {
        float2 a = *(const float2*)(assn + 2 * (size_t)src[e]);
        float2 b = *(const float2*)(assn + 2 * (size_t)dst[e]);
        p00 += a.x * b.x; p01 += a.x * b.y; p10 += a.y * b.x; p11 += a.y * b.y;
    }
    __shared__ float s0[256], s1[256], s2[256], s3[256];
    s0[t] = p00; s1[t] = p01; s2[t] = p10; s3[t] = p11;
    __syncthreads();
    for (int s = 128; s > 0; s >>= 1) {
        if (t < s) { s0[t] += s0[t + s]; s1[t] += s1[t + s]; s2[t] += s2[t + s]; s3[t] += s3[t + s]; }
        __syncthreads();
    }
    if (t == 0) {
        float4* o = (float4*)(adjp + 4 * (size_t)blockIdx.x);
        *o = make_float4(s0[0], s1[0], s2[0], s3[0]);
    }
}

// ---------------- final scalars: reduce kl + adj partials ----------------
__global__ __launch_bounds__(256) void final_scalar_kernel(const float* __restrict__ kpart,
                                                           const float* __restrict__ adjp,
                                                           float* __restrict__ out) {
    __shared__ float sh[6 * 256];
    int t = threadIdx.x;
    float k1 = 0.f, k2 = 0.f, a0 = 0.f, a1 = 0.f, a2 = 0.f, a3 = 0.f;
    for (int i = t; i < NOISY_BLOCKS; i += 256) {
        float2 v = ((const float2*)kpart)[i];
        k1 += v.x; k2 += v.y;
    }
    for (int i = t; i < ADJ_BLOCKS; i += 256) {
        float4 v = ((const float4*)adjp)[i];
        a0 += v.x; a1 += v.y; a2 += v.z; a3 += v.w;
    }
    sh[t] = k1; sh[256 + t] = k2; sh[512 + t] = a0;
    sh[768 + t] = a1; sh[1024 + t] = a2; sh[1280 + t] = a3;
    __syncthreads();
    for (int s = 128; s > 0; s >>= 1) {
        if (t < s) {
#pragma unroll
            for (int v = 0; v < 6; v++) sh[v * 256 + t] += sh[v * 256 + t + s];
        }
        __syncthreads();
    }
    if (t == 0) {
        float kl = 0.5f / ((float)NND * (float)DIM) * sh[0] + (1.0f / (float)DIM) * sh[256];
        out[16896] = kl;
        float a00 = sh[512], a01 = sh[768], a10 = sh[1024], a11 = sh[1280];
        float r0 = fmaxf(fabsf(a00) + fabsf(a01), 1e-12f);
        float r1 = fmaxf(fabsf(a10) + fabsf(a11), 1e-12f);
        float d0 = a00 / r0 - 1.f, d1 = a11 / r1 - 1.f;
        out[16897] = 0.5f * (d0 * d0 + d1 * d1);
    }
}

// ---------------- launcher ----------------
extern "C" void kernel_launch(void* const* d_in, const int* in_sizes, int n_in,
                              void* d_out, int out_size, void* d_ws, size_t ws_size,
                              hipStream_t stream) {
    (void)in_sizes; (void)n_in; (void)out_size; (void)ws_size;
    const float* x     = (const float*)d_in[0];
    const int*   ei    = (const int*)d_in[1];
    const int*   batch = (const int*)d_in[2];
    const float* W0a   = (const float*)d_in[3];
    const float* W0b   = (const float*)d_in[4];
    const float* g0    = (const float*)d_in[5];
    const float* b0    = (const float*)d_in[6];
    const float* W1a   = (const float*)d_in[7];
    const float* W1b   = (const float*)d_in[8];
    const float* g1    = (const float*)d_in[9];
    const float* b1    = (const float*)d_in[10];
    const float* Wm0   = (const float*)d_in[11];
    const float* bm0   = (const float*)d_in[12];
    const float* gm    = (const float*)d_in[13];
    const float* bm    = (const float*)d_in[14];
    const float* Wm1   = (const float*)d_in[15];
    const float* bm1   = (const float*)d_in[16];
    const float* Wfc1  = (const float*)d_in[17];
    const float* bfc1  = (const float*)d_in[18];
    const float* Wfc2  = (const float*)d_in[19];
    const float* bfc2  = (const float*)d_in[20];
    const float* protos= (const float*)d_in[21];
    const float* Wlast = (const float*)d_in[22];
    const int* src = ei;
    const int* dst = ei + NE;
    float* out = (float*)d_out;

    float* ws   = (float*)d_ws;
    float* agg  = ws;                               // N*128
    float* tA   = agg + (size_t)NND * DIM;          // N*128
    float* tB   = tA + (size_t)NND * DIM;           // N*128
    float* t5   = tB + (size_t)NND * DIM;           // N*64
    float* lam  = t5 + (size_t)NND * HID;           // N*2
    float* assn = lam + (size_t)NND * 2;            // N*2
    float* cs   = assn + (size_t)NND * 2;           // 1024 (4 stat segments)
    float* kpart= cs + 1024;                        // NOISY_BLOCKS*2
    float* adjp = kpart + NOISY_BLOCKS * 2;         // ADJ_BLOCKS*4
    float* sscr = adjp + ADJ_BLOCKS * 4;            // 313*256 stats partials
    float* gpart= sscr + 313 * 256;                 // NG*EMB_SPLIT*DIM
    int* ib     = (int*)(gpart + NG * EMB_SPLIT * DIM);  // int region
    int* deg    = ib;                               // N
    int* offv   = deg + NND;                        // N+1
    int* cursor = offv + NND + 1;                   // N
    int* elist  = cursor + NND;                     // E
    int* gstart = elist + NE;                       // NG+1
    int* bsum   = gstart + NG + 1;                  // NSCB
    int* boff   = bsum + NSCB;                      // NSCB

    // threefry keys on host: key(42) = (0,42); partitionable fold-like split
    uint32_t kg0 = 0u, kg1 = 0u; threefry2x32(0u, 42u, kg0, kg1);  // ctr (0,0)
    uint32_t kn0 = 0u, kn1 = 1u; threefry2x32(0u, 42u, kn0, kn1);  // ctr (0,1)

    hipMemsetAsync(deg, 0, NND * sizeof(int), stream);

    // CSR (shared by both GIN layers)
    hist_kernel<<<(NE + 255) / 256, 256, 0, stream>>>(dst, deg);
    scan_bsum_kernel<<<NSCB, 256, 0, stream>>>(deg, bsum);
    scan_boff_kernel<<<1, 256, 0, stream>>>(bsum, boff, offv);
    scan_final_kernel<<<NSCB, 256, 0, stream>>>(deg, boff, offv, cursor);
    build_kernel<<<(NE + 255) / 256, 256, 0, stream>>>(src, dst, cursor, elist);

    const int GR = (NND + 127) / 128;   // 313 row blocks
    dim3 g2(GR, 2), g1x(GR, 1);

    // GIN layer 1 (gather folds in self term)
    gather_kernel<<<(NND * 32) / 256, 256, 0, stream>>>(x, offv, elist, agg);
    gemm_kernel<128,128,1,0><<<g2, 128, 0, stream>>>(agg, W0a, nullptr, tB, nullptr, NND);
    gemm_kernel<128,128,1,1><<<g2, 128, 0, stream>>>(tB, W0b, nullptr, tA, sscr, NND);
    stats_reduce_kernel<128><<<32, 256, 0, stream>>>(sscr, GR, cs + 0);
    bn_apply_kernel<128,1><<<5000, 256, 0, stream>>>(tA, cs + 0, g0, b0);      // nf1

    // GIN layer 2
    gather_kernel<<<(NND * 32) / 256, 256, 0, stream>>>(tA, offv, elist, agg);
    gemm_kernel<128,128,1,0><<<g2, 128, 0, stream>>>(agg, W1a, nullptr, tB, nullptr, NND);
    gemm_kernel<128,128,1,1><<<g2, 128, 0, stream>>>(tB, W1b, nullptr, tA, sscr, NND);
    stats_reduce_kernel<128><<<32, 256, 0, stream>>>(sscr, GR, cs + 256);
    bn_apply_kernel<128,0><<<5000, 256, 0, stream>>>(tA, cs + 256, g1, b1);    // nf2

    // bottleneck MLP
    gemm_kernel<128,64,0,1><<<g1x, 128, 0, stream>>>(tA, Wm0, bm0, t5, sscr, NND);
    stats_reduce_kernel<64><<<16, 256, 0, stream>>>(sscr, GR, cs + 512);
    bn_apply_kernel<64,1><<<2500, 256, 0, stream>>>(t5, cs + 512, gm, bm);     // h
    gemm_kernel<64,128,0,1><<<g2, 128, 0, stream>>>(t5, Wm1, bm1, agg, sscr, NND); // node_feature
    stats_reduce_kernel<128><<<32, 256, 0, stream>>>(sscr, GR, cs + 640);
    gemm_kernel<128,128,2,0><<<g2, 128, 0, stream>>>(agg, Wfc1, bfc1, tB, nullptr, NND); // a1

    // assignment + gumbel
    assign_kernel<<<(NND + 255) / 256, 256, 0, stream>>>(tB, Wfc2, bfc2, assn, lam, kg0, kg1);

    // noisy features (into tA) + kl partials
    noisy_kernel<<<NOISY_BLOCKS, 256, 0, stream>>>(agg, lam, cs + 640, tA, kpart, kn0, kn1);

    // graph pooling + head
    gstart_kernel<<<(NND + 255) / 256, 256, 0, stream>>>(batch, gstart);
    graph_emb_part_kernel<<<NG * EMB_SPLIT, 128, 0, stream>>>(tA, gstart, gpart);
    graph_emb_reduce_kernel<<<NG, 128, 0, stream>>>(gpart, gstart, out + 512);
    head_kernel<<<NG, 64, 0, stream>>>(out + 512, protos, Wlast,
                                       out, out + 256, out + 16898, out + 18178);

    // penalties
    adj_kernel<<<ADJ_BLOCKS, 256, 0, stream>>>(assn, src, dst, adjp);
    final_scalar_kernel<<<1, 256, 0, stream>>>(kpart, adjp, out);
}

// Round 9
// 474.000 us; speedup vs baseline: 1.8808x; 1.0317x over previous
//
#include <hip/hip_runtime.h>
#include <hip/hip_bf16.h>
#include <stdint.h>

#define NND 40000
#define NE  640000
#define NG  128
#define DIM 128
#define HID 64
#define ADJ_BLOCKS 640
#define NOISY_BLOCKS 5000   // NND*32/256
#define NSCB ((NND + 255) / 256)   // 157 scan blocks
#define EMB_SPLIT 8

// ---------------- threefry2x32 (20 rounds), JAX-compatible ----------------
__host__ __device__ inline uint32_t rotl32(uint32_t v, uint32_t r) {
    return (v << r) | (v >> (32u - r));
}

__host__ __device__ inline void threefry2x32(uint32_t k0, uint32_t k1,
                                             uint32_t& x0, uint32_t& x1) {
    uint32_t k2 = k0 ^ k1 ^ 0x1BD11BDAu;
    x0 += k0; x1 += k1;
#define TFR(r) { x0 += x1; x1 = rotl32(x1, r); x1 ^= x0; }
    TFR(13u) TFR(15u) TFR(26u) TFR(6u)
    x0 += k1; x1 += k2 + 1u;
    TFR(17u) TFR(29u) TFR(16u) TFR(24u)
    x0 += k2; x1 += k0 + 2u;
    TFR(13u) TFR(15u) TFR(26u) TFR(6u)
    x0 += k0; x1 += k1 + 3u;
    TFR(17u) TFR(29u) TFR(16u) TFR(24u)
    x0 += k1; x1 += k2 + 4u;
    TFR(13u) TFR(15u) TFR(26u) TFR(6u)
    x0 += k2; x1 += k0 + 5u;
#undef TFR
}

// partitionable-mode random bits -> uniform [0,1)
__device__ inline float rbits_u01(uint32_t k0, uint32_t k1, uint32_t idx) {
    uint32_t x0 = 0u, x1 = idx;
    threefry2x32(k0, k1, x0, x1);
    uint32_t b = x0 ^ x1;
    return __uint_as_float((b >> 9) | 0x3f800000u) - 1.0f;
}

__device__ inline uint32_t bfpack(float a, float b) {
    __hip_bfloat16 ha = __float2bfloat16(a), hb = __float2bfloat16(b);
    uint16_t ua = *(uint16_t*)&ha, ub = *(uint16_t*)&hb;
    return (uint32_t)ua | ((uint32_t)ub << 16);
}

__device__ inline float4 bf4_to_f4(ushort4 v) {
    return make_float4(__uint_as_float((uint32_t)v.x << 16),
                       __uint_as_float((uint32_t)v.y << 16),
                       __uint_as_float((uint32_t)v.z << 16),
                       __uint_as_float((uint32_t)v.w << 16));
}

// ---------------- CSR build ----------------
__global__ __launch_bounds__(256) void hist_kernel(const int* __restrict__ dst,
                                                   int* __restrict__ deg) {
    int e = blockIdx.x * 256 + threadIdx.x;
    if (e < NE) atomicAdd(&deg[dst[e]], 1);
}

__global__ __launch_bounds__(256) void scan_bsum_kernel(const int* __restrict__ deg,
                                                        int* __restrict__ bsum) {
    int t = threadIdx.x;
    int i = blockIdx.x * 256 + t;
    int v = (i < NND) ? deg[i] : 0;
    __shared__ int sh[256];
    sh[t] = v;
    __syncthreads();
#pragma unroll
    for (int s = 128; s > 0; s >>= 1) {
        if (t < s) sh[t] += sh[t + s];
        __syncthreads();
    }
    if (t == 0) bsum[blockIdx.x] = sh[0];
}

__global__ __launch_bounds__(256) void scan_boff_kernel(const int* __restrict__ bsum,
                                                        int* __restrict__ boff,
                                                        int* __restrict__ offv) {
    int t = threadIdx.x;
    int v = (t < NSCB) ? bsum[t] : 0;
    __shared__ int sh[256];
    sh[t] = v;
    __syncthreads();
    for (int d = 1; d < 256; d <<= 1) {
        int u = (t >= d) ? sh[t - d] : 0;
        __syncthreads();
        sh[t] += u;
        __syncthreads();
    }
    if (t < NSCB) boff[t] = sh[t] - v;   // exclusive
    if (t == NSCB - 1) offv[NND] = sh[t];
}

__global__ __launch_bounds__(256) void scan_final_kernel(const int* __restrict__ deg,
                                                         const int* __restrict__ boff,
                                                         int* __restrict__ offv,
                                                         int* __restrict__ cursor) {
    int t = threadIdx.x;
    int i = blockIdx.x * 256 + t;
    int v = (i < NND) ? deg[i] : 0;
    __shared__ int sh[256];
    sh[t] = v;
    __syncthreads();
    for (int d = 1; d < 256; d <<= 1) {
        int u = (t >= d) ? sh[t - d] : 0;
        __syncthreads();
        sh[t] += u;
        __syncthreads();
    }
    int off = boff[blockIdx.x] + sh[t] - v;   // exclusive prefix
    if (i < NND) { offv[i] = off; cursor[i] = off; }
}

__global__ __launch_bounds__(256) void build_kernel(const int* __restrict__ src,
                                                    const int* __restrict__ dst,
                                                    int* __restrict__ cursor,
                                                    int* __restrict__ elist) {
    int e = blockIdx.x * 256 + threadIdx.x;
    if (e < NE) {
        int p = atomicAdd(&cursor[dst[e]], 1);
        elist[p] = src[e];
    }
}

// ---------------- f32 -> bf16 converts ----------------
// plain convert (for x)
__global__ __launch_bounds__(256) void cvt_kernel(const float* __restrict__ in,
                                                  ushort* __restrict__ outh) {
    int i = blockIdx.x * 256 + threadIdx.x;    // per 8 elements
    if (i >= NND * DIM / 8) return;
    const float4* p = (const float4*)in + (size_t)i * 2;
    float4 a = p[0], b = p[1];
    uint4 o;
    o.x = bfpack(a.x, a.y); o.y = bfpack(a.z, a.w);
    o.z = bfpack(b.x, b.y); o.w = bfpack(b.z, b.w);
    *(uint4*)(outh + (size_t)i * 8) = o;
}

// affine (BN scale/shift) + relu + convert (for nf1)
__global__ __launch_bounds__(256) void cvt_affine_kernel(const float* __restrict__ in,
                                                         const float* __restrict__ cs,
                                                         ushort* __restrict__ outh) {
    int i = blockIdx.x * 256 + threadIdx.x;    // per 8 elements
    if (i >= NND * DIM / 8) return;
    int c = (i * 8) % DIM;
    float4 sc0 = *(const float4*)(cs + c), sc1 = *(const float4*)(cs + c + 4);
    float4 sh0 = *(const float4*)(cs + DIM + c), sh1 = *(const float4*)(cs + DIM + c + 4);
    const float4* p = (const float4*)in + (size_t)i * 2;
    float4 a = p[0], b = p[1];
    a.x = fmaxf(fmaf(a.x, sc0.x, sh0.x), 0.f); a.y = fmaxf(fmaf(a.y, sc0.y, sh0.y), 0.f);
    a.z = fmaxf(fmaf(a.z, sc0.z, sh0.z), 0.f); a.w = fmaxf(fmaf(a.w, sc0.w, sh0.w), 0.f);
    b.x = fmaxf(fmaf(b.x, sc1.x, sh1.x), 0.f); b.y = fmaxf(fmaf(b.y, sc1.y, sh1.y), 0.f);
    b.z = fmaxf(fmaf(b.z, sc1.z, sh1.z), 0.f); b.w = fmaxf(fmaf(b.w, sc1.w, sh1.w), 0.f);
    uint4 o;
    o.x = bfpack(a.x, a.y); o.y = bfpack(a.z, a.w);
    o.z = bfpack(b.x, b.y); o.w = bfpack(b.z, b.w);
    *(uint4*)(outh + (size_t)i * 8) = o;
}

// agg[n] = feat[n] + sum over in-edges of feat[src]; bf16 source, f32 accumulate
__global__ __launch_bounds__(256) void gather_kernel(const ushort* __restrict__ feath,
                                                     const int* __restrict__ offv,
                                                     const int* __restrict__ elist,
                                                     float* __restrict__ agg) {
    int gt = blockIdx.x * 256 + threadIdx.x;
    int n = gt >> 5, c4 = gt & 31;
    const ushort4* F = (const ushort4*)feath;
    int o0 = offv[n], o1 = offv[n + 1];
    float4 acc = bf4_to_f4(F[(size_t)n * 32 + c4]);   // self term
    for (int i = o0; i < o1; i++) {
        int s = elist[i];
        float4 v = bf4_to_f4(F[(size_t)s * 32 + c4]);
        acc.x += v.x; acc.y += v.y; acc.z += v.z; acc.w += v.w;
    }
    *(float4*)(agg + (size_t)n * DIM + c4 * 4) = acc;
}

// ---------------- fused GEMM v5: 128 threads, 128 rows x 64 cols per block,
// 8x8 thread tile, W col-slice in LDS (split halves, conflict-free), A global with
// 2-deep prefetch. PRE: 0=none, 1=affine(scale,shift on A cols), 2=affine+relu.
// ACT (on output): 0=none,1=relu,2=tanh. STATS: per-row-block col sum/sumsq.
#define GEMM_COMPUTE(buf, kcv)                                               \
    if (PRE > 0) {                                                           \
        float4 sc_ = *(const float4*)(pscale + (kcv) * 4);                   \
        float4 sf_ = *(const float4*)(pshift + (kcv) * 4);                   \
        _Pragma("unroll")                                                    \
        for (int i = 0; i < 8; i++) {                                        \
            buf[i].x = fmaf(buf[i].x, sc_.x, sf_.x);                         \
            buf[i].y = fmaf(buf[i].y, sc_.y, sf_.y);                         \
            buf[i].z = fmaf(buf[i].z, sc_.z, sf_.z);                         \
            buf[i].w = fmaf(buf[i].w, sc_.w, sf_.w);                         \
            if (PRE == 2) {                                                  \
                buf[i].x = fmaxf(buf[i].x, 0.f); buf[i].y = fmaxf(buf[i].y, 0.f); \
                buf[i].z = fmaxf(buf[i].z, 0.f); buf[i].w = fmaxf(buf[i].w, 0.f); \
            }                                                                \
        }                                                                    \
    }                                                                        \
    _Pragma("unroll")                                                        \
    for (int kk = 0; kk < 4; kk++) {                                         \
        int k_ = (kcv) * 4 + kk;                                             \
        float4 wA = *(const float4*)(sWa + k_ * 32 + cg * 4);                \
        float4 wB = *(const float4*)(sWb + k_ * 32 + cg * 4);                \
        float wv[8] = {wA.x, wA.y, wA.z, wA.w, wB.x, wB.y, wB.z, wB.w};      \
        _Pragma("unroll")                                                    \
        for (int i = 0; i < 8; i++) {                                        \
            float av = ((const float*)&buf[i])[kk];                          \
            _Pragma("unroll")                                                \
            for (int j = 0; j < 8; j++)                                      \
                acc[i][j] = fmaf(av, wv[j], acc[i][j]);                      \
        }                                                                    \
    }

template <int K, int M, int ACT, int STATS, int PRE>
__global__ __launch_bounds__(128, 2) void gemm_kernel(const float* __restrict__ A,
                                                      const float* __restrict__ W,
                                                      const float* __restrict__ bias,
                                                      float* __restrict__ out,
                                                      float* __restrict__ sscr,
                                                      const float* __restrict__ pscale,
                                                      const float* __restrict__ pshift,
                                                      int nrows) {
    constexpr int K4 = K / 4;
    __shared__ __align__(16) float sWa[K * 32];
    __shared__ __align__(16) float sWb[K * 32];

    const int t = threadIdx.x;
    const int cg = t & 7;         // 0..7 (8 cols each)
    const int rg = t >> 3;        // 0..15 (8 rows each)
    const int col0 = blockIdx.y * 64;
    const int row0 = blockIdx.x * 128;

    for (int i = t; i < K * 16; i += 128) {
        int k = i >> 4, c4 = i & 15;
        float4 v = *(const float4*)(W + (size_t)k * M + col0 + c4 * 4);
        float* d = ((c4 & 1) ? sWb : sWa) + k * 32 + (c4 >> 1) * 4;
        *(float4*)d = v;
    }
    __syncthreads();

    size_t roff[8];
#pragma unroll
    for (int i = 0; i < 8; i++) {
        int gr = row0 + rg * 8 + i;
        roff[i] = (size_t)min(gr, nrows - 1) * K4;
    }

    float acc[8][8];
#pragma unroll
    for (int i = 0; i < 8; i++)
#pragma unroll
        for (int j = 0; j < 8; j++) acc[i][j] = 0.f;

    const float4* A4 = (const float4*)A;
    float4 pa[8], pb[8];
#pragma unroll
    for (int i = 0; i < 8; i++) pa[i] = A4[roff[i]];

    for (int kc = 0; kc < K4; kc += 2) {
#pragma unroll
        for (int i = 0; i < 8; i++) pb[i] = A4[roff[i] + kc + 1];
        GEMM_COMPUTE(pa, kc)
        if (kc + 2 < K4) {
#pragma unroll
            for (int i = 0; i < 8; i++) pa[i] = A4[roff[i] + kc + 2];
        }
        GEMM_COMPUTE(pb, kc + 1)
    }

    float bv[8];
#pragma unroll
    for (int j = 0; j < 8; j++) bv[j] = bias ? bias[col0 + cg * 8 + j] : 0.f;

    float ps[8], pq[8];
#pragma unroll
    for (int j = 0; j < 8; j++) { ps[j] = 0.f; pq[j] = 0.f; }

#pragma unroll
    for (int i = 0; i < 8; i++) {
        int gr = row0 + rg * 8 + i;
        if (gr < nrows) {
            float o[8];
#pragma unroll
            for (int j = 0; j < 8; j++) {
                float v = acc[i][j] + bv[j];
                if (ACT == 1) v = fmaxf(v, 0.f);
                if (ACT == 2) v = tanhf(v);
                o[j] = v;
                ps[j] += v; pq[j] += v * v;
            }
            float4* o4 = (float4*)(out + (size_t)gr * M + col0 + cg * 8);
            o4[0] = make_float4(o[0], o[1], o[2], o[3]);
            o4[1] = make_float4(o[4], o[5], o[6], o[7]);
        }
    }

    if (STATS) {
        __syncthreads();
#pragma unroll
        for (int j = 0; j < 8; j++) {
            sWa[rg * 64 + cg * 8 + j] = ps[j];
            sWb[rg * 64 + cg * 8 + j] = pq[j];
        }
        __syncthreads();
        if (t < 64) {
            float s = 0.f, q = 0.f;
#pragma unroll
            for (int i = 0; i < 16; i++) { s += sWa[i * 64 + t]; q += sWb[i * 64 + t]; }
            sscr[(size_t)blockIdx.x * 2 * M + col0 + t]     = s;
            sscr[(size_t)blockIdx.x * 2 * M + M + col0 + t] = q;
        }
    }
}

// reduce stats partials; affine=1: write (scale, shift) from (g,b); else raw (sum,sumsq).
// grid = M/8 blocks x 256 threads.
template <int M>
__global__ __launch_bounds__(256) void stats_reduce_kernel(const float* __restrict__ sscr,
                                                           int nblk,
                                                           const float* __restrict__ g,
                                                           const float* __restrict__ b,
                                                           float* __restrict__ cs,
                                                           int affine) {
    const int cols = 2 * M;
    const int t = threadIdx.x;
    const int c = blockIdx.x * 8 + (t & 7);
    const int rl = t >> 3;
    float s = 0.f, q = 0.f;
    for (int r = rl; r < nblk; r += 32) {
        s += sscr[(size_t)r * cols + c];
        q += sscr[(size_t)r * cols + M + c];
    }
    __shared__ float shs[256], shq[256];
    shs[t] = s; shq[t] = q;
    __syncthreads();
#pragma unroll
    for (int st = 128; st >= 8; st >>= 1) {
        if (t < st) { shs[t] += shs[t + st]; shq[t] += shq[t + st]; }
        __syncthreads();
    }
    if (t < 8) {
        float ss = shs[t], qq = shq[t];
        if (affine) {
            const float invN = 1.0f / (float)NND;
            float mu = ss * invN;
            float var = fmaxf(qq * invN - mu * mu, 0.f);
            float sc = g[c] * rsqrtf(var + 1e-5f);
            cs[c] = sc;
            cs[M + c] = b[c] - mu * sc;
        } else {
            cs[c] = ss;
            cs[M + c] = qq;
        }
    }
}

// ---------------- assignment / gumbel-softmax lambdas ----------------
__global__ __launch_bounds__(256) void assign_kernel(const float* __restrict__ a1,
                                                     const float* __restrict__ Wfc2,
                                                     const float* __restrict__ bfc2,
                                                     float* __restrict__ assn,
                                                     float* __restrict__ lam,
                                                     uint32_t kg0, uint32_t kg1) {
    __shared__ float w[DIM * 2];
    int t = threadIdx.x;
    w[t] = Wfc2[t];
    __syncthreads();
    int n = blockIdx.x * 256 + t;
    if (n >= NND) return;

    float d0 = bfc2[0], d1 = bfc2[1];
    const float4* row4 = (const float4*)(a1 + (size_t)n * DIM);
#pragma unroll 8
    for (int k4 = 0; k4 < DIM / 4; k4++) {
        float4 v = row4[k4];
        d0 = fmaf(v.x, w[8 * k4 + 0], d0); d1 = fmaf(v.x, w[8 * k4 + 1], d1);
        d0 = fmaf(v.y, w[8 * k4 + 2], d0); d1 = fmaf(v.y, w[8 * k4 + 3], d1);
        d0 = fmaf(v.z, w[8 * k4 + 4], d0); d1 = fmaf(v.z, w[8 * k4 + 5], d1);
        d0 = fmaf(v.w, w[8 * k4 + 6], d0); d1 = fmaf(v.w, w[8 * k4 + 7], d1);
    }
    float m = fmaxf(d0, d1);
    float e0 = expf(d0 - m), e1 = expf(d1 - m);
    float inv = 1.f / (e0 + e1);
    float as0 = e0 * inv, as1 = e1 * inv;
    assn[2 * n] = as0; assn[2 * n + 1] = as1;

    float uf0 = rbits_u01(kg0, kg1, (uint32_t)(2 * n));
    float uf1 = rbits_u01(kg0, kg1, (uint32_t)(2 * n + 1));
    float u0 = fmaxf(1e-10f, uf0 + 1e-10f);
    float u1 = fmaxf(1e-10f, uf1 + 1e-10f);
    float gu0 = -logf(-logf(u0));
    float gu1 = -logf(-logf(u1));
    float y0 = as0 + gu0, y1 = as1 + gu1;
    float mm = fmaxf(y0, y1);
    float f0 = expf(y0 - mm), f1 = expf(y1 - mm);
    float iv = 1.f / (f0 + f1);
    lam[2 * n] = f0 * iv; lam[2 * n + 1] = f1 * iv;
}

// ---------------- noisy features + kl partial sums ----------------
__global__ __launch_bounds__(256) void noisy_kernel(const float* __restrict__ nfeat,
                                                    const float* __restrict__ lam,
                                                    const float* __restrict__ cs3,
                                                    float* __restrict__ noisy,
                                                    float* __restrict__ kpart,
                                                    uint32_t kn0, uint32_t kn1) {
    int gt = blockIdx.x * 256 + threadIdx.x;
    int n = gt >> 5, c4 = gt & 31, d = c4 * 4;
    const float invN = 1.0f / (float)NND;
    float la0 = lam[2 * n], la1 = lam[2 * n + 1];
    float4 xv = *(const float4*)(nfeat + (size_t)n * DIM + d);
    float xa[4] = {xv.x, xv.y, xv.z, xv.w};
    float t1 = 0.f, t2 = 0.f, o[4];
#pragma unroll
    for (int j = 0; j < 4; j++) {
        float mu = cs3[d + j] * invN;
        float q = cs3[DIM + d + j];
        float var1 = fmaxf(q - (float)NND * mu * mu, 0.f) / (float)(NND - 1);
        float sd = sqrtf(var1);
        float r = rbits_u01(kn0, kn1, (uint32_t)(n * DIM + d + j));
        float nm = la0 * xa[j] + la1 * mu;
        float ns = la1 * sd;
        o[j] = fmaf(r, ns, nm);
        float inv = 1.0f / (sd + 1e-7f);
        float z1 = ns * inv;            t1 += z1 * z1;
        float z2 = (nm - mu) * inv;     t2 += z2 * z2;
    }
    *(float4*)(noisy + (size_t)n * DIM + d) = make_float4(o[0], o[1], o[2], o[3]);

    __shared__ float s1[256], s2[256];
    int t = threadIdx.x;
    s1[t] = t1; s2[t] = t2;
    __syncthreads();
    for (int s = 128; s > 0; s >>= 1) {
        if (t < s) { s1[t] += s1[t + s]; s2[t] += s2[t + s]; }
        __syncthreads();
    }
    if (t == 0) { kpart[2 * blockIdx.x] = s1[0]; kpart[2 * blockIdx.x + 1] = s2[0]; }
}

// ---------------- graph segment starts (batch is sorted) ----------------
__global__ __launch_bounds__(256) void gstart_kernel(const int* __restrict__ batch,
                                                     int* __restrict__ gstart) {
    int i = blockIdx.x * 256 + threadIdx.x;
    if (i >= NND) return;
    int b = batch[i];
    int prev = (i == 0) ? -1 : batch[i - 1];
    for (int g = prev + 1; g <= b; g++) gstart[g] = i;
    if (i == NND - 1)
        for (int g = b + 1; g <= NG; g++) gstart[g] = NND;
}

// ---------------- graph mean pooling ----------------
__global__ __launch_bounds__(128) void graph_emb_part_kernel(const float* __restrict__ noisy,
                                                             const int* __restrict__ gstart,
                                                             float* __restrict__ gpart) {
    int g = blockIdx.x / EMB_SPLIT;
    int sidx = blockIdx.x % EMB_SPLIT;
    int c = threadIdx.x;
    int s = gstart[g], e = gstart[g + 1];
    int len = e - s;
    int chunk = (len + EMB_SPLIT - 1) / EMB_SPLIT;
    int r0 = s + sidx * chunk;
    int r1 = min(r0 + chunk, e);
    float acc = 0.f;
    for (int r = r0; r < r1; r++) acc += noisy[(size_t)r * DIM + c];
    gpart[((size_t)g * EMB_SPLIT + sidx) * DIM + c] = acc;
}

__global__ __launch_bounds__(128) void graph_emb_reduce_kernel(const float* __restrict__ gpart,
                                                               const int* __restrict__ gstart,
                                                               float* __restrict__ emb) {
    int g = blockIdx.x, c = threadIdx.x;
    float acc = 0.f;
#pragma unroll
    for (int si = 0; si < EMB_SPLIT; si++)
        acc += gpart[((size_t)g * EMB_SPLIT + si) * DIM + c];
    float cnt = (float)(gstart[g + 1] - gstart[g]);
    emb[(size_t)g * DIM + c] = acc / fmaxf(cnt, 1.f);
}

// ---------------- proto distances + final head ----------------
__global__ __launch_bounds__(64) void head_kernel(const float* __restrict__ emb,
                                                  const float* __restrict__ protos,
                                                  const float* __restrict__ Wlast,
                                                  float* __restrict__ out_logits,
                                                  float* __restrict__ out_probs,
                                                  float* __restrict__ out_sim,
                                                  float* __restrict__ out_dist) {
    int g = blockIdx.x, l = threadIdx.x;
    float ge0 = emb[(size_t)g * DIM + l];
    float ge1 = emb[(size_t)g * DIM + l + 64];
    float gn = ge0 * ge0 + ge1 * ge1;
    float dj[10], pj[10];
#pragma unroll
    for (int j = 0; j < 10; j++) {
        float pa = protos[j * DIM + l], pb = protos[j * DIM + l + 64];
        dj[j] = ge0 * pa + ge1 * pb;
        pj[j] = pa * pa + pb * pb;
    }
    float wl0 = ge0 * Wlast[10 + l] + ge1 * Wlast[10 + l + 64];
    float wl1 = ge0 * Wlast[138 + 10 + l] + ge1 * Wlast[138 + 10 + l + 64];
#pragma unroll
    for (int s = 32; s > 0; s >>= 1) {
        gn += __shfl_xor(gn, s);
        wl0 += __shfl_xor(wl0, s);
        wl1 += __shfl_xor(wl1, s);
#pragma unroll
        for (int j = 0; j < 10; j++) {
            dj[j] += __shfl_xor(dj[j], s);
            pj[j] += __shfl_xor(pj[j], s);
        }
    }
    if (l == 0) {
        float lg0 = wl0, lg1 = wl1;
#pragma unroll
        for (int j = 0; j < 10; j++) {
            float dist = -2.f * dj[j] + gn + pj[j];
            float sv = logf((dist + 1.0f) / (dist + 1e-4f));
            out_dist[g * 10 + j] = dist;
            out_sim[g * 10 + j] = sv;
            lg0 = fmaf(Wlast[j], sv, lg0);
            lg1 = fmaf(Wlast[138 + j], sv, lg1);
        }
        out_logits[2 * g] = lg0; out_logits[2 * g + 1] = lg1;
        float m = fmaxf(lg0, lg1);
        float e0 = expf(lg0 - m), e1 = expf(lg1 - m);
        float iv = 1.f / (e0 + e1);
        out_probs[2 * g] = e0 * iv; out_probs[2 * g + 1] = e1 * iv;
    }
}

// ---------------- 2x2 adjacency accumulation ----------------
__global__ __launch_bounds__(256) void adj_kernel(const float* __restrict__ assn,
                                                  const int* __restrict__ src,
                                                  const int* __restrict__ dst,
                                                  float* __restrict__ adjp) {
    int t = threadIdx.x;
    float p00 = 0.f, p01 = 0.f, p10 = 0.f, p11 = 0.f;
    for (int e = blockIdx.x * 256 + t; e < NE; e += ADJ_BLOCKS * 256) {
        float2 a = *(const float2*)(assn + 2 * (size_t)src[e]);
        float2 b = *(const float2*)(assn + 2 * (size_t)dst[e]);
        p00 += a.x * b.x; p01 += a.x * b.y; p10 += a.y * b.x; p11 += a.y * b.y;
    }
    __shared__ float s0[256], s1[256], s2[256], s3[256];
    s0[t] = p00; s1[t] = p01; s2[t] = p10; s3[t] = p11;
    __syncthreads();
    for (int s = 128; s > 0; s >>= 1) {
        if (t < s) { s0[t] += s0[t + s]; s1[t] += s1[t + s]; s2[t] += s2[t + s]; s3[t] += s3[t + s]; }
        __syncthreads();
    }
    if (t == 0) {
        float4* o = (float4*)(adjp + 4 * (size_t)blockIdx.x);
        *o = make_float4(s0[0], s1[0], s2[0], s3[0]);
    }
}

// ---------------- final scalars ----------------
__global__ __launch_bounds__(256) void final_scalar_kernel(const float* __restrict__ kpart,
                                                           const float* __restrict__ adjp,
                                                           float* __restrict__ out) {
    __shared__ float sh[6 * 256];
    int t = threadIdx.x;
    float k1 = 0.f, k2 = 0.f, a0 = 0.f, a1 = 0.f, a2 = 0.f, a3 = 0.f;
    for (int i = t; i < NOISY_BLOCKS; i += 256) {
        float2 v = ((const float2*)kpart)[i];
        k1 += v.x; k2 += v.y;
    }
    for (int i = t; i < ADJ_BLOCKS; i += 256) {
        float4 v = ((const float4*)adjp)[i];
        a0 += v.x; a1 += v.y; a2 += v.z; a3 += v.w;
    }
    sh[t] = k1; sh[256 + t] = k2; sh[512 + t] = a0;
    sh[768 + t] = a1; sh[1024 + t] = a2; sh[1280 + t] = a3;
    __syncthreads();
    for (int s = 128; s > 0; s >>= 1) {
        if (t < s) {
#pragma unroll
            for (int v = 0; v < 6; v++) sh[v * 256 + t] += sh[v * 256 + t + s];
        }
        __syncthreads();
    }
    if (t == 0) {
        float kl = 0.5f / ((float)NND * (float)DIM) * sh[0] + (1.0f / (float)DIM) * sh[256];
        out[16896] = kl;
        float a00 = sh[512], a01 = sh[768], a10 = sh[1024], a11 = sh[1280];
        float r0 = fmaxf(fabsf(a00) + fabsf(a01), 1e-12f);
        float r1 = fmaxf(fabsf(a10) + fabsf(a11), 1e-12f);
        float d0 = a00 / r0 - 1.f, d1 = a11 / r1 - 1.f;
        out[16897] = 0.5f * (d0 * d0 + d1 * d1);
    }
}

// ---------------- launcher ----------------
extern "C" void kernel_launch(void* const* d_in, const int* in_sizes, int n_in,
                              void* d_out, int out_size, void* d_ws, size_t ws_size,
                              hipStream_t stream) {
    (void)in_sizes; (void)n_in; (void)out_size; (void)ws_size;
    const float* x     = (const float*)d_in[0];
    const int*   ei    = (const int*)d_in[1];
    const int*   batch = (const int*)d_in[2];
    const float* W0a   = (const float*)d_in[3];
    const float* W0b   = (const float*)d_in[4];
    const float* g0    = (const float*)d_in[5];
    const float* b0    = (const float*)d_in[6];
    const float* W1a   = (const float*)d_in[7];
    const float* W1b   = (const float*)d_in[8];
    const float* g1    = (const float*)d_in[9];
    const float* b1    = (const float*)d_in[10];
    const float* Wm0   = (const float*)d_in[11];
    const float* bm0   = (const float*)d_in[12];
    const float* gm    = (const float*)d_in[13];
    const float* bm    = (const float*)d_in[14];
    const float* Wm1   = (const float*)d_in[15];
    const float* bm1   = (const float*)d_in[16];
    const float* Wfc1  = (const float*)d_in[17];
    const float* bfc1  = (const float*)d_in[18];
    const float* Wfc2  = (const float*)d_in[19];
    const float* bfc2  = (const float*)d_in[20];
    const float* protos= (const float*)d_in[21];
    const float* Wlast = (const float*)d_in[22];
    const int* src = ei;
    const int* dst = ei + NE;
    float* out = (float*)d_out;

    float* ws   = (float*)d_ws;
    float* agg  = ws;                               // N*128
    float* tA   = agg + (size_t)NND * DIM;          // N*128
    float* tB   = tA + (size_t)NND * DIM;           // N*128 (also aliased as bf16 scratch)
    float* t5   = tB + (size_t)NND * DIM;           // N*64
    float* lam  = t5 + (size_t)NND * HID;           // N*2
    float* assn = lam + (size_t)NND * 2;            // N*2
    float* cs   = assn + (size_t)NND * 2;           // 1024 (4 segments of 256)
    float* kpart= cs + 1024;                        // NOISY_BLOCKS*2
    float* adjp = kpart + NOISY_BLOCKS * 2;         // ADJ_BLOCKS*4
    float* sscr = adjp + ADJ_BLOCKS * 4;            // 313*256 stats partials
    float* gpart= sscr + 313 * 256;                 // NG*EMB_SPLIT*DIM
    int* ib     = (int*)(gpart + NG * EMB_SPLIT * DIM);  // int region
    int* deg    = ib;                               // N
    int* offv   = deg + NND;                        // N+1
    int* cursor = offv + NND + 1;                   // N
    int* elist  = cursor + NND;                     // E
    int* gstart = elist + NE;                       // NG+1
    int* bsum   = gstart + NG + 1;                  // NSCB
    int* boff   = bsum + NSCB;                      // NSCB

    ushort* bfscr = (ushort*)tB;   // bf16 scratch aliases tB (dead intervals only)

    // threefry keys on host: key(42) = (0,42); partitionable fold-like split
    uint32_t kg0 = 0u, kg1 = 0u; threefry2x32(0u, 42u, kg0, kg1);  // ctr (0,0)
    uint32_t kn0 = 0u, kn1 = 1u; threefry2x32(0u, 42u, kn0, kn1);  // ctr (0,1)

    hipMemsetAsync(deg, 0, NND * sizeof(int), stream);

    // CSR (shared by both GIN layers)
    hist_kernel<<<(NE + 255) / 256, 256, 0, stream>>>(dst, deg);
    scan_bsum_kernel<<<NSCB, 256, 0, stream>>>(deg, bsum);
    scan_boff_kernel<<<1, 256, 0, stream>>>(bsum, boff, offv);
    scan_final_kernel<<<NSCB, 256, 0, stream>>>(deg, boff, offv, cursor);
    build_kernel<<<(NE + 255) / 256, 256, 0, stream>>>(src, dst, cursor, elist);

    const int GR = (NND + 127) / 128;   // 313 row blocks
    dim3 g2(GR, 2), g1x(GR, 1);
    const int CVB = (NND * DIM / 8 + 255) / 256;   // 2500 convert blocks

    // GIN layer 1: x -> bf16 (into tB scratch) -> gather -> two GEMMs
    cvt_kernel<<<CVB, 256, 0, stream>>>(x, bfscr);
    gather_kernel<<<(NND * 32) / 256, 256, 0, stream>>>(bfscr, offv, elist, agg);
    gemm_kernel<128,128,1,0,0><<<g2, 128, 0, stream>>>(agg, W0a, nullptr, tB, nullptr, nullptr, nullptr, NND);
    gemm_kernel<128,128,1,1,0><<<g2, 128, 0, stream>>>(tB, W0b, nullptr, tA, sscr, nullptr, nullptr, NND);
    stats_reduce_kernel<128><<<16, 256, 0, stream>>>(sscr, GR, g0, b0, cs + 0, 1);   // affine0

    // GIN layer 2: nf1 = relu(affine0(tA)) as bf16 (into tB scratch) -> gather -> GEMMs
    cvt_affine_kernel<<<CVB, 256, 0, stream>>>(tA, cs + 0, bfscr);
    gather_kernel<<<(NND * 32) / 256, 256, 0, stream>>>(bfscr, offv, elist, agg);
    gemm_kernel<128,128,1,0,0><<<g2, 128, 0, stream>>>(agg, W1a, nullptr, tB, nullptr, nullptr, nullptr, NND);
    gemm_kernel<128,128,1,1,0><<<g2, 128, 0, stream>>>(tB, W1b, nullptr, tA, sscr, nullptr, nullptr, NND);
    stats_reduce_kernel<128><<<16, 256, 0, stream>>>(sscr, GR, g1, b1, cs + 256, 1); // affine1

    // bottleneck MLP: affine1 folded into A-path (PRE=1); affine2+relu into gemm5 (PRE=2)
    gemm_kernel<128,64,0,1,1><<<g1x, 128, 0, stream>>>(tA, Wm0, bm0, t5, sscr, cs + 256, cs + 384, NND);
    stats_reduce_kernel<64><<<8, 256, 0, stream>>>(sscr, GR, gm, bm, cs + 512, 1);   // affine2
    gemm_kernel<64,128,0,1,2><<<g2, 128, 0, stream>>>(t5, Wm1, bm1, agg, sscr, cs + 512, cs + 576, NND); // node_feature
    stats_reduce_kernel<128><<<16, 256, 0, stream>>>(sscr, GR, nullptr, nullptr, cs + 640, 0); // raw sums
    gemm_kernel<128,128,2,0,0><<<g2, 128, 0, stream>>>(agg, Wfc1, bfc1, tB, nullptr, nullptr, nullptr, NND); // a1

    // assignment + gumbel
    assign_kernel<<<(NND + 255) / 256, 256, 0, stream>>>(tB, Wfc2, bfc2, assn, lam, kg0, kg1);

    // noisy features (into tA) + kl partials
    noisy_kernel<<<NOISY_BLOCKS, 256, 0, stream>>>(agg, lam, cs + 640, tA, kpart, kn0, kn1);

    // graph pooling + head
    gstart_kernel<<<(NND + 255) / 256, 256, 0, stream>>>(batch, gstart);
    graph_emb_part_kernel<<<NG * EMB_SPLIT, 128, 0, stream>>>(tA, gstart, gpart);
    graph_emb_reduce_kernel<<<NG, 128, 0, stream>>>(gpart, gstart, out + 512);
    head_kernel<<<NG, 64, 0, stream>>>(out + 512, protos, Wlast,
                                       out, out + 256, out + 16898, out + 18178);

    // penalties
    adj_kernel<<<ADJ_BLOCKS, 256, 0, stream>>>(assn, src, dst, adjp);
    final_scalar_kernel<<<1, 256, 0, stream>>>(kpart, adjp, out);
}

// Round 10
// 464.303 us; speedup vs baseline: 1.9201x; 1.0209x over previous
//
#include <hip/hip_runtime.h>
#include <hip/hip_bf16.h>
#include <stdint.h>

#define NND 40000
#define NE  640000
#define NG  128
#define DIM 128
#define HID 64
#define ADJ_BLOCKS 640
#define NOISY_BLOCKS 5000   // NND*32/256
#define NSCB ((NND + 255) / 256)   // 157 scan blocks
#define EMB_SPLIT 8
#define GRB 625              // gemm row blocks (64 rows each)

// ---------------- threefry2x32 (20 rounds), JAX-compatible ----------------
__host__ __device__ inline uint32_t rotl32(uint32_t v, uint32_t r) {
    return (v << r) | (v >> (32u - r));
}

__host__ __device__ inline void threefry2x32(uint32_t k0, uint32_t k1,
                                             uint32_t& x0, uint32_t& x1) {
    uint32_t k2 = k0 ^ k1 ^ 0x1BD11BDAu;
    x0 += k0; x1 += k1;
#define TFR(r) { x0 += x1; x1 = rotl32(x1, r); x1 ^= x0; }
    TFR(13u) TFR(15u) TFR(26u) TFR(6u)
    x0 += k1; x1 += k2 + 1u;
    TFR(17u) TFR(29u) TFR(16u) TFR(24u)
    x0 += k2; x1 += k0 + 2u;
    TFR(13u) TFR(15u) TFR(26u) TFR(6u)
    x0 += k0; x1 += k1 + 3u;
    TFR(17u) TFR(29u) TFR(16u) TFR(24u)
    x0 += k1; x1 += k2 + 4u;
    TFR(13u) TFR(15u) TFR(26u) TFR(6u)
    x0 += k2; x1 += k0 + 5u;
#undef TFR
}

// partitionable-mode random bits -> uniform [0,1)
__device__ inline float rbits_u01(uint32_t k0, uint32_t k1, uint32_t idx) {
    uint32_t x0 = 0u, x1 = idx;
    threefry2x32(k0, k1, x0, x1);
    uint32_t b = x0 ^ x1;
    return __uint_as_float((b >> 9) | 0x3f800000u) - 1.0f;
}

__device__ inline uint32_t bfpack(float a, float b) {
    __hip_bfloat16 ha = __float2bfloat16(a), hb = __float2bfloat16(b);
    uint16_t ua = *(uint16_t*)&ha, ub = *(uint16_t*)&hb;
    return (uint32_t)ua | ((uint32_t)ub << 16);
}

// unpack 8 bf16 (uint4) -> 8 f32
#define UNPACK8(v, f)                                                     \
    f[0] = __uint_as_float((v).x << 16); f[1] = __uint_as_float((v).x & 0xffff0000u); \
    f[2] = __uint_as_float((v).y << 16); f[3] = __uint_as_float((v).y & 0xffff0000u); \
    f[4] = __uint_as_float((v).z << 16); f[5] = __uint_as_float((v).z & 0xffff0000u); \
    f[6] = __uint_as_float((v).w << 16); f[7] = __uint_as_float((v).w & 0xffff0000u);

// ---------------- CSR build ----------------
__global__ __launch_bounds__(256) void hist_kernel(const int* __restrict__ dst,
                                                   int* __restrict__ deg) {
    int e = blockIdx.x * 256 + threadIdx.x;
    if (e < NE) atomicAdd(&deg[dst[e]], 1);
}

__global__ __launch_bounds__(256) void scan_bsum_kernel(const int* __restrict__ deg,
                                                        int* __restrict__ bsum) {
    int t = threadIdx.x;
    int i = blockIdx.x * 256 + t;
    int v = (i < NND) ? deg[i] : 0;
    __shared__ int sh[256];
    sh[t] = v;
    __syncthreads();
#pragma unroll
    for (int s = 128; s > 0; s >>= 1) {
        if (t < s) sh[t] += sh[t + s];
        __syncthreads();
    }
    if (t == 0) bsum[blockIdx.x] = sh[0];
}

__global__ __launch_bounds__(256) void scan_boff_kernel(const int* __restrict__ bsum,
                                                        int* __restrict__ boff,
                                                        int* __restrict__ offv) {
    int t = threadIdx.x;
    int v = (t < NSCB) ? bsum[t] : 0;
    __shared__ int sh[256];
    sh[t] = v;
    __syncthreads();
    for (int d = 1; d < 256; d <<= 1) {
        int u = (t >= d) ? sh[t - d] : 0;
        __syncthreads();
        sh[t] += u;
        __syncthreads();
    }
    if (t < NSCB) boff[t] = sh[t] - v;   // exclusive
    if (t == NSCB - 1) offv[NND] = sh[t];
}

__global__ __launch_bounds__(256) void scan_final_kernel(const int* __restrict__ deg,
                                                         const int* __restrict__ boff,
                                                         int* __restrict__ offv,
                                                         int* __restrict__ cursor) {
    int t = threadIdx.x;
    int i = blockIdx.x * 256 + t;
    int v = (i < NND) ? deg[i] : 0;
    __shared__ int sh[256];
    sh[t] = v;
    __syncthreads();
    for (int d = 1; d < 256; d <<= 1) {
        int u = (t >= d) ? sh[t - d] : 0;
        __syncthreads();
        sh[t] += u;
        __syncthreads();
    }
    int off = boff[blockIdx.x] + sh[t] - v;   // exclusive prefix
    if (i < NND) { offv[i] = off; cursor[i] = off; }
}

__global__ __launch_bounds__(256) void build_kernel(const int* __restrict__ src,
                                                    const int* __restrict__ dst,
                                                    int* __restrict__ cursor,
                                                    int* __restrict__ elist) {
    int e = blockIdx.x * 256 + threadIdx.x;
    if (e < NE) {
        int p = atomicAdd(&cursor[dst[e]], 1);
        elist[p] = src[e];
    }
}

// ---------------- f32 -> bf16 converts ----------------
__global__ __launch_bounds__(256) void cvt_kernel(const float* __restrict__ in,
                                                  ushort* __restrict__ outh) {
    int i = blockIdx.x * 256 + threadIdx.x;    // per 8 elements
    if (i >= NND * DIM / 8) return;
    const float4* p = (const float4*)in + (size_t)i * 2;
    float4 a = p[0], b = p[1];
    uint4 o;
    o.x = bfpack(a.x, a.y); o.y = bfpack(a.z, a.w);
    o.z = bfpack(b.x, b.y); o.w = bfpack(b.z, b.w);
    *(uint4*)(outh + (size_t)i * 8) = o;
}

__global__ __launch_bounds__(256) void cvt_affine_kernel(const float* __restrict__ in,
                                                         const float* __restrict__ cs,
                                                         ushort* __restrict__ outh) {
    int i = blockIdx.x * 256 + threadIdx.x;    // per 8 elements
    if (i >= NND * DIM / 8) return;
    int c = (i * 8) % DIM;
    float4 sc0 = *(const float4*)(cs + c), sc1 = *(const float4*)(cs + c + 4);
    float4 sh0 = *(const float4*)(cs + DIM + c), sh1 = *(const float4*)(cs + DIM + c + 4);
    const float4* p = (const float4*)in + (size_t)i * 2;
    float4 a = p[0], b = p[1];
    a.x = fmaxf(fmaf(a.x, sc0.x, sh0.x), 0.f); a.y = fmaxf(fmaf(a.y, sc0.y, sh0.y), 0.f);
    a.z = fmaxf(fmaf(a.z, sc0.z, sh0.z), 0.f); a.w = fmaxf(fmaf(a.w, sc0.w, sh0.w), 0.f);
    b.x = fmaxf(fmaf(b.x, sc1.x, sh1.x), 0.f); b.y = fmaxf(fmaf(b.y, sc1.y, sh1.y), 0.f);
    b.z = fmaxf(fmaf(b.z, sc1.z, sh1.z), 0.f); b.w = fmaxf(fmaf(b.w, sc1.w, sh1.w), 0.f);
    uint4 o;
    o.x = bfpack(a.x, a.y); o.y = bfpack(a.z, a.w);
    o.z = bfpack(b.x, b.y); o.w = bfpack(b.z, b.w);
    *(uint4*)(outh + (size_t)i * 8) = o;
}

// ---------------- gather v2: one wave per node, 4 edge-slots x 16 col-slots,
// 16B bf16 loads, f32 accumulate, shfl_xor reduce. agg = self + sum(neighbors).
__global__ __launch_bounds__(256) void gather_kernel(const ushort* __restrict__ feath,
                                                     const int* __restrict__ offv,
                                                     const int* __restrict__ elist,
                                                     float* __restrict__ agg) {
    int gt = blockIdx.x * 256 + threadIdx.x;
    int n = gt >> 6;                    // wave id = node (grid sized exactly)
    int lane = threadIdx.x & 63;
    int e = lane >> 4, c = lane & 15;   // edge slot, column slot (8 bf16)
    const uint4* F = (const uint4*)feath;
    int o0 = offv[n], o1 = offv[n + 1];

    float acc[8];
    if (e == 0) {                        // self term, counted once
        uint4 v = F[(size_t)n * 16 + c];
        UNPACK8(v, acc)
    } else {
#pragma unroll
        for (int j = 0; j < 8; j++) acc[j] = 0.f;
    }

    for (int i = o0 + e; i < o1; i += 4) {
        int s = elist[i];
        uint4 v = F[(size_t)s * 16 + c];
        float f[8];
        UNPACK8(v, f)
#pragma unroll
        for (int j = 0; j < 8; j++) acc[j] += f[j];
    }

#pragma unroll
    for (int j = 0; j < 8; j++) {
        acc[j] += __shfl_xor(acc[j], 16);
        acc[j] += __shfl_xor(acc[j], 32);
    }

    // each edge-slot group writes its float2 slice (static indexing)
    float2 w2;
    if (e == 0)      w2 = make_float2(acc[0], acc[1]);
    else if (e == 1) w2 = make_float2(acc[2], acc[3]);
    else if (e == 2) w2 = make_float2(acc[4], acc[5]);
    else             w2 = make_float2(acc[6], acc[7]);
    *(float2*)(agg + (size_t)n * DIM + c * 8 + e * 2) = w2;
}

// ---------------- fused GEMM v6: 128 threads, 64 rows x 64 cols per block,
// 4x8 thread tile, W col-slice in LDS (split halves, conflict-free), A global
// with 2-deep prefetch. grid = (ceil(N/64), M/64) -> 1250 blocks, ~5/CU.
// PRE: 0=none, 1=affine on A cols, 2=affine+relu. ACT: 0=none,1=relu,2=tanh.
#define GEMM_COMPUTE(buf, kcv)                                               \
    if (PRE > 0) {                                                           \
        float4 sc_ = *(const float4*)(pscale + (kcv) * 4);                   \
        float4 sf_ = *(const float4*)(pshift + (kcv) * 4);                   \
        _Pragma("unroll")                                                    \
        for (int i = 0; i < 4; i++) {                                        \
            buf[i].x = fmaf(buf[i].x, sc_.x, sf_.x);                         \
            buf[i].y = fmaf(buf[i].y, sc_.y, sf_.y);                         \
            buf[i].z = fmaf(buf[i].z, sc_.z, sf_.z);                         \
            buf[i].w = fmaf(buf[i].w, sc_.w, sf_.w);                         \
            if (PRE == 2) {                                                  \
                buf[i].x = fmaxf(buf[i].x, 0.f); buf[i].y = fmaxf(buf[i].y, 0.f); \
                buf[i].z = fmaxf(buf[i].z, 0.f); buf[i].w = fmaxf(buf[i].w, 0.f); \
            }                                                                \
        }                                                                    \
    }                                                                        \
    _Pragma("unroll")                                                        \
    for (int kk = 0; kk < 4; kk++) {                                         \
        int k_ = (kcv) * 4 + kk;                                             \
        float4 wA = *(const float4*)(sWa + k_ * 32 + cg * 4);                \
        float4 wB = *(const float4*)(sWb + k_ * 32 + cg * 4);                \
        float wv[8] = {wA.x, wA.y, wA.z, wA.w, wB.x, wB.y, wB.z, wB.w};      \
        _Pragma("unroll")                                                    \
        for (int i = 0; i < 4; i++) {                                        \
            float av = ((const float*)&buf[i])[kk];                          \
            _Pragma("unroll")                                                \
            for (int j = 0; j < 8; j++)                                      \
                acc[i][j] = fmaf(av, wv[j], acc[i][j]);                      \
        }                                                                    \
    }

template <int K, int M, int ACT, int STATS, int PRE>
__global__ __launch_bounds__(128, 2) void gemm_kernel(const float* __restrict__ A,
                                                      const float* __restrict__ W,
                                                      const float* __restrict__ bias,
                                                      float* __restrict__ out,
                                                      float* __restrict__ sscr,
                                                      const float* __restrict__ pscale,
                                                      const float* __restrict__ pshift,
                                                      int nrows) {
    constexpr int K4 = K / 4;
    __shared__ __align__(16) float sWa[K * 32];
    __shared__ __align__(16) float sWb[K * 32];

    const int t = threadIdx.x;
    const int cg = t & 7;         // 0..7 (8 cols each)
    const int rg = t >> 3;        // 0..15 (4 rows each)
    const int col0 = blockIdx.y * 64;
    const int row0 = blockIdx.x * 64;

    for (int i = t; i < K * 16; i += 128) {
        int k = i >> 4, c4 = i & 15;
        float4 v = *(const float4*)(W + (size_t)k * M + col0 + c4 * 4);
        float* d = ((c4 & 1) ? sWb : sWa) + k * 32 + (c4 >> 1) * 4;
        *(float4*)d = v;
    }
    __syncthreads();

    size_t roff[4];
#pragma unroll
    for (int i = 0; i < 4; i++) {
        int gr = row0 + rg * 4 + i;
        roff[i] = (size_t)min(gr, nrows - 1) * K4;
    }

    float acc[4][8];
#pragma unroll
    for (int i = 0; i < 4; i++)
#pragma unroll
        for (int j = 0; j < 8; j++) acc[i][j] = 0.f;

    const float4* A4 = (const float4*)A;
    float4 pa[4], pb[4];
#pragma unroll
    for (int i = 0; i < 4; i++) pa[i] = A4[roff[i]];

    for (int kc = 0; kc < K4; kc += 2) {
#pragma unroll
        for (int i = 0; i < 4; i++) pb[i] = A4[roff[i] + kc + 1];
        GEMM_COMPUTE(pa, kc)
        if (kc + 2 < K4) {
#pragma unroll
            for (int i = 0; i < 4; i++) pa[i] = A4[roff[i] + kc + 2];
        }
        GEMM_COMPUTE(pb, kc + 1)
    }

    float bv[8];
#pragma unroll
    for (int j = 0; j < 8; j++) bv[j] = bias ? bias[col0 + cg * 8 + j] : 0.f;

    float ps[8], pq[8];
#pragma unroll
    for (int j = 0; j < 8; j++) { ps[j] = 0.f; pq[j] = 0.f; }

#pragma unroll
    for (int i = 0; i < 4; i++) {
        int gr = row0 + rg * 4 + i;
        if (gr < nrows) {
            float o[8];
#pragma unroll
            for (int j = 0; j < 8; j++) {
                float v = acc[i][j] + bv[j];
                if (ACT == 1) v = fmaxf(v, 0.f);
                if (ACT == 2) v = tanhf(v);
                o[j] = v;
                ps[j] += v; pq[j] += v * v;
            }
            float4* o4 = (float4*)(out + (size_t)gr * M + col0 + cg * 8);
            o4[0] = make_float4(o[0], o[1], o[2], o[3]);
            o4[1] = make_float4(o[4], o[5], o[6], o[7]);
        }
    }

    if (STATS) {
        __syncthreads();
#pragma unroll
        for (int j = 0; j < 8; j++) {
            sWa[rg * 64 + cg * 8 + j] = ps[j];
            sWb[rg * 64 + cg * 8 + j] = pq[j];
        }
        __syncthreads();
        if (t < 64) {
            float s = 0.f, q = 0.f;
#pragma unroll
            for (int i = 0; i < 16; i++) { s += sWa[i * 64 + t]; q += sWb[i * 64 + t]; }
            sscr[(size_t)blockIdx.x * 2 * M + col0 + t]     = s;
            sscr[(size_t)blockIdx.x * 2 * M + M + col0 + t] = q;
        }
    }
}

// reduce stats partials; affine=1: write (scale, shift); else raw (sum,sumsq).
template <int M>
__global__ __launch_bounds__(256) void stats_reduce_kernel(const float* __restrict__ sscr,
                                                           int nblk,
                                                           const float* __restrict__ g,
                                                           const float* __restrict__ b,
                                                           float* __restrict__ cs,
                                                           int affine) {
    const int cols = 2 * M;
    const int t = threadIdx.x;
    const int c = blockIdx.x * 8 + (t & 7);
    const int rl = t >> 3;
    float s = 0.f, q = 0.f;
    for (int r = rl; r < nblk; r += 32) {
        s += sscr[(size_t)r * cols + c];
        q += sscr[(size_t)r * cols + M + c];
    }
    __shared__ float shs[256], shq[256];
    shs[t] = s; shq[t] = q;
    __syncthreads();
#pragma unroll
    for (int st = 128; st >= 8; st >>= 1) {
        if (t < st) { shs[t] += shs[t + st]; shq[t] += shq[t + st]; }
        __syncthreads();
    }
    if (t < 8) {
        float ss = shs[t], qq = shq[t];
        if (affine) {
            const float invN = 1.0f / (float)NND;
            float mu = ss * invN;
            float var = fmaxf(qq * invN - mu * mu, 0.f);
            float sc = g[c] * rsqrtf(var + 1e-5f);
            cs[c] = sc;
            cs[M + c] = b[c] - mu * sc;
        } else {
            cs[c] = ss;
            cs[M + c] = qq;
        }
    }
}

// ---------------- assignment / gumbel-softmax lambdas ----------------
__global__ __launch_bounds__(256) void assign_kernel(const float* __restrict__ a1,
                                                     const float* __restrict__ Wfc2,
                                                     const float* __restrict__ bfc2,
                                                     float* __restrict__ assn,
                                                     float* __restrict__ lam,
                                                     uint32_t kg0, uint32_t kg1) {
    __shared__ float w[DIM * 2];
    int t = threadIdx.x;
    w[t] = Wfc2[t];
    __syncthreads();
    int n = blockIdx.x * 256 + t;
    if (n >= NND) return;

    float d0 = bfc2[0], d1 = bfc2[1];
    const float4* row4 = (const float4*)(a1 + (size_t)n * DIM);
#pragma unroll 8
    for (int k4 = 0; k4 < DIM / 4; k4++) {
        float4 v = row4[k4];
        d0 = fmaf(v.x, w[8 * k4 + 0], d0); d1 = fmaf(v.x, w[8 * k4 + 1], d1);
        d0 = fmaf(v.y, w[8 * k4 + 2], d0); d1 = fmaf(v.y, w[8 * k4 + 3], d1);
        d0 = fmaf(v.z, w[8 * k4 + 4], d0); d1 = fmaf(v.z, w[8 * k4 + 5], d1);
        d0 = fmaf(v.w, w[8 * k4 + 6], d0); d1 = fmaf(v.w, w[8 * k4 + 7], d1);
    }
    float m = fmaxf(d0, d1);
    float e0 = expf(d0 - m), e1 = expf(d1 - m);
    float inv = 1.f / (e0 + e1);
    float as0 = e0 * inv, as1 = e1 * inv;
    assn[2 * n] = as0; assn[2 * n + 1] = as1;

    float uf0 = rbits_u01(kg0, kg1, (uint32_t)(2 * n));
    float uf1 = rbits_u01(kg0, kg1, (uint32_t)(2 * n + 1));
    float u0 = fmaxf(1e-10f, uf0 + 1e-10f);
    float u1 = fmaxf(1e-10f, uf1 + 1e-10f);
    float gu0 = -logf(-logf(u0));
    float gu1 = -logf(-logf(u1));
    float y0 = as0 + gu0, y1 = as1 + gu1;
    float mm = fmaxf(y0, y1);
    float f0 = expf(y0 - mm), f1 = expf(y1 - mm);
    float iv = 1.f / (f0 + f1);
    lam[2 * n] = f0 * iv; lam[2 * n + 1] = f1 * iv;
}

// ---------------- noisy features + kl partial sums ----------------
__global__ __launch_bounds__(256) void noisy_kernel(const float* __restrict__ nfeat,
                                                    const float* __restrict__ lam,
                                                    const float* __restrict__ cs3,
                                                    float* __restrict__ noisy,
                                                    float* __restrict__ kpart,
                                                    uint32_t kn0, uint32_t kn1) {
    int gt = blockIdx.x * 256 + threadIdx.x;
    int n = gt >> 5, c4 = gt & 31, d = c4 * 4;
    const float invN = 1.0f / (float)NND;
    float la0 = lam[2 * n], la1 = lam[2 * n + 1];
    float4 xv = *(const float4*)(nfeat + (size_t)n * DIM + d);
    float xa[4] = {xv.x, xv.y, xv.z, xv.w};
    float t1 = 0.f, t2 = 0.f, o[4];
#pragma unroll
    for (int j = 0; j < 4; j++) {
        float mu = cs3[d + j] * invN;
        float q = cs3[DIM + d + j];
        float var1 = fmaxf(q - (float)NND * mu * mu, 0.f) / (float)(NND - 1);
        float sd = sqrtf(var1);
        float r = rbits_u01(kn0, kn1, (uint32_t)(n * DIM + d + j));
        float nm = la0 * xa[j] + la1 * mu;
        float ns = la1 * sd;
        o[j] = fmaf(r, ns, nm);
        float inv = 1.0f / (sd + 1e-7f);
        float z1 = ns * inv;            t1 += z1 * z1;
        float z2 = (nm - mu) * inv;     t2 += z2 * z2;
    }
    *(float4*)(noisy + (size_t)n * DIM + d) = make_float4(o[0], o[1], o[2], o[3]);

    __shared__ float s1[256], s2[256];
    int t = threadIdx.x;
    s1[t] = t1; s2[t] = t2;
    __syncthreads();
    for (int s = 128; s > 0; s >>= 1) {
        if (t < s) { s1[t] += s1[t + s]; s2[t] += s2[t + s]; }
        __syncthreads();
    }
    if (t == 0) { kpart[2 * blockIdx.x] = s1[0]; kpart[2 * blockIdx.x + 1] = s2[0]; }
}

// ---------------- graph segment starts (batch is sorted) ----------------
__global__ __launch_bounds__(256) void gstart_kernel(const int* __restrict__ batch,
                                                     int* __restrict__ gstart) {
    int i = blockIdx.x * 256 + threadIdx.x;
    if (i >= NND) return;
    int b = batch[i];
    int prev = (i == 0) ? -1 : batch[i - 1];
    for (int g = prev + 1; g <= b; g++) gstart[g] = i;
    if (i == NND - 1)
        for (int g = b + 1; g <= NG; g++) gstart[g] = NND;
}

// ---------------- graph mean pooling ----------------
__global__ __launch_bounds__(128) void graph_emb_part_kernel(const float* __restrict__ noisy,
                                                             const int* __restrict__ gstart,
                                                             float* __restrict__ gpart) {
    int g = blockIdx.x / EMB_SPLIT;
    int sidx = blockIdx.x % EMB_SPLIT;
    int c = threadIdx.x;
    int s = gstart[g], e = gstart[g + 1];
    int len = e - s;
    int chunk = (len + EMB_SPLIT - 1) / EMB_SPLIT;
    int r0 = s + sidx * chunk;
    int r1 = min(r0 + chunk, e);
    float acc = 0.f;
    for (int r = r0; r < r1; r++) acc += noisy[(size_t)r * DIM + c];
    gpart[((size_t)g * EMB_SPLIT + sidx) * DIM + c] = acc;
}

__global__ __launch_bounds__(128) void graph_emb_reduce_kernel(const float* __restrict__ gpart,
                                                               const int* __restrict__ gstart,
                                                               float* __restrict__ emb) {
    int g = blockIdx.x, c = threadIdx.x;
    float acc = 0.f;
#pragma unroll
    for (int si = 0; si < EMB_SPLIT; si++)
        acc += gpart[((size_t)g * EMB_SPLIT + si) * DIM + c];
    float cnt = (float)(gstart[g + 1] - gstart[g]);
    emb[(size_t)g * DIM + c] = acc / fmaxf(cnt, 1.f);
}

// ---------------- proto distances + final head ----------------
__global__ __launch_bounds__(64) void head_kernel(const float* __restrict__ emb,
                                                  const float* __restrict__ protos,
                                                  const float* __restrict__ Wlast,
                                                  float* __restrict__ out_logits,
                                                  float* __restrict__ out_probs,
                                                  float* __restrict__ out_sim,
                                                  float* __restrict__ out_dist) {
    int g = blockIdx.x, l = threadIdx.x;
    float ge0 = emb[(size_t)g * DIM + l];
    float ge1 = emb[(size_t)g * DIM + l + 64];
    float gn = ge0 * ge0 + ge1 * ge1;
    float dj[10], pj[10];
#pragma unroll
    for (int j = 0; j < 10; j++) {
        float pa = protos[j * DIM + l], pb = protos[j * DIM + l + 64];
        dj[j] = ge0 * pa + ge1 * pb;
        pj[j] = pa * pa + pb * pb;
    }
    float wl0 = ge0 * Wlast[10 + l] + ge1 * Wlast[10 + l + 64];
    float wl1 = ge0 * Wlast[138 + 10 + l] + ge1 * Wlast[138 + 10 + l + 64];
#pragma unroll
    for (int s = 32; s > 0; s >>= 1) {
        gn += __shfl_xor(gn, s);
        wl0 += __shfl_xor(wl0, s);
        wl1 += __shfl_xor(wl1, s);
#pragma unroll
        for (int j = 0; j < 10; j++) {
            dj[j] += __shfl_xor(dj[j], s);
            pj[j] += __shfl_xor(pj[j], s);
        }
    }
    if (l == 0) {
        float lg0 = wl0, lg1 = wl1;
#pragma unroll
        for (int j = 0; j < 10; j++) {
            float dist = -2.f * dj[j] + gn + pj[j];
            float sv = logf((dist + 1.0f) / (dist + 1e-4f));
            out_dist[g * 10 + j] = dist;
            out_sim[g * 10 + j] = sv;
            lg0 = fmaf(Wlast[j], sv, lg0);
            lg1 = fmaf(Wlast[138 + j], sv, lg1);
        }
        out_logits[2 * g] = lg0; out_logits[2 * g + 1] = lg1;
        float m = fmaxf(lg0, lg1);
        float e0 = expf(lg0 - m), e1 = expf(lg1 - m);
        float iv = 1.f / (e0 + e1);
        out_probs[2 * g] = e0 * iv; out_probs[2 * g + 1] = e1 * iv;
    }
}

// ---------------- 2x2 adjacency accumulation ----------------
__global__ __launch_bounds__(256) void adj_kernel(const float* __restrict__ assn,
                                                  const int* __restrict__ src,
                                                  const int* __restrict__ dst,
                                                  float* __restrict__ adjp) {
    int t = threadIdx.x;
    float p00 = 0.f, p01 = 0.f, p10 = 0.f, p11 = 0.f;
    for (int e = blockIdx.x * 256 + t; e < NE; e += ADJ_BLOCKS * 256) {
        float2 a = *(const float2*)(assn + 2 * (size_t)src[e]);
        float2 b = *(const float2*)(assn + 2 * (size_t)dst[e]);
        p00 += a.x * b.x; p01 += a.x * b.y; p10 += a.y * b.x; p11 += a.y * b.y;
    }
    __shared__ float s0[256], s1[256], s2[256], s3[256];
    s0[t] = p00; s1[t] = p01; s2[t] = p10; s3[t] = p11;
    __syncthreads();
    for (int s = 128; s > 0; s >>= 1) {
        if (t < s) { s0[t] += s0[t + s]; s1[t] += s1[t + s]; s2[t] += s2[t + s]; s3[t] += s3[t + s]; }
        __syncthreads();
    }
    if (t == 0) {
        float4* o = (float4*)(adjp + 4 * (size_t)blockIdx.x);
        *o = make_float4(s0[0], s1[0], s2[0], s3[0]);
    }
}

// ---------------- final scalars ----------------
__global__ __launch_bounds__(256) void final_scalar_kernel(const float* __restrict__ kpart,
                                                           const float* __restrict__ adjp,
                                                           float* __restrict__ out) {
    __shared__ float sh[6 * 256];
    int t = threadIdx.x;
    float k1 = 0.f, k2 = 0.f, a0 = 0.f, a1 = 0.f, a2 = 0.f, a3 = 0.f;
    for (int i = t; i < NOISY_BLOCKS; i += 256) {
        float2 v = ((const float2*)kpart)[i];
        k1 += v.x; k2 += v.y;
    }
    for (int i = t; i < ADJ_BLOCKS; i += 256) {
        float4 v = ((const float4*)adjp)[i];
        a0 += v.x; a1 += v.y; a2 += v.z; a3 += v.w;
    }
    sh[t] = k1; sh[256 + t] = k2; sh[512 + t] = a0;
    sh[768 + t] = a1; sh[1024 + t] = a2; sh[1280 + t] = a3;
    __syncthreads();
    for (int s = 128; s > 0; s >>= 1) {
        if (t < s) {
#pragma unroll
            for (int v = 0; v < 6; v++) sh[v * 256 + t] += sh[v * 256 + t + s];
        }
        __syncthreads();
    }
    if (t == 0) {
        float kl = 0.5f / ((float)NND * (float)DIM) * sh[0] + (1.0f / (float)DIM) * sh[256];
        out[16896] = kl;
        float a00 = sh[512], a01 = sh[768], a10 = sh[1024], a11 = sh[1280];
        float r0 = fmaxf(fabsf(a00) + fabsf(a01), 1e-12f);
        float r1 = fmaxf(fabsf(a10) + fabsf(a11), 1e-12f);
        float d0 = a00 / r0 - 1.f, d1 = a11 / r1 - 1.f;
        out[16897] = 0.5f * (d0 * d0 + d1 * d1);
    }
}

// ---------------- launcher ----------------
extern "C" void kernel_launch(void* const* d_in, const int* in_sizes, int n_in,
                              void* d_out, int out_size, void* d_ws, size_t ws_size,
                              hipStream_t stream) {
    (void)in_sizes; (void)n_in; (void)out_size; (void)ws_size;
    const float* x     = (const float*)d_in[0];
    const int*   ei    = (const int*)d_in[1];
    const int*   batch = (const int*)d_in[2];
    const float* W0a   = (const float*)d_in[3];
    const float* W0b   = (const float*)d_in[4];
    const float* g0    = (const float*)d_in[5];
    const float* b0    = (const float*)d_in[6];
    const float* W1a   = (const float*)d_in[7];
    const float* W1b   = (const float*)d_in[8];
    const float* g1    = (const float*)d_in[9];
    const float* b1    = (const float*)d_in[10];
    const float* Wm0   = (const float*)d_in[11];
    const float* bm0   = (const float*)d_in[12];
    const float* gm    = (const float*)d_in[13];
    const float* bm    = (const float*)d_in[14];
    const float* Wm1   = (const float*)d_in[15];
    const float* bm1   = (const float*)d_in[16];
    const float* Wfc1  = (const float*)d_in[17];
    const float* bfc1  = (const float*)d_in[18];
    const float* Wfc2  = (const float*)d_in[19];
    const float* bfc2  = (const float*)d_in[20];
    const float* protos= (const float*)d_in[21];
    const float* Wlast = (const float*)d_in[22];
    const int* src = ei;
    const int* dst = ei + NE;
    float* out = (float*)d_out;

    float* ws   = (float*)d_ws;
    float* agg  = ws;                               // N*128
    float* tA   = agg + (size_t)NND * DIM;          // N*128
    float* tB   = tA + (size_t)NND * DIM;           // N*128 (also bf16 scratch alias)
    float* t5   = tB + (size_t)NND * DIM;           // N*64
    float* lam  = t5 + (size_t)NND * HID;           // N*2
    float* assn = lam + (size_t)NND * 2;            // N*2
    float* cs   = assn + (size_t)NND * 2;           // 1024 (4 segments of 256)
    float* kpart= cs + 1024;                        // NOISY_BLOCKS*2
    float* adjp = kpart + NOISY_BLOCKS * 2;         // ADJ_BLOCKS*4
    float* sscr = adjp + ADJ_BLOCKS * 4;            // GRB*256 stats partials
    float* gpart= sscr + (size_t)GRB * 256;         // NG*EMB_SPLIT*DIM
    int* ib     = (int*)(gpart + NG * EMB_SPLIT * DIM);  // int region
    int* deg    = ib;                               // N
    int* offv   = deg + NND;                        // N+1
    int* cursor = offv + NND + 1;                   // N
    int* elist  = cursor + NND;                     // E
    int* gstart = elist + NE;                       // NG+1
    int* bsum   = gstart + NG + 1;                  // NSCB
    int* boff   = bsum + NSCB;                      // NSCB

    ushort* bfscr = (ushort*)tB;   // bf16 scratch aliases tB (dead intervals only)

    // threefry keys on host: key(42) = (0,42); partitionable fold-like split
    uint32_t kg0 = 0u, kg1 = 0u; threefry2x32(0u, 42u, kg0, kg1);  // ctr (0,0)
    uint32_t kn0 = 0u, kn1 = 1u; threefry2x32(0u, 42u, kn0, kn1);  // ctr (0,1)

    hipMemsetAsync(deg, 0, NND * sizeof(int), stream);

    // CSR (shared by both GIN layers)
    hist_kernel<<<(NE + 255) / 256, 256, 0, stream>>>(dst, deg);
    scan_bsum_kernel<<<NSCB, 256, 0, stream>>>(deg, bsum);
    scan_boff_kernel<<<1, 256, 0, stream>>>(bsum, boff, offv);
    scan_final_kernel<<<NSCB, 256, 0, stream>>>(deg, boff, offv, cursor);
    build_kernel<<<(NE + 255) / 256, 256, 0, stream>>>(src, dst, cursor, elist);

    dim3 g2(GRB, 2), g1x(GRB, 1);
    const int CVB = (NND * DIM / 8 + 255) / 256;   // 2500 convert blocks
    const int GAB = NND / 4;                        // gather blocks (wave/node)

    // GIN layer 1: x -> bf16 -> gather -> two GEMMs
    cvt_kernel<<<CVB, 256, 0, stream>>>(x, bfscr);
    gather_kernel<<<GAB, 256, 0, stream>>>(bfscr, offv, elist, agg);
    gemm_kernel<128,128,1,0,0><<<g2, 128, 0, stream>>>(agg, W0a, nullptr, tB, nullptr, nullptr, nullptr, NND);
    gemm_kernel<128,128,1,1,0><<<g2, 128, 0, stream>>>(tB, W0b, nullptr, tA, sscr, nullptr, nullptr, NND);
    stats_reduce_kernel<128><<<16, 256, 0, stream>>>(sscr, GRB, g0, b0, cs + 0, 1);   // affine0

    // GIN layer 2: nf1 = relu(affine0(tA)) as bf16 -> gather -> GEMMs
    cvt_affine_kernel<<<CVB, 256, 0, stream>>>(tA, cs + 0, bfscr);
    gather_kernel<<<GAB, 256, 0, stream>>>(bfscr, offv, elist, agg);
    gemm_kernel<128,128,1,0,0><<<g2, 128, 0, stream>>>(agg, W1a, nullptr, tB, nullptr, nullptr, nullptr, NND);
    gemm_kernel<128,128,1,1,0><<<g2, 128, 0, stream>>>(tB, W1b, nullptr, tA, sscr, nullptr, nullptr, NND);
    stats_reduce_kernel<128><<<16, 256, 0, stream>>>(sscr, GRB, g1, b1, cs + 256, 1); // affine1

    // bottleneck MLP: affine1 folded into A-path (PRE=1); affine2+relu (PRE=2)
    gemm_kernel<128,64,0,1,1><<<g1x, 128, 0, stream>>>(tA, Wm0, bm0, t5, sscr, cs + 256, cs + 384, NND);
    stats_reduce_kernel<64><<<8, 256, 0, stream>>>(sscr, GRB, gm, bm, cs + 512, 1);   // affine2
    gemm_kernel<64,128,0,1,2><<<g2, 128, 0, stream>>>(t5, Wm1, bm1, agg, sscr, cs + 512, cs + 576, NND); // node_feature
    stats_reduce_kernel<128><<<16, 256, 0, stream>>>(sscr, GRB, nullptr, nullptr, cs + 640, 0); // raw sums
    gemm_kernel<128,128,2,0,0><<<g2, 128, 0, stream>>>(agg, Wfc1, bfc1, tB, nullptr, nullptr, nullptr, NND); // a1

    // assignment + gumbel
    assign_kernel<<<(NND + 255) / 256, 256, 0, stream>>>(tB, Wfc2, bfc2, assn, lam, kg0, kg1);

    // noisy features (into tA) + kl partials
    noisy_kernel<<<NOISY_BLOCKS, 256, 0, stream>>>(agg, lam, cs + 640, tA, kpart, kn0, kn1);

    // graph pooling + head
    gstart_kernel<<<(NND + 255) / 256, 256, 0, stream>>>(batch, gstart);
    graph_emb_part_kernel<<<NG * EMB_SPLIT, 128, 0, stream>>>(tA, gstart, gpart);
    graph_emb_reduce_kernel<<<NG, 128, 0, stream>>>(gpart, gstart, out + 512);
    head_kernel<<<NG, 64, 0, stream>>>(out + 512, protos, Wlast,
                                       out, out + 256, out + 16898, out + 18178);

    // penalties
    adj_kernel<<<ADJ_BLOCKS, 256, 0, stream>>>(assn, src, dst, adjp);
    final_scalar_kernel<<<1, 256, 0, stream>>>(kpart, adjp, out);
}

// Round 11
// 318.225 us; speedup vs baseline: 2.8015x; 1.4590x over previous
//
#include <hip/hip_runtime.h>
#include <hip/hip_bf16.h>
#include <stdint.h>

#define NND 40000
#define NE  640000
#define NG  128
#define DIM 128
#define HID 64
#define ADJ_BLOCKS 640
#define NOISY_BLOCKS 5000   // NND*32/256
#define NSCB ((NND + 255) / 256)   // 157 scan blocks
#define EMB_SPLIT 8
#define SROWS 313            // mgemm row blocks (128 rows each) = stats rows

typedef short v8s __attribute__((ext_vector_type(8)));
typedef float v4f __attribute__((ext_vector_type(4)));

// ---------------- threefry2x32 (20 rounds), JAX-compatible ----------------
__host__ __device__ inline uint32_t rotl32(uint32_t v, uint32_t r) {
    return (v << r) | (v >> (32u - r));
}

__host__ __device__ inline void threefry2x32(uint32_t k0, uint32_t k1,
                                             uint32_t& x0, uint32_t& x1) {
    uint32_t k2 = k0 ^ k1 ^ 0x1BD11BDAu;
    x0 += k0; x1 += k1;
#define TFR(r) { x0 += x1; x1 = rotl32(x1, r); x1 ^= x0; }
    TFR(13u) TFR(15u) TFR(26u) TFR(6u)
    x0 += k1; x1 += k2 + 1u;
    TFR(17u) TFR(29u) TFR(16u) TFR(24u)
    x0 += k2; x1 += k0 + 2u;
    TFR(13u) TFR(15u) TFR(26u) TFR(6u)
    x0 += k0; x1 += k1 + 3u;
    TFR(17u) TFR(29u) TFR(16u) TFR(24u)
    x0 += k1; x1 += k2 + 4u;
    TFR(13u) TFR(15u) TFR(26u) TFR(6u)
    x0 += k2; x1 += k0 + 5u;
#undef TFR
}

// partitionable-mode random bits -> uniform [0,1)
__device__ inline float rbits_u01(uint32_t k0, uint32_t k1, uint32_t idx) {
    uint32_t x0 = 0u, x1 = idx;
    threefry2x32(k0, k1, x0, x1);
    uint32_t b = x0 ^ x1;
    return __uint_as_float((b >> 9) | 0x3f800000u) - 1.0f;
}

__device__ inline ushort bfbits(float a) {
    __hip_bfloat16 h = __float2bfloat16(a);
    return *(ushort*)&h;
}

__device__ inline uint32_t bfpack(float a, float b) {
    return (uint32_t)bfbits(a) | ((uint32_t)bfbits(b) << 16);
}

// unpack 8 bf16 (uint4) -> 8 f32
#define UNPACK8(v, f)                                                     \
    f[0] = __uint_as_float((v).x << 16); f[1] = __uint_as_float((v).x & 0xffff0000u); \
    f[2] = __uint_as_float((v).y << 16); f[3] = __uint_as_float((v).y & 0xffff0000u); \
    f[4] = __uint_as_float((v).z << 16); f[5] = __uint_as_float((v).z & 0xffff0000u); \
    f[6] = __uint_as_float((v).w << 16); f[7] = __uint_as_float((v).w & 0xffff0000u);

// ---------------- CSR build ----------------
__global__ __launch_bounds__(256) void hist_kernel(const int* __restrict__ dst,
                                                   int* __restrict__ deg) {
    int e = blockIdx.x * 256 + threadIdx.x;
    if (e < NE) atomicAdd(&deg[dst[e]], 1);
}

__global__ __launch_bounds__(256) void scan_bsum_kernel(const int* __restrict__ deg,
                                                        int* __restrict__ bsum) {
    int t = threadIdx.x;
    int i = blockIdx.x * 256 + t;
    int v = (i < NND) ? deg[i] : 0;
    __shared__ int sh[256];
    sh[t] = v;
    __syncthreads();
#pragma unroll
    for (int s = 128; s > 0; s >>= 1) {
        if (t < s) sh[t] += sh[t + s];
        __syncthreads();
    }
    if (t == 0) bsum[blockIdx.x] = sh[0];
}

__global__ __launch_bounds__(256) void scan_boff_kernel(const int* __restrict__ bsum,
                                                        int* __restrict__ boff,
                                                        int* __restrict__ offv) {
    int t = threadIdx.x;
    int v = (t < NSCB) ? bsum[t] : 0;
    __shared__ int sh[256];
    sh[t] = v;
    __syncthreads();
    for (int d = 1; d < 256; d <<= 1) {
        int u = (t >= d) ? sh[t - d] : 0;
        __syncthreads();
        sh[t] += u;
        __syncthreads();
    }
    if (t < NSCB) boff[t] = sh[t] - v;   // exclusive
    if (t == NSCB - 1) offv[NND] = sh[t];
}

__global__ __launch_bounds__(256) void scan_final_kernel(const int* __restrict__ deg,
                                                         const int* __restrict__ boff,
                                                         int* __restrict__ offv,
                                                         int* __restrict__ cursor) {
    int t = threadIdx.x;
    int i = blockIdx.x * 256 + t;
    int v = (i < NND) ? deg[i] : 0;
    __shared__ int sh[256];
    sh[t] = v;
    __syncthreads();
    for (int d = 1; d < 256; d <<= 1) {
        int u = (t >= d) ? sh[t - d] : 0;
        __syncthreads();
        sh[t] += u;
        __syncthreads();
    }
    int off = boff[blockIdx.x] + sh[t] - v;   // exclusive prefix
    if (i < NND) { offv[i] = off; cursor[i] = off; }
}

__global__ __launch_bounds__(256) void build_kernel(const int* __restrict__ src,
                                                    const int* __restrict__ dst,
                                                    int* __restrict__ cursor,
                                                    int* __restrict__ elist) {
    int e = blockIdx.x * 256 + threadIdx.x;
    if (e < NE) {
        int p = atomicAdd(&cursor[dst[e]], 1);
        elist[p] = src[e];
    }
}

// ---------------- f32 -> bf16 converts ----------------
__global__ __launch_bounds__(256) void cvt_kernel(const float* __restrict__ in,
                                                  ushort* __restrict__ outh) {
    int i = blockIdx.x * 256 + threadIdx.x;    // per 8 elements
    if (i >= NND * DIM / 8) return;
    const float4* p = (const float4*)in + (size_t)i * 2;
    float4 a = p[0], b = p[1];
    uint4 o;
    o.x = bfpack(a.x, a.y); o.y = bfpack(a.z, a.w);
    o.z = bfpack(b.x, b.y); o.w = bfpack(b.z, b.w);
    *(uint4*)(outh + (size_t)i * 8) = o;
}

// affine (BN) + relu on bf16 input -> bf16 output (nf1 path)
__global__ __launch_bounds__(256) void cvt_affine_kernel(const ushort* __restrict__ inh,
                                                         const float* __restrict__ cs,
                                                         ushort* __restrict__ outh) {
    int i = blockIdx.x * 256 + threadIdx.x;    // per 8 elements
    if (i >= NND * DIM / 8) return;
    int c = (i * 8) % DIM;
    float4 sc0 = *(const float4*)(cs + c), sc1 = *(const float4*)(cs + c + 4);
    float4 sh0 = *(const float4*)(cs + DIM + c), sh1 = *(const float4*)(cs + DIM + c + 4);
    uint4 v = *(const uint4*)(inh + (size_t)i * 8);
    float f[8];
    UNPACK8(v, f)
    f[0] = fmaxf(fmaf(f[0], sc0.x, sh0.x), 0.f); f[1] = fmaxf(fmaf(f[1], sc0.y, sh0.y), 0.f);
    f[2] = fmaxf(fmaf(f[2], sc0.z, sh0.z), 0.f); f[3] = fmaxf(fmaf(f[3], sc0.w, sh0.w), 0.f);
    f[4] = fmaxf(fmaf(f[4], sc1.x, sh1.x), 0.f); f[5] = fmaxf(fmaf(f[5], sc1.y, sh1.y), 0.f);
    f[6] = fmaxf(fmaf(f[6], sc1.z, sh1.z), 0.f); f[7] = fmaxf(fmaf(f[7], sc1.w, sh1.w), 0.f);
    uint4 o;
    o.x = bfpack(f[0], f[1]); o.y = bfpack(f[2], f[3]);
    o.z = bfpack(f[4], f[5]); o.w = bfpack(f[6], f[7]);
    *(uint4*)(outh + (size_t)i * 8) = o;
}

// ---------------- gather: wave/node, 4 edge-slots x 16 col-slots; bf16 in/out ----
__global__ __launch_bounds__(256) void gather_kernel(const ushort* __restrict__ feath,
                                                     const int* __restrict__ offv,
                                                     const int* __restrict__ elist,
                                                     ushort* __restrict__ aggh) {
    int gt = blockIdx.x * 256 + threadIdx.x;
    int n = gt >> 6;
    int lane = threadIdx.x & 63;
    int e = lane >> 4, c = lane & 15;
    const uint4* F = (const uint4*)feath;
    int o0 = offv[n], o1 = offv[n + 1];

    float acc[8];
    if (e == 0) {                        // self term, counted once
        uint4 v = F[(size_t)n * 16 + c];
        UNPACK8(v, acc)
    } else {
#pragma unroll
        for (int j = 0; j < 8; j++) acc[j] = 0.f;
    }

    for (int i = o0 + e; i < o1; i += 4) {
        int s = elist[i];
        uint4 v = F[(size_t)s * 16 + c];
        float f[8];
        UNPACK8(v, f)
#pragma unroll
        for (int j = 0; j < 8; j++) acc[j] += f[j];
    }

#pragma unroll
    for (int j = 0; j < 8; j++) {
        acc[j] += __shfl_xor(acc[j], 16);
        acc[j] += __shfl_xor(acc[j], 32);
    }

    uint32_t wv;
    if (e == 0)      wv = bfpack(acc[0], acc[1]);
    else if (e == 1) wv = bfpack(acc[2], acc[3]);
    else if (e == 2) wv = bfpack(acc[4], acc[5]);
    else             wv = bfpack(acc[6], acc[7]);
    ((uint32_t*)aggh)[(size_t)n * 64 + c * 4 + e] = wv;
}

// ---------------- MFMA GEMM: out = ACT(PRE(A) @ bf16(W) [+ bias]) -----------
// A bf16 row-major N x K. Block 256 thr = 4 waves; tile 128 rows x 64 cols;
// wave w owns rows w*32..+31 (2 row-frags x 4 col-frags of 16x16).
// W staged f32->bf16 TRANSPOSED in LDS [col][K+8]. A frags loaded up-front.
// PRE: 0 none, 1 affine(scale,shift per k), 2 affine+relu.
// ACT: 0 none, 1 relu, 2 tanh.  OUTM: 0 bf16->outh, 1 f32->outf, 2 both.
template <int K, int M, int ACT, int STATS, int PRE, int OUTM>
__global__ __launch_bounds__(256) void mgemm_kernel(const ushort* __restrict__ Ah,
                                                    const float* __restrict__ W,
                                                    const float* __restrict__ bias,
                                                    float* __restrict__ outf,
                                                    ushort* __restrict__ outh,
                                                    float* __restrict__ sscr,
                                                    const float* __restrict__ pscale,
                                                    const float* __restrict__ pshift,
                                                    int nrows) {
    constexpr int KP  = K + 8;
    constexpr int NKC = K / 32;
    __shared__ __align__(16) ushort sW[64 * KP];

    const int t = threadIdx.x;
    const int w = t >> 6, l = t & 63;
    const int lm = l & 15, lk = l >> 4;
    const int col0 = blockIdx.y * 64;
    const int row0 = blockIdx.x * 128 + w * 32;

    // stage W col-slice, converted + transposed: sW[c][k]
    for (int idx = t; idx < K * 64; idx += 256) {
        int k = idx >> 6, c = idx & 63;
        sW[c * KP + k] = bfbits(W[(size_t)k * M + col0 + c]);
    }

    // issue ALL A-frag loads up-front (max prefetch; waits inserted at use)
    uint4 areg[2][NKC];
#pragma unroll
    for (int rf = 0; rf < 2; rf++) {
        int r = row0 + rf * 16 + lm;
        const ushort* ap = Ah + (size_t)min(r, nrows - 1) * K + lk * 8;
#pragma unroll
        for (int kc = 0; kc < NKC; kc++)
            areg[rf][kc] = *(const uint4*)(ap + kc * 32);
    }

    __syncthreads();

    v4f acc[2][4];
#pragma unroll
    for (int i = 0; i < 2; i++)
#pragma unroll
        for (int j = 0; j < 4; j++) acc[i][j] = (v4f){0.f, 0.f, 0.f, 0.f};

#pragma unroll
    for (int kc = 0; kc < NKC; kc++) {
        v8s bfr[4];
#pragma unroll
        for (int nc = 0; nc < 4; nc++)
            bfr[nc] = *(const v8s*)(sW + (nc * 16 + lm) * KP + kc * 32 + lk * 8);

        v8s afr[2];
#pragma unroll
        for (int rf = 0; rf < 2; rf++) {
            if (PRE > 0) {
                int k0 = kc * 32 + lk * 8;
                float f[8];
                uint4 v = areg[rf][kc];
                UNPACK8(v, f)
                float4 s0 = *(const float4*)(pscale + k0);
                float4 s1 = *(const float4*)(pscale + k0 + 4);
                float4 h0 = *(const float4*)(pshift + k0);
                float4 h1 = *(const float4*)(pshift + k0 + 4);
                f[0] = fmaf(f[0], s0.x, h0.x); f[1] = fmaf(f[1], s0.y, h0.y);
                f[2] = fmaf(f[2], s0.z, h0.z); f[3] = fmaf(f[3], s0.w, h0.w);
                f[4] = fmaf(f[4], s1.x, h1.x); f[5] = fmaf(f[5], s1.y, h1.y);
                f[6] = fmaf(f[6], s1.z, h1.z); f[7] = fmaf(f[7], s1.w, h1.w);
                if (PRE == 2) {
#pragma unroll
                    for (int e2 = 0; e2 < 8; e2++) f[e2] = fmaxf(f[e2], 0.f);
                }
                v8s a;
#pragma unroll
                for (int e2 = 0; e2 < 8; e2++) a[e2] = (short)bfbits(f[e2]);
                afr[rf] = a;
            } else {
                afr[rf] = *(const v8s*)&areg[rf][kc];
            }
        }

#pragma unroll
        for (int rf = 0; rf < 2; rf++)
#pragma unroll
            for (int nc = 0; nc < 4; nc++)
                acc[rf][nc] = __builtin_amdgcn_mfma_f32_16x16x32_bf16(
                    afr[rf], bfr[nc], acc[rf][nc], 0, 0, 0);
    }

    // epilogue: D[row][col]: col = lm (within 16-tile), row = lk*4 + reg
    float ps[4], pq[4];
#pragma unroll
    for (int nc = 0; nc < 4; nc++) { ps[nc] = 0.f; pq[nc] = 0.f; }

#pragma unroll
    for (int nc = 0; nc < 4; nc++) {
        int cg = col0 + nc * 16 + lm;
        float bv = bias ? bias[cg] : 0.f;
#pragma unroll
        for (int rf = 0; rf < 2; rf++) {
#pragma unroll
            for (int reg = 0; reg < 4; reg++) {
                int rg = row0 + rf * 16 + lk * 4 + reg;
                if (rg < nrows) {
                    float v = acc[rf][nc][reg] + bv;
                    if (ACT == 1) v = fmaxf(v, 0.f);
                    if (ACT == 2) v = tanhf(v);
                    if (OUTM != 0) outf[(size_t)rg * M + cg] = v;
                    if (OUTM != 1) outh[(size_t)rg * M + cg] = bfbits(v);
                    ps[nc] += v; pq[nc] += v * v;
                }
            }
        }
    }

    if (STATS) {
        __syncthreads();                 // everyone done reading sW
        float* scr = (float*)sW;         // 64*KP*2B >= 512 floats
#pragma unroll
        for (int nc = 0; nc < 4; nc++) {
            ps[nc] += __shfl_xor(ps[nc], 16); ps[nc] += __shfl_xor(ps[nc], 32);
            pq[nc] += __shfl_xor(pq[nc], 16); pq[nc] += __shfl_xor(pq[nc], 32);
        }
        if (lk == 0) {
#pragma unroll
            for (int nc = 0; nc < 4; nc++) {
                scr[w * 64 + nc * 16 + lm]       = ps[nc];
                scr[256 + w * 64 + nc * 16 + lm] = pq[nc];
            }
        }
        __syncthreads();
        if (t < 64) {
            float s = scr[t] + scr[64 + t] + scr[128 + t] + scr[192 + t];
            float q = scr[256 + t] + scr[320 + t] + scr[384 + t] + scr[448 + t];
            sscr[(size_t)blockIdx.x * 2 * M + col0 + t]     = s;
            sscr[(size_t)blockIdx.x * 2 * M + M + col0 + t] = q;
        }
    }
}

// reduce stats partials; affine=1: write (scale, shift); else raw (sum,sumsq).
template <int M>
__global__ __launch_bounds__(256) void stats_reduce_kernel(const float* __restrict__ sscr,
                                                           int nblk,
                                                           const float* __restrict__ g,
                                                           const float* __restrict__ b,
                                                           float* __restrict__ cs,
                                                           int affine) {
    const int cols = 2 * M;
    const int t = threadIdx.x;
    const int c = blockIdx.x * 8 + (t & 7);
    const int rl = t >> 3;
    float s = 0.f, q = 0.f;
    for (int r = rl; r < nblk; r += 32) {
        s += sscr[(size_t)r * cols + c];
        q += sscr[(size_t)r * cols + M + c];
    }
    __shared__ float shs[256], shq[256];
    shs[t] = s; shq[t] = q;
    __syncthreads();
#pragma unroll
    for (int st = 128; st >= 8; st >>= 1) {
        if (t < st) { shs[t] += shs[t + st]; shq[t] += shq[t + st]; }
        __syncthreads();
    }
    if (t < 8) {
        float ss = shs[t], qq = shq[t];
        if (affine) {
            const float invN = 1.0f / (float)NND;
            float mu = ss * invN;
            float var = fmaxf(qq * invN - mu * mu, 0.f);
            float sc = g[c] * rsqrtf(var + 1e-5f);
            cs[c] = sc;
            cs[M + c] = b[c] - mu * sc;
        } else {
            cs[c] = ss;
            cs[M + c] = qq;
        }
    }
}

// ---------------- assignment / gumbel-softmax lambdas ----------------
__global__ __launch_bounds__(256) void assign_kernel(const float* __restrict__ a1,
                                                     const float* __restrict__ Wfc2,
                                                     const float* __restrict__ bfc2,
                                                     float* __restrict__ assn,
                                                     float* __restrict__ lam,
                                                     uint32_t kg0, uint32_t kg1) {
    __shared__ float w[DIM * 2];
    int t = threadIdx.x;
    w[t] = Wfc2[t];
    __syncthreads();
    int n = blockIdx.x * 256 + t;
    if (n >= NND) return;

    float d0 = bfc2[0], d1 = bfc2[1];
    const float4* row4 = (const float4*)(a1 + (size_t)n * DIM);
#pragma unroll 8
    for (int k4 = 0; k4 < DIM / 4; k4++) {
        float4 v = row4[k4];
        d0 = fmaf(v.x, w[8 * k4 + 0], d0); d1 = fmaf(v.x, w[8 * k4 + 1], d1);
        d0 = fmaf(v.y, w[8 * k4 + 2], d0); d1 = fmaf(v.y, w[8 * k4 + 3], d1);
        d0 = fmaf(v.z, w[8 * k4 + 4], d0); d1 = fmaf(v.z, w[8 * k4 + 5], d1);
        d0 = fmaf(v.w, w[8 * k4 + 6], d0); d1 = fmaf(v.w, w[8 * k4 + 7], d1);
    }
    float m = fmaxf(d0, d1);
    float e0 = expf(d0 - m), e1 = expf(d1 - m);
    float inv = 1.f / (e0 + e1);
    float as0 = e0 * inv, as1 = e1 * inv;
    assn[2 * n] = as0; assn[2 * n + 1] = as1;

    float uf0 = rbits_u01(kg0, kg1, (uint32_t)(2 * n));
    float uf1 = rbits_u01(kg0, kg1, (uint32_t)(2 * n + 1));
    float u0 = fmaxf(1e-10f, uf0 + 1e-10f);
    float u1 = fmaxf(1e-10f, uf1 + 1e-10f);
    float gu0 = -logf(-logf(u0));
    float gu1 = -logf(-logf(u1));
    float y0 = as0 + gu0, y1 = as1 + gu1;
    float mm = fmaxf(y0, y1);
    float f0 = expf(y0 - mm), f1 = expf(y1 - mm);
    float iv = 1.f / (f0 + f1);
    lam[2 * n] = f0 * iv; lam[2 * n + 1] = f1 * iv;
}

// ---------------- noisy features + kl partial sums ----------------
__global__ __launch_bounds__(256) void noisy_kernel(const float* __restrict__ nfeat,
                                                    const float* __restrict__ lam,
                                                    const float* __restrict__ cs3,
                                                    float* __restrict__ noisy,
                                                    float* __restrict__ kpart,
                                                    uint32_t kn0, uint32_t kn1) {
    int gt = blockIdx.x * 256 + threadIdx.x;
    int n = gt >> 5, c4 = gt & 31, d = c4 * 4;
    const float invN = 1.0f / (float)NND;
    float la0 = lam[2 * n], la1 = lam[2 * n + 1];
    float4 xv = *(const float4*)(nfeat + (size_t)n * DIM + d);
    float xa[4] = {xv.x, xv.y, xv.z, xv.w};
    float t1 = 0.f, t2 = 0.f, o[4];
#pragma unroll
    for (int j = 0; j < 4; j++) {
        float mu = cs3[d + j] * invN;
        float q = cs3[DIM + d + j];
        float var1 = fmaxf(q - (float)NND * mu * mu, 0.f) / (float)(NND - 1);
        float sd = sqrtf(var1);
        float r = rbits_u01(kn0, kn1, (uint32_t)(n * DIM + d + j));
        float nm = la0 * xa[j] + la1 * mu;
        float ns = la1 * sd;
        o[j] = fmaf(r, ns, nm);
        float inv = 1.0f / (sd + 1e-7f);
        float z1 = ns * inv;            t1 += z1 * z1;
        float z2 = (nm - mu) * inv;     t2 += z2 * z2;
    }
    *(float4*)(noisy + (size_t)n * DIM + d) = make_float4(o[0], o[1], o[2], o[3]);

    __shared__ float s1[256], s2[256];
    int t = threadIdx.x;
    s1[t] = t1; s2[t] = t2;
    __syncthreads();
    for (int s = 128; s > 0; s >>= 1) {
        if (t < s) { s1[t] += s1[t + s]; s2[t] += s2[t + s]; }
        __syncthreads();
    }
    if (t == 0) { kpart[2 * blockIdx.x] = s1[0]; kpart[2 * blockIdx.x + 1] = s2[0]; }
}

// ---------------- graph segment starts (batch is sorted) ----------------
__global__ __launch_bounds__(256) void gstart_kernel(const int* __restrict__ batch,
                                                     int* __restrict__ gstart) {
    int i = blockIdx.x * 256 + threadIdx.x;
    if (i >= NND) return;
    int b = batch[i];
    int prev = (i == 0) ? -1 : batch[i - 1];
    for (int g = prev + 1; g <= b; g++) gstart[g] = i;
    if (i == NND - 1)
        for (int g = b + 1; g <= NG; g++) gstart[g] = NND;
}

// ---------------- graph mean pooling ----------------
__global__ __launch_bounds__(128) void graph_emb_part_kernel(const float* __restrict__ noisy,
                                                             const int* __restrict__ gstart,
                                                             float* __restrict__ gpart) {
    int g = blockIdx.x / EMB_SPLIT;
    int sidx = blockIdx.x % EMB_SPLIT;
    int c = threadIdx.x;
    int s = gstart[g], e = gstart[g + 1];
    int len = e - s;
    int chunk = (len + EMB_SPLIT - 1) / EMB_SPLIT;
    int r0 = s + sidx * chunk;
    int r1 = min(r0 + chunk, e);
    float acc = 0.f;
    for (int r = r0; r < r1; r++) acc += noisy[(size_t)r * DIM + c];
    gpart[((size_t)g * EMB_SPLIT + sidx) * DIM + c] = acc;
}

__global__ __launch_bounds__(128) void graph_emb_reduce_kernel(const float* __restrict__ gpart,
                                                               const int* __restrict__ gstart,
                                                               float* __restrict__ emb) {
    int g = blockIdx.x, c = threadIdx.x;
    float acc = 0.f;
#pragma unroll
    for (int si = 0; si < EMB_SPLIT; si++)
        acc += gpart[((size_t)g * EMB_SPLIT + si) * DIM + c];
    float cnt = (float)(gstart[g + 1] - gstart[g]);
    emb[(size_t)g * DIM + c] = acc / fmaxf(cnt, 1.f);
}

// ---------------- proto distances + final head ----------------
__global__ __launch_bounds__(64) void head_kernel(const float* __restrict__ emb,
                                                  const float* __restrict__ protos,
                                                  const float* __restrict__ Wlast,
                                                  float* __restrict__ out_logits,
                                                  float* __restrict__ out_probs,
                                                  float* __restrict__ out_sim,
                                                  float* __restrict__ out_dist) {
    int g = blockIdx.x, l = threadIdx.x;
    float ge0 = emb[(size_t)g * DIM + l];
    float ge1 = emb[(size_t)g * DIM + l + 64];
    float gn = ge0 * ge0 + ge1 * ge1;
    float dj[10], pj[10];
#pragma unroll
    for (int j = 0; j < 10; j++) {
        float pa = protos[j * DIM + l], pb = protos[j * DIM + l + 64];
        dj[j] = ge0 * pa + ge1 * pb;
        pj[j] = pa * pa + pb * pb;
    }
    float wl0 = ge0 * Wlast[10 + l] + ge1 * Wlast[10 + l + 64];
    float wl1 = ge0 * Wlast[138 + 10 + l] + ge1 * Wlast[138 + 10 + l + 64];
#pragma unroll
    for (int s = 32; s > 0; s >>= 1) {
        gn += __shfl_xor(gn, s);
        wl0 += __shfl_xor(wl0, s);
        wl1 += __shfl_xor(wl1, s);
#pragma unroll
        for (int j = 0; j < 10; j++) {
            dj[j] += __shfl_xor(dj[j], s);
            pj[j] += __shfl_xor(pj[j], s);
        }
    }
    if (l == 0) {
        float lg0 = wl0, lg1 = wl1;
#pragma unroll
        for (int j = 0; j < 10; j++) {
            float dist = -2.f * dj[j] + gn + pj[j];
            float sv = logf((dist + 1.0f) / (dist + 1e-4f));
            out_dist[g * 10 + j] = dist;
            out_sim[g * 10 + j] = sv;
            lg0 = fmaf(Wlast[j], sv, lg0);
            lg1 = fmaf(Wlast[138 + j], sv, lg1);
        }
        out_logits[2 * g] = lg0; out_logits[2 * g + 1] = lg1;
        float m = fmaxf(lg0, lg1);
        float e0 = expf(lg0 - m), e1 = expf(lg1 - m);
        float iv = 1.f / (e0 + e1);
        out_probs[2 * g] = e0 * iv; out_probs[2 * g + 1] = e1 * iv;
    }
}

// ---------------- 2x2 adjacency accumulation ----------------
__global__ __launch_bounds__(256) void adj_kernel(const float* __restrict__ assn,
                                                  const int* __restrict__ src,
                                                  const int* __restrict__ dst,
                                                  float* __restrict__ adjp) {
    int t = threadIdx.x;
    float p00 = 0.f, p01 = 0.f, p10 = 0.f, p11 = 0.f;
    for (int e = blockIdx.x * 256 + t; e < NE; e += ADJ_BLOCKS * 256) {
        float2 a = *(const float2*)(assn + 2 * (size_t)src[e]);
        float2 b = *(const float2*)(assn + 2 * (size_t)dst[e]);
        p00 += a.x * b.x; p01 += a.x * b.y; p10 += a.y * b.x; p11 += a.y * b.y;
    }
    __shared__ float s0[256], s1[256], s2[256], s3[256];
    s0[t] = p00; s1[t] = p01; s2[t] = p10; s3[t] = p11;
    __syncthreads();
    for (int s = 128; s > 0; s >>= 1) {
        if (t < s) { s0[t] += s0[t + s]; s1[t] += s1[t + s]; s2[t] += s2[t + s]; s3[t] += s3[t + s]; }
        __syncthreads();
    }
    if (t == 0) {
        float4* o = (float4*)(adjp + 4 * (size_t)blockIdx.x);
        *o = make_float4(s0[0], s1[0], s2[0], s3[0]);
    }
}

// ---------------- final scalars ----------------
__global__ __launch_bounds__(256) void final_scalar_kernel(const float* __restrict__ kpart,
                                                           const float* __restrict__ adjp,
                                                           float* __restrict__ out) {
    __shared__ float sh[6 * 256];
    int t = threadIdx.x;
    float k1 = 0.f, k2 = 0.f, a0 = 0.f, a1 = 0.f, a2 = 0.f, a3 = 0.f;
    for (int i = t; i < NOISY_BLOCKS; i += 256) {
        float2 v = ((const float2*)kpart)[i];
        k1 += v.x; k2 += v.y;
    }
    for (int i = t; i < ADJ_BLOCKS; i += 256) {
        float4 v = ((const float4*)adjp)[i];
        a0 += v.x; a1 += v.y; a2 += v.z; a3 += v.w;
    }
    sh[t] = k1; sh[256 + t] = k2; sh[512 + t] = a0;
    sh[768 + t] = a1; sh[1024 + t] = a2; sh[1280 + t] = a3;
    __syncthreads();
    for (int s = 128; s > 0; s >>= 1) {
        if (t < s) {
#pragma unroll
            for (int v = 0; v < 6; v++) sh[v * 256 + t] += sh[v * 256 + t + s];
        }
        __syncthreads();
    }
    if (t == 0) {
        float kl = 0.5f / ((float)NND * (float)DIM) * sh[0] + (1.0f / (float)DIM) * sh[256];
        out[16896] = kl;
        float a00 = sh[512], a01 = sh[768], a10 = sh[1024], a11 = sh[1280];
        float r0 = fmaxf(fabsf(a00) + fabsf(a01), 1e-12f);
        float r1 = fmaxf(fabsf(a10) + fabsf(a11), 1e-12f);
        float d0 = a00 / r0 - 1.f, d1 = a11 / r1 - 1.f;
        out[16897] = 0.5f * (d0 * d0 + d1 * d1);
    }
}

// ---------------- launcher ----------------
extern "C" void kernel_launch(void* const* d_in, const int* in_sizes, int n_in,
                              void* d_out, int out_size, void* d_ws, size_t ws_size,
                              hipStream_t stream) {
    (void)in_sizes; (void)n_in; (void)out_size; (void)ws_size;
    const float* x     = (const float*)d_in[0];
    const int*   ei    = (const int*)d_in[1];
    const int*   batch = (const int*)d_in[2];
    const float* W0a   = (const float*)d_in[3];
    const float* W0b   = (const float*)d_in[4];
    const float* g0    = (const float*)d_in[5];
    const float* b0    = (const float*)d_in[6];
    const float* W1a   = (const float*)d_in[7];
    const float* W1b   = (const float*)d_in[8];
    const float* g1    = (const float*)d_in[9];
    const float* b1    = (const float*)d_in[10];
    const float* Wm0   = (const float*)d_in[11];
    const float* bm0   = (const float*)d_in[12];
    const float* gm    = (const float*)d_in[13];
    const float* bm    = (const float*)d_in[14];
    const float* Wm1   = (const float*)d_in[15];
    const float* bm1   = (const float*)d_in[16];
    const float* Wfc1  = (const float*)d_in[17];
    const float* bfc1  = (const float*)d_in[18];
    const float* Wfc2  = (const float*)d_in[19];
    const float* bfc2  = (const float*)d_in[20];
    const float* protos= (const float*)d_in[21];
    const float* Wlast = (const float*)d_in[22];
    const int* src = ei;
    const int* dst = ei + NE;
    float* out = (float*)d_out;

    // f32 region
    float* nodef = (float*)d_ws;                    // N*128 (node_feature, f32)
    float* abuf  = nodef + (size_t)NND * DIM;       // N*128 (a1, then noisy)
    float* lam   = abuf + (size_t)NND * DIM;        // N*2
    float* assn  = lam + (size_t)NND * 2;           // N*2
    float* cs    = assn + (size_t)NND * 2;          // 1024
    float* kpart = cs + 1024;                       // NOISY_BLOCKS*2
    float* adjp  = kpart + NOISY_BLOCKS * 2;        // ADJ_BLOCKS*4
    float* sscr  = adjp + ADJ_BLOCKS * 4;           // SROWS*256
    float* gpart = sscr + (size_t)SROWS * 256;      // NG*EMB_SPLIT*DIM
    // bf16 region
    ushort* aggH = (ushort*)(gpart + NG * EMB_SPLIT * DIM);  // N*128
    ushort* xnfH = aggH + (size_t)NND * DIM;                 // N*128
    ushort* tBH  = xnfH + (size_t)NND * DIM;                 // N*128
    ushort* tAH  = tBH + (size_t)NND * DIM;                  // N*128
    ushort* ndH  = tAH + (size_t)NND * DIM;                  // N*128
    ushort* t5H  = ndH + (size_t)NND * DIM;                  // N*64
    // int region
    int* deg    = (int*)(t5H + (size_t)NND * HID);
    int* offv   = deg + NND;
    int* cursor = offv + NND + 1;
    int* elist  = cursor + NND;
    int* gstart = elist + NE;
    int* bsum   = gstart + NG + 1;
    int* boff   = bsum + NSCB;

    // threefry keys on host: key(42) = (0,42); partitionable fold-like split
    uint32_t kg0 = 0u, kg1 = 0u; threefry2x32(0u, 42u, kg0, kg1);  // ctr (0,0)
    uint32_t kn0 = 0u, kn1 = 1u; threefry2x32(0u, 42u, kn0, kn1);  // ctr (0,1)

    hipMemsetAsync(deg, 0, NND * sizeof(int), stream);

    // CSR (shared by both GIN layers)
    hist_kernel<<<(NE + 255) / 256, 256, 0, stream>>>(dst, deg);
    scan_bsum_kernel<<<NSCB, 256, 0, stream>>>(deg, bsum);
    scan_boff_kernel<<<1, 256, 0, stream>>>(bsum, boff, offv);
    scan_final_kernel<<<NSCB, 256, 0, stream>>>(deg, boff, offv, cursor);
    build_kernel<<<(NE + 255) / 256, 256, 0, stream>>>(src, dst, cursor, elist);

    dim3 g2(SROWS, 2), g1x(SROWS, 1);
    const int CVB = (NND * DIM / 8 + 255) / 256;   // 2500 convert blocks
    const int GAB = NND / 4;                        // gather blocks (wave/node)

    // GIN layer 1
    cvt_kernel<<<CVB, 256, 0, stream>>>(x, xnfH);
    gather_kernel<<<GAB, 256, 0, stream>>>(xnfH, offv, elist, aggH);
    mgemm_kernel<128,128,1,0,0,0><<<g2, 256, 0, stream>>>(aggH, W0a, nullptr, nullptr, tBH, nullptr, nullptr, nullptr, NND);
    mgemm_kernel<128,128,1,1,0,0><<<g2, 256, 0, stream>>>(tBH, W0b, nullptr, nullptr, tAH, sscr, nullptr, nullptr, NND);
    stats_reduce_kernel<128><<<16, 256, 0, stream>>>(sscr, SROWS, g0, b0, cs + 0, 1);   // affine0

    // GIN layer 2
    cvt_affine_kernel<<<CVB, 256, 0, stream>>>(tAH, cs + 0, xnfH);   // nf1 bf16
    gather_kernel<<<GAB, 256, 0, stream>>>(xnfH, offv, elist, aggH);
    mgemm_kernel<128,128,1,0,0,0><<<g2, 256, 0, stream>>>(aggH, W1a, nullptr, nullptr, tBH, nullptr, nullptr, nullptr, NND);
    mgemm_kernel<128,128,1,1,0,0><<<g2, 256, 0, stream>>>(tBH, W1b, nullptr, nullptr, tAH, sscr, nullptr, nullptr, NND);
    stats_reduce_kernel<128><<<16, 256, 0, stream>>>(sscr, SROWS, g1, b1, cs + 256, 1); // affine1

    // bottleneck MLP
    mgemm_kernel<128,64,0,1,1,0><<<g1x, 256, 0, stream>>>(tAH, Wm0, bm0, nullptr, t5H, sscr, cs + 256, cs + 384, NND);
    stats_reduce_kernel<64><<<8, 256, 0, stream>>>(sscr, SROWS, gm, bm, cs + 512, 1);   // affine2
    mgemm_kernel<64,128,0,1,2,2><<<g2, 256, 0, stream>>>(t5H, Wm1, bm1, nodef, ndH, sscr, cs + 512, cs + 576, NND); // node_feature
    stats_reduce_kernel<128><<<16, 256, 0, stream>>>(sscr, SROWS, nullptr, nullptr, cs + 640, 0); // raw sums
    mgemm_kernel<128,128,2,0,0,1><<<g2, 256, 0, stream>>>(ndH, Wfc1, bfc1, abuf, nullptr, nullptr, nullptr, nullptr, NND); // a1

    // assignment + gumbel
    assign_kernel<<<(NND + 255) / 256, 256, 0, stream>>>(abuf, Wfc2, bfc2, assn, lam, kg0, kg1);

    // noisy features (into abuf, a1 is dead) + kl partials
    noisy_kernel<<<NOISY_BLOCKS, 256, 0, stream>>>(nodef, lam, cs + 640, abuf, kpart, kn0, kn1);

    // graph pooling + head
    gstart_kernel<<<(NND + 255) / 256, 256, 0, stream>>>(batch, gstart);
    graph_emb_part_kernel<<<NG * EMB_SPLIT, 128, 0, stream>>>(abuf, gstart, gpart);
    graph_emb_reduce_kernel<<<NG, 128, 0, stream>>>(gpart, gstart, out + 512);
    head_kernel<<<NG, 64, 0, stream>>>(out + 512, protos, Wlast,
                                       out, out + 256, out + 16898, out + 18178);

    // penalties
    adj_kernel<<<ADJ_BLOCKS, 256, 0, stream>>>(assn, src, dst, adjp);
    final_scalar_kernel<<<1, 256, 0, stream>>>(kpart, adjp, out);
}

// Round 12
// 300.553 us; speedup vs baseline: 2.9663x; 1.0588x over previous
//
#include <hip/hip_runtime.h>
#include <hip/hip_bf16.h>
#include <stdint.h>

#define NND 40000
#define NE  640000
#define NG  128
#define DIM 128
#define HID 64
#define ADJ_BLOCKS 640
#define NOISY_BLOCKS 5000   // NND*32/256
#define NSCB ((NND + 255) / 256)   // 157 scan blocks
#define EMB_SPLIT 8
#define SROWS 313            // gemm row blocks (128 rows each) = stats rows

typedef short v8s __attribute__((ext_vector_type(8)));
typedef float v4f __attribute__((ext_vector_type(4)));

// ---------------- threefry2x32 (20 rounds), JAX-compatible ----------------
__host__ __device__ inline uint32_t rotl32(uint32_t v, uint32_t r) {
    return (v << r) | (v >> (32u - r));
}

__host__ __device__ inline void threefry2x32(uint32_t k0, uint32_t k1,
                                             uint32_t& x0, uint32_t& x1) {
    uint32_t k2 = k0 ^ k1 ^ 0x1BD11BDAu;
    x0 += k0; x1 += k1;
#define TFR(r) { x0 += x1; x1 = rotl32(x1, r); x1 ^= x0; }
    TFR(13u) TFR(15u) TFR(26u) TFR(6u)
    x0 += k1; x1 += k2 + 1u;
    TFR(17u) TFR(29u) TFR(16u) TFR(24u)
    x0 += k2; x1 += k0 + 2u;
    TFR(13u) TFR(15u) TFR(26u) TFR(6u)
    x0 += k0; x1 += k1 + 3u;
    TFR(17u) TFR(29u) TFR(16u) TFR(24u)
    x0 += k1; x1 += k2 + 4u;
    TFR(13u) TFR(15u) TFR(26u) TFR(6u)
    x0 += k2; x1 += k0 + 5u;
#undef TFR
}

// partitionable-mode random bits -> uniform [0,1)
__device__ inline float rbits_u01(uint32_t k0, uint32_t k1, uint32_t idx) {
    uint32_t x0 = 0u, x1 = idx;
    threefry2x32(k0, k1, x0, x1);
    uint32_t b = x0 ^ x1;
    return __uint_as_float((b >> 9) | 0x3f800000u) - 1.0f;
}

__device__ inline ushort bfbits(float a) {
    __hip_bfloat16 h = __float2bfloat16(a);
    return *(ushort*)&h;
}

__device__ inline uint32_t bfpack(float a, float b) {
    return (uint32_t)bfbits(a) | ((uint32_t)bfbits(b) << 16);
}

// unpack 8 bf16 (uint4) -> 8 f32
#define UNPACK8(v, f)                                                     \
    f[0] = __uint_as_float((v).x << 16); f[1] = __uint_as_float((v).x & 0xffff0000u); \
    f[2] = __uint_as_float((v).y << 16); f[3] = __uint_as_float((v).y & 0xffff0000u); \
    f[4] = __uint_as_float((v).z << 16); f[5] = __uint_as_float((v).z & 0xffff0000u); \
    f[6] = __uint_as_float((v).w << 16); f[7] = __uint_as_float((v).w & 0xffff0000u);

// ---------------- CSR build ----------------
__global__ __launch_bounds__(256) void hist_kernel(const int* __restrict__ dst,
                                                   int* __restrict__ deg) {
    int e = blockIdx.x * 256 + threadIdx.x;
    if (e < NE) atomicAdd(&deg[dst[e]], 1);
}

__global__ __launch_bounds__(256) void scan_bsum_kernel(const int* __restrict__ deg,
                                                        int* __restrict__ bsum) {
    int t = threadIdx.x;
    int i = blockIdx.x * 256 + t;
    int v = (i < NND) ? deg[i] : 0;
    __shared__ int sh[256];
    sh[t] = v;
    __syncthreads();
#pragma unroll
    for (int s = 128; s > 0; s >>= 1) {
        if (t < s) sh[t] += sh[t + s];
        __syncthreads();
    }
    if (t == 0) bsum[blockIdx.x] = sh[0];
}

__global__ __launch_bounds__(256) void scan_boff_kernel(const int* __restrict__ bsum,
                                                        int* __restrict__ boff,
                                                        int* __restrict__ offv) {
    int t = threadIdx.x;
    int v = (t < NSCB) ? bsum[t] : 0;
    __shared__ int sh[256];
    sh[t] = v;
    __syncthreads();
    for (int d = 1; d < 256; d <<= 1) {
        int u = (t >= d) ? sh[t - d] : 0;
        __syncthreads();
        sh[t] += u;
        __syncthreads();
    }
    if (t < NSCB) boff[t] = sh[t] - v;   // exclusive
    if (t == NSCB - 1) offv[NND] = sh[t];
}

__global__ __launch_bounds__(256) void scan_final_kernel(const int* __restrict__ deg,
                                                         const int* __restrict__ boff,
                                                         int* __restrict__ offv,
                                                         int* __restrict__ cursor) {
    int t = threadIdx.x;
    int i = blockIdx.x * 256 + t;
    int v = (i < NND) ? deg[i] : 0;
    __shared__ int sh[256];
    sh[t] = v;
    __syncthreads();
    for (int d = 1; d < 256; d <<= 1) {
        int u = (t >= d) ? sh[t - d] : 0;
        __syncthreads();
        sh[t] += u;
        __syncthreads();
    }
    int off = boff[blockIdx.x] + sh[t] - v;   // exclusive prefix
    if (i < NND) { offv[i] = off; cursor[i] = off; }
}

__global__ __launch_bounds__(256) void build_kernel(const int* __restrict__ src,
                                                    const int* __restrict__ dst,
                                                    int* __restrict__ cursor,
                                                    int* __restrict__ elist) {
    int e = blockIdx.x * 256 + threadIdx.x;
    if (e < NE) {
        int p = atomicAdd(&cursor[dst[e]], 1);
        elist[p] = src[e];
    }
}

// ---------------- f32 -> bf16 convert (x) ----------------
__global__ __launch_bounds__(256) void cvt_kernel(const float* __restrict__ in,
                                                  ushort* __restrict__ outh) {
    int i = blockIdx.x * 256 + threadIdx.x;    // per 8 elements
    if (i >= NND * DIM / 8) return;
    const float4* p = (const float4*)in + (size_t)i * 2;
    float4 a = p[0], b = p[1];
    uint4 o;
    o.x = bfpack(a.x, a.y); o.y = bfpack(a.z, a.w);
    o.z = bfpack(b.x, b.y); o.w = bfpack(b.z, b.w);
    *(uint4*)(outh + (size_t)i * 8) = o;
}

// ---------------- gather: wave/node, 4 edge-slots x 16 col-slots; bf16 in/out.
// AFF=1: apply per-column affine+relu to each loaded element (BN fold).
template <int AFF>
__global__ __launch_bounds__(256) void gather_kernel(const ushort* __restrict__ feath,
                                                     const int* __restrict__ offv,
                                                     const int* __restrict__ elist,
                                                     ushort* __restrict__ aggh,
                                                     const float* __restrict__ cs) {
    int gt = blockIdx.x * 256 + threadIdx.x;
    int n = gt >> 6;
    int lane = threadIdx.x & 63;
    int e = lane >> 4, c = lane & 15;
    const uint4* F = (const uint4*)feath;
    int o0 = offv[n], o1 = offv[n + 1];

    float sc[8], sh[8];
    if (AFF) {
#pragma unroll
        for (int j = 0; j < 8; j++) {
            sc[j] = cs[c * 8 + j];
            sh[j] = cs[DIM + c * 8 + j];
        }
    }

    float acc[8];
    if (e == 0) {                        // self term, counted once
        uint4 v = F[(size_t)n * 16 + c];
        UNPACK8(v, acc)
        if (AFF) {
#pragma unroll
            for (int j = 0; j < 8; j++) acc[j] = fmaxf(fmaf(acc[j], sc[j], sh[j]), 0.f);
        }
    } else {
#pragma unroll
        for (int j = 0; j < 8; j++) acc[j] = 0.f;
    }

    for (int i = o0 + e; i < o1; i += 4) {
        int s = elist[i];
        uint4 v = F[(size_t)s * 16 + c];
        float f[8];
        UNPACK8(v, f)
        if (AFF) {
#pragma unroll
            for (int j = 0; j < 8; j++) f[j] = fmaxf(fmaf(f[j], sc[j], sh[j]), 0.f);
        }
#pragma unroll
        for (int j = 0; j < 8; j++) acc[j] += f[j];
    }

#pragma unroll
    for (int j = 0; j < 8; j++) {
        acc[j] += __shfl_xor(acc[j], 16);
        acc[j] += __shfl_xor(acc[j], 32);
    }

    uint32_t wv;
    if (e == 0)      wv = bfpack(acc[0], acc[1]);
    else if (e == 1) wv = bfpack(acc[2], acc[3]);
    else if (e == 2) wv = bfpack(acc[4], acc[5]);
    else             wv = bfpack(acc[6], acc[7]);
    ((uint32_t*)aggh)[(size_t)n * 64 + c * 4 + e] = wv;
}

// ---------------- fused GIN double-GEMM: out = relu(relu(A@Wa)@Wb), + stats ----
// A bf16 N x 128. Block 256 thr (4 waves); tile 128 rows x 128 cols.
// Wave w owns rows w*32..+31 (2 row-frags x 8 col-frags of 16x16).
// LDS (dynamic 68KB): B1 = Wa^T bf16 [c][k] then h1 [r][k]; B2 = Wb^T [c][k].
__global__ __launch_bounds__(256) void gin2_kernel(const ushort* __restrict__ Ah,
                                                   const float* __restrict__ Wa,
                                                   const float* __restrict__ Wb,
                                                   ushort* __restrict__ outh,
                                                   float* __restrict__ sscr,
                                                   int nrows) {
    constexpr int K = 128, KP = 136;
    extern __shared__ ushort lds[];
    ushort* B1 = lds;                 // KP*128
    ushort* B2 = lds + 128 * KP;      // KP*128

    const int t = threadIdx.x;
    const int w = t >> 6, l = t & 63;
    const int lm = l & 15, lk = l >> 4;
    const int row0 = blockIdx.x * 128 + w * 32;

    // A-frag loads up-front (overlap with W staging)
    uint4 areg[2][4];
#pragma unroll
    for (int rf = 0; rf < 2; rf++) {
        int r = row0 + rf * 16 + lm;
        const ushort* ap = Ah + (size_t)min(r, nrows - 1) * K + lk * 8;
#pragma unroll
        for (int kc = 0; kc < 4; kc++)
            areg[rf][kc] = *(const uint4*)(ap + kc * 32);
    }

    // stage Wa, Wb transposed + converted: B[c*KP + k]
    for (int idx = t; idx < K * K; idx += 256) {
        int k = idx >> 7, c = idx & 127;
        B1[c * KP + k] = bfbits(Wa[idx]);
        B2[c * KP + k] = bfbits(Wb[idx]);
    }
    __syncthreads();

    // GEMM1: h1 = A @ Wa
    v4f acc[2][8];
#pragma unroll
    for (int i = 0; i < 2; i++)
#pragma unroll
        for (int j = 0; j < 8; j++) acc[i][j] = (v4f){0.f, 0.f, 0.f, 0.f};

#pragma unroll
    for (int kc = 0; kc < 4; kc++) {
        v8s a0 = *(const v8s*)&areg[0][kc];
        v8s a1 = *(const v8s*)&areg[1][kc];
#pragma unroll
        for (int nc = 0; nc < 8; nc++) {
            v8s bfr = *(const v8s*)(B1 + (nc * 16 + lm) * KP + kc * 32 + lk * 8);
            acc[0][nc] = __builtin_amdgcn_mfma_f32_16x16x32_bf16(a0, bfr, acc[0][nc], 0, 0, 0);
            acc[1][nc] = __builtin_amdgcn_mfma_f32_16x16x32_bf16(a1, bfr, acc[1][nc], 0, 0, 0);
        }
    }

    __syncthreads();   // all waves done reading Wa from B1
    // write h1 = relu(acc) bf16 into B1[r][k] (C-layout -> row-major redistribution)
#pragma unroll
    for (int rf = 0; rf < 2; rf++)
#pragma unroll
        for (int nc = 0; nc < 8; nc++)
#pragma unroll
            for (int reg = 0; reg < 4; reg++) {
                int r = w * 32 + rf * 16 + lk * 4 + reg;
                int c = nc * 16 + lm;
                B1[r * KP + c] = bfbits(fmaxf(acc[rf][nc][reg], 0.f));
            }
    __syncthreads();

    // GEMM2: out = h1 @ Wb
    v4f acc2[2][8];
#pragma unroll
    for (int i = 0; i < 2; i++)
#pragma unroll
        for (int j = 0; j < 8; j++) acc2[i][j] = (v4f){0.f, 0.f, 0.f, 0.f};

#pragma unroll
    for (int kc = 0; kc < 4; kc++) {
        v8s a0 = *(const v8s*)(B1 + (w * 32 + lm) * KP + kc * 32 + lk * 8);
        v8s a1 = *(const v8s*)(B1 + (w * 32 + 16 + lm) * KP + kc * 32 + lk * 8);
#pragma unroll
        for (int nc = 0; nc < 8; nc++) {
            v8s bfr = *(const v8s*)(B2 + (nc * 16 + lm) * KP + kc * 32 + lk * 8);
            acc2[0][nc] = __builtin_amdgcn_mfma_f32_16x16x32_bf16(a0, bfr, acc2[0][nc], 0, 0, 0);
            acc2[1][nc] = __builtin_amdgcn_mfma_f32_16x16x32_bf16(a1, bfr, acc2[1][nc], 0, 0, 0);
        }
    }

    // epilogue: relu, bf16 store, column stats
    float ps[8], pq[8];
#pragma unroll
    for (int nc = 0; nc < 8; nc++) { ps[nc] = 0.f; pq[nc] = 0.f; }

#pragma unroll
    for (int nc = 0; nc < 8; nc++) {
        int cg = nc * 16 + lm;
#pragma unroll
        for (int rf = 0; rf < 2; rf++)
#pragma unroll
            for (int reg = 0; reg < 4; reg++) {
                int rg = row0 + rf * 16 + lk * 4 + reg;
                if (rg < nrows) {
                    float v = fmaxf(acc2[rf][nc][reg], 0.f);
                    outh[(size_t)rg * K + cg] = bfbits(v);
                    ps[nc] += v; pq[nc] += v * v;
                }
            }
    }

    __syncthreads();
    float* scr = (float*)lds;    // 1024 floats
#pragma unroll
    for (int nc = 0; nc < 8; nc++) {
        ps[nc] += __shfl_xor(ps[nc], 16); ps[nc] += __shfl_xor(ps[nc], 32);
        pq[nc] += __shfl_xor(pq[nc], 16); pq[nc] += __shfl_xor(pq[nc], 32);
    }
    if (lk == 0) {
#pragma unroll
        for (int nc = 0; nc < 8; nc++) {
            scr[w * 128 + nc * 16 + lm]       = ps[nc];
            scr[512 + w * 128 + nc * 16 + lm] = pq[nc];
        }
    }
    __syncthreads();
    if (t < 128) {
        float s = scr[t] + scr[128 + t] + scr[256 + t] + scr[384 + t];
        float q = scr[512 + t] + scr[640 + t] + scr[768 + t] + scr[896 + t];
        sscr[(size_t)blockIdx.x * 256 + t]       = s;
        sscr[(size_t)blockIdx.x * 256 + 128 + t] = q;
    }
}

// ---------------- MFMA GEMM (single): out = ACT(PRE(A) @ bf16(W) [+ bias]) ------
// Block 256 thr = 4 waves; tile 128 rows x 64 cols (grid.y = M/64).
// PRE: 0 none, 1 affine(scale,shift per k), 2 affine+relu.
// ACT: 0 none, 1 relu, 2 tanh.  OUTM: 0 bf16->outh, 1 f32->outf, 2 both.
template <int K, int M, int ACT, int STATS, int PRE, int OUTM>
__global__ __launch_bounds__(256) void mgemm_kernel(const ushort* __restrict__ Ah,
                                                    const float* __restrict__ W,
                                                    const float* __restrict__ bias,
                                                    float* __restrict__ outf,
                                                    ushort* __restrict__ outh,
                                                    float* __restrict__ sscr,
                                                    const float* __restrict__ pscale,
                                                    const float* __restrict__ pshift,
                                                    int nrows) {
    constexpr int KP  = K + 8;
    constexpr int NKC = K / 32;
    __shared__ __align__(16) ushort sW[64 * KP];

    const int t = threadIdx.x;
    const int w = t >> 6, l = t & 63;
    const int lm = l & 15, lk = l >> 4;
    const int col0 = blockIdx.y * 64;
    const int row0 = blockIdx.x * 128 + w * 32;

    // stage W col-slice, converted + transposed: sW[c][k]
    for (int idx = t; idx < K * 64; idx += 256) {
        int k = idx >> 6, c = idx & 63;
        sW[c * KP + k] = bfbits(W[(size_t)k * M + col0 + c]);
    }

    uint4 areg[2][NKC];
#pragma unroll
    for (int rf = 0; rf < 2; rf++) {
        int r = row0 + rf * 16 + lm;
        const ushort* ap = Ah + (size_t)min(r, nrows - 1) * K + lk * 8;
#pragma unroll
        for (int kc = 0; kc < NKC; kc++)
            areg[rf][kc] = *(const uint4*)(ap + kc * 32);
    }

    __syncthreads();

    v4f acc[2][4];
#pragma unroll
    for (int i = 0; i < 2; i++)
#pragma unroll
        for (int j = 0; j < 4; j++) acc[i][j] = (v4f){0.f, 0.f, 0.f, 0.f};

#pragma unroll
    for (int kc = 0; kc < NKC; kc++) {
        v8s bfr[4];
#pragma unroll
        for (int nc = 0; nc < 4; nc++)
            bfr[nc] = *(const v8s*)(sW + (nc * 16 + lm) * KP + kc * 32 + lk * 8);

        v8s afr[2];
#pragma unroll
        for (int rf = 0; rf < 2; rf++) {
            if (PRE > 0) {
                int k0 = kc * 32 + lk * 8;
                float f[8];
                uint4 v = areg[rf][kc];
                UNPACK8(v, f)
                float4 s0 = *(const float4*)(pscale + k0);
                float4 s1 = *(const float4*)(pscale + k0 + 4);
                float4 h0 = *(const float4*)(pshift + k0);
                float4 h1 = *(const float4*)(pshift + k0 + 4);
                f[0] = fmaf(f[0], s0.x, h0.x); f[1] = fmaf(f[1], s0.y, h0.y);
                f[2] = fmaf(f[2], s0.z, h0.z); f[3] = fmaf(f[3], s0.w, h0.w);
                f[4] = fmaf(f[4], s1.x, h1.x); f[5] = fmaf(f[5], s1.y, h1.y);
                f[6] = fmaf(f[6], s1.z, h1.z); f[7] = fmaf(f[7], s1.w, h1.w);
                if (PRE == 2) {
#pragma unroll
                    for (int e2 = 0; e2 < 8; e2++) f[e2] = fmaxf(f[e2], 0.f);
                }
                v8s a;
#pragma unroll
                for (int e2 = 0; e2 < 8; e2++) a[e2] = (short)bfbits(f[e2]);
                afr[rf] = a;
            } else {
                afr[rf] = *(const v8s*)&areg[rf][kc];
            }
        }

#pragma unroll
        for (int rf = 0; rf < 2; rf++)
#pragma unroll
            for (int nc = 0; nc < 4; nc++)
                acc[rf][nc] = __builtin_amdgcn_mfma_f32_16x16x32_bf16(
                    afr[rf], bfr[nc], acc[rf][nc], 0, 0, 0);
    }

    float ps[4], pq[4];
#pragma unroll
    for (int nc = 0; nc < 4; nc++) { ps[nc] = 0.f; pq[nc] = 0.f; }

#pragma unroll
    for (int nc = 0; nc < 4; nc++) {
        int cg = col0 + nc * 16 + lm;
        float bv = bias ? bias[cg] : 0.f;
#pragma unroll
        for (int rf = 0; rf < 2; rf++) {
#pragma unroll
            for (int reg = 0; reg < 4; reg++) {
                int rg = row0 + rf * 16 + lk * 4 + reg;
                if (rg < nrows) {
                    float v = acc[rf][nc][reg] + bv;
                    if (ACT == 1) v = fmaxf(v, 0.f);
                    if (ACT == 2) v = tanhf(v);
                    if (OUTM != 0) outf[(size_t)rg * M + cg] = v;
                    if (OUTM != 1) outh[(size_t)rg * M + cg] = bfbits(v);
                    ps[nc] += v; pq[nc] += v * v;
                }
            }
        }
    }

    if (STATS) {
        __syncthreads();
        float* scr = (float*)sW;
#pragma unroll
        for (int nc = 0; nc < 4; nc++) {
            ps[nc] += __shfl_xor(ps[nc], 16); ps[nc] += __shfl_xor(ps[nc], 32);
            pq[nc] += __shfl_xor(pq[nc], 16); pq[nc] += __shfl_xor(pq[nc], 32);
        }
        if (lk == 0) {
#pragma unroll
            for (int nc = 0; nc < 4; nc++) {
                scr[w * 64 + nc * 16 + lm]       = ps[nc];
                scr[256 + w * 64 + nc * 16 + lm] = pq[nc];
            }
        }
        __syncthreads();
        if (t < 64) {
            float s = scr[t] + scr[64 + t] + scr[128 + t] + scr[192 + t];
            float q = scr[256 + t] + scr[320 + t] + scr[384 + t] + scr[448 + t];
            sscr[(size_t)blockIdx.x * 2 * M + col0 + t]     = s;
            sscr[(size_t)blockIdx.x * 2 * M + M + col0 + t] = q;
        }
    }
}

// reduce stats partials; affine=1: write (scale, shift); else raw (sum,sumsq).
template <int M>
__global__ __launch_bounds__(256) void stats_reduce_kernel(const float* __restrict__ sscr,
                                                           int nblk,
                                                           const float* __restrict__ g,
                                                           const float* __restrict__ b,
                                                           float* __restrict__ cs,
                                                           int affine) {
    const int cols = 2 * M;
    const int t = threadIdx.x;
    const int c = blockIdx.x * 8 + (t & 7);
    const int rl = t >> 3;
    float s = 0.f, q = 0.f;
    for (int r = rl; r < nblk; r += 32) {
        s += sscr[(size_t)r * cols + c];
        q += sscr[(size_t)r * cols + M + c];
    }
    __shared__ float shs[256], shq[256];
    shs[t] = s; shq[t] = q;
    __syncthreads();
#pragma unroll
    for (int st = 128; st >= 8; st >>= 1) {
        if (t < st) { shs[t] += shs[t + st]; shq[t] += shq[t + st]; }
        __syncthreads();
    }
    if (t < 8) {
        float ss = shs[t], qq = shq[t];
        if (affine) {
            const float invN = 1.0f / (float)NND;
            float mu = ss * invN;
            float var = fmaxf(qq * invN - mu * mu, 0.f);
            float sc = g[c] * rsqrtf(var + 1e-5f);
            cs[c] = sc;
            cs[M + c] = b[c] - mu * sc;
        } else {
            cs[c] = ss;
            cs[M + c] = qq;
        }
    }
}

// ---------------- assignment / gumbel-softmax lambdas (bf16 a1) ----------------
__global__ __launch_bounds__(256) void assign_kernel(const ushort* __restrict__ a1h,
                                                     const float* __restrict__ Wfc2,
                                                     const float* __restrict__ bfc2,
                                                     float* __restrict__ assn,
                                                     float* __restrict__ lam,
                                                     uint32_t kg0, uint32_t kg1) {
    __shared__ float w[DIM * 2];
    int t = threadIdx.x;
    w[t] = Wfc2[t];
    __syncthreads();
    int n = blockIdx.x * 256 + t;
    if (n >= NND) return;

    float d0 = bfc2[0], d1 = bfc2[1];
    const uint4* row = (const uint4*)(a1h + (size_t)n * DIM);
#pragma unroll 4
    for (int k8 = 0; k8 < DIM / 8; k8++) {
        uint4 v = row[k8];
        float f[8];
        UNPACK8(v, f)
#pragma unroll
        for (int j = 0; j < 8; j++) {
            d0 = fmaf(f[j], w[(k8 * 8 + j) * 2], d0);
            d1 = fmaf(f[j], w[(k8 * 8 + j) * 2 + 1], d1);
        }
    }
    float m = fmaxf(d0, d1);
    float e0 = expf(d0 - m), e1 = expf(d1 - m);
    float inv = 1.f / (e0 + e1);
    float as0 = e0 * inv, as1 = e1 * inv;
    assn[2 * n] = as0; assn[2 * n + 1] = as1;

    float uf0 = rbits_u01(kg0, kg1, (uint32_t)(2 * n));
    float uf1 = rbits_u01(kg0, kg1, (uint32_t)(2 * n + 1));
    float u0 = fmaxf(1e-10f, uf0 + 1e-10f);
    float u1 = fmaxf(1e-10f, uf1 + 1e-10f);
    float gu0 = -logf(-logf(u0));
    float gu1 = -logf(-logf(u1));
    float y0 = as0 + gu0, y1 = as1 + gu1;
    float mm = fmaxf(y0, y1);
    float f0 = expf(y0 - mm), f1 = expf(y1 - mm);
    float iv = 1.f / (f0 + f1);
    lam[2 * n] = f0 * iv; lam[2 * n + 1] = f1 * iv;
}

// ---------------- noisy features + kl partial sums ----------------
__global__ __launch_bounds__(256) void noisy_kernel(const float* __restrict__ nfeat,
                                                    const float* __restrict__ lam,
                                                    const float* __restrict__ cs3,
                                                    float* __restrict__ noisy,
                                                    float* __restrict__ kpart,
                                                    uint32_t kn0, uint32_t kn1) {
    int gt = blockIdx.x * 256 + threadIdx.x;
    int n = gt >> 5, c4 = gt & 31, d = c4 * 4;
    const float invN = 1.0f / (float)NND;
    float la0 = lam[2 * n], la1 = lam[2 * n + 1];
    float4 xv = *(const float4*)(nfeat + (size_t)n * DIM + d);
    float xa[4] = {xv.x, xv.y, xv.z, xv.w};
    float t1 = 0.f, t2 = 0.f, o[4];
#pragma unroll
    for (int j = 0; j < 4; j++) {
        float mu = cs3[d + j] * invN;
        float q = cs3[DIM + d + j];
        float var1 = fmaxf(q - (float)NND * mu * mu, 0.f) / (float)(NND - 1);
        float sd = sqrtf(var1);
        float r = rbits_u01(kn0, kn1, (uint32_t)(n * DIM + d + j));
        float nm = la0 * xa[j] + la1 * mu;
        float ns = la1 * sd;
        o[j] = fmaf(r, ns, nm);
        float inv = 1.0f / (sd + 1e-7f);
        float z1 = ns * inv;            t1 += z1 * z1;
        float z2 = (nm - mu) * inv;     t2 += z2 * z2;
    }
    *(float4*)(noisy + (size_t)n * DIM + d) = make_float4(o[0], o[1], o[2], o[3]);

    __shared__ float s1[256], s2[256];
    int t = threadIdx.x;
    s1[t] = t1; s2[t] = t2;
    __syncthreads();
    for (int s = 128; s > 0; s >>= 1) {
        if (t < s) { s1[t] += s1[t + s]; s2[t] += s2[t + s]; }
        __syncthreads();
    }
    if (t == 0) { kpart[2 * blockIdx.x] = s1[0]; kpart[2 * blockIdx.x + 1] = s2[0]; }
}

// ---------------- graph segment starts (batch is sorted) ----------------
__global__ __launch_bounds__(256) void gstart_kernel(const int* __restrict__ batch,
                                                     int* __restrict__ gstart) {
    int i = blockIdx.x * 256 + threadIdx.x;
    if (i >= NND) return;
    int b = batch[i];
    int prev = (i == 0) ? -1 : batch[i - 1];
    for (int g = prev + 1; g <= b; g++) gstart[g] = i;
    if (i == NND - 1)
        for (int g = b + 1; g <= NG; g++) gstart[g] = NND;
}

// ---------------- graph mean pooling ----------------
__global__ __launch_bounds__(128) void graph_emb_part_kernel(const float* __restrict__ noisy,
                                                             const int* __restrict__ gstart,
                                                             float* __restrict__ gpart) {
    int g = blockIdx.x / EMB_SPLIT;
    int sidx = blockIdx.x % EMB_SPLIT;
    int c = threadIdx.x;
    int s = gstart[g], e = gstart[g + 1];
    int len = e - s;
    int chunk = (len + EMB_SPLIT - 1) / EMB_SPLIT;
    int r0 = s + sidx * chunk;
    int r1 = min(r0 + chunk, e);
    float acc = 0.f;
    for (int r = r0; r < r1; r++) acc += noisy[(size_t)r * DIM + c];
    gpart[((size_t)g * EMB_SPLIT + sidx) * DIM + c] = acc;
}

__global__ __launch_bounds__(128) void graph_emb_reduce_kernel(const float* __restrict__ gpart,
                                                               const int* __restrict__ gstart,
                                                               float* __restrict__ emb) {
    int g = blockIdx.x, c = threadIdx.x;
    float acc = 0.f;
#pragma unroll
    for (int si = 0; si < EMB_SPLIT; si++)
        acc += gpart[((size_t)g * EMB_SPLIT + si) * DIM + c];
    float cnt = (float)(gstart[g + 1] - gstart[g]);
    emb[(size_t)g * DIM + c] = acc / fmaxf(cnt, 1.f);
}

// ---------------- proto distances + final head ----------------
__global__ __launch_bounds__(64) void head_kernel(const float* __restrict__ emb,
                                                  const float* __restrict__ protos,
                                                  const float* __restrict__ Wlast,
                                                  float* __restrict__ out_logits,
                                                  float* __restrict__ out_probs,
                                                  float* __restrict__ out_sim,
                                                  float* __restrict__ out_dist) {
    int g = blockIdx.x, l = threadIdx.x;
    float ge0 = emb[(size_t)g * DIM + l];
    float ge1 = emb[(size_t)g * DIM + l + 64];
    float gn = ge0 * ge0 + ge1 * ge1;
    float dj[10], pj[10];
#pragma unroll
    for (int j = 0; j < 10; j++) {
        float pa = protos[j * DIM + l], pb = protos[j * DIM + l + 64];
        dj[j] = ge0 * pa + ge1 * pb;
        pj[j] = pa * pa + pb * pb;
    }
    float wl0 = ge0 * Wlast[10 + l] + ge1 * Wlast[10 + l + 64];
    float wl1 = ge0 * Wlast[138 + 10 + l] + ge1 * Wlast[138 + 10 + l + 64];
#pragma unroll
    for (int s = 32; s > 0; s >>= 1) {
        gn += __shfl_xor(gn, s);
        wl0 += __shfl_xor(wl0, s);
        wl1 += __shfl_xor(wl1, s);
#pragma unroll
        for (int j = 0; j < 10; j++) {
            dj[j] += __shfl_xor(dj[j], s);
            pj[j] += __shfl_xor(pj[j], s);
        }
    }
    if (l == 0) {
        float lg0 = wl0, lg1 = wl1;
#pragma unroll
        for (int j = 0; j < 10; j++) {
            float dist = -2.f * dj[j] + gn + pj[j];
            float sv = logf((dist + 1.0f) / (dist + 1e-4f));
            out_dist[g * 10 + j] = dist;
            out_sim[g * 10 + j] = sv;
            lg0 = fmaf(Wlast[j], sv, lg0);
            lg1 = fmaf(Wlast[138 + j], sv, lg1);
        }
        out_logits[2 * g] = lg0; out_logits[2 * g + 1] = lg1;
        float m = fmaxf(lg0, lg1);
        float e0 = expf(lg0 - m), e1 = expf(lg1 - m);
        float iv = 1.f / (e0 + e1);
        out_probs[2 * g] = e0 * iv; out_probs[2 * g + 1] = e1 * iv;
    }
}

// ---------------- 2x2 adjacency accumulation ----------------
__global__ __launch_bounds__(256) void adj_kernel(const float* __restrict__ assn,
                                                  const int* __restrict__ src,
                                                  const int* __restrict__ dst,
                                                  float* __restrict__ adjp) {
    int t = threadIdx.x;
    float p00 = 0.f, p01 = 0.f, p10 = 0.f, p11 = 0.f;
    for (int e = blockIdx.x * 256 + t; e < NE; e += ADJ_BLOCKS * 256) {
        float2 a = *(const float2*)(assn + 2 * (size_t)src[e]);
        float2 b = *(const float2*)(assn + 2 * (size_t)dst[e]);
        p00 += a.x * b.x; p01 += a.x * b.y; p10 += a.y * b.x; p11 += a.y * b.y;
    }
    __shared__ float s0[256], s1[256], s2[256], s3[256];
    s0[t] = p00; s1[t] = p01; s2[t] = p10; s3[t] = p11;
    __syncthreads();
    for (int s = 128; s > 0; s >>= 1) {
        if (t < s) { s0[t] += s0[t + s]; s1[t] += s1[t + s]; s2[t] += s2[t + s]; s3[t] += s3[t + s]; }
        __syncthreads();
    }
    if (t == 0) {
        float4* o = (float4*)(adjp + 4 * (size_t)blockIdx.x);
        *o = make_float4(s0[0], s1[0], s2[0], s3[0]);
    }
}

// ---------------- final scalars ----------------
__global__ __launch_bounds__(256) void final_scalar_kernel(const float* __restrict__ kpart,
                                                           const float* __restrict__ adjp,
                                                           float* __restrict__ out) {
    __shared__ float sh[6 * 256];
    int t = threadIdx.x;
    float k1 = 0.f, k2 = 0.f, a0 = 0.f, a1 = 0.f, a2 = 0.f, a3 = 0.f;
    for (int i = t; i < NOISY_BLOCKS; i += 256) {
        float2 v = ((const float2*)kpart)[i];
        k1 += v.x; k2 += v.y;
    }
    for (int i = t; i < ADJ_BLOCKS; i += 256) {
        float4 v = ((const float4*)adjp)[i];
        a0 += v.x; a1 += v.y; a2 += v.z; a3 += v.w;
    }
    sh[t] = k1; sh[256 + t] = k2; sh[512 + t] = a0;
    sh[768 + t] = a1; sh[1024 + t] = a2; sh[1280 + t] = a3;
    __syncthreads();
    for (int s = 128; s > 0; s >>= 1) {
        if (t < s) {
#pragma unroll
            for (int v = 0; v < 6; v++) sh[v * 256 + t] += sh[v * 256 + t + s];
        }
        __syncthreads();
    }
    if (t == 0) {
        float kl = 0.5f / ((float)NND * (float)DIM) * sh[0] + (1.0f / (float)DIM) * sh[256];
        out[16896] = kl;
        float a00 = sh[512], a01 = sh[768], a10 = sh[1024], a11 = sh[1280];
        float r0 = fmaxf(fabsf(a00) + fabsf(a01), 1e-12f);
        float r1 = fmaxf(fabsf(a10) + fabsf(a11), 1e-12f);
        float d0 = a00 / r0 - 1.f, d1 = a11 / r1 - 1.f;
        out[16897] = 0.5f * (d0 * d0 + d1 * d1);
    }
}

// ---------------- launcher ----------------
extern "C" void kernel_launch(void* const* d_in, const int* in_sizes, int n_in,
                              void* d_out, int out_size, void* d_ws, size_t ws_size,
                              hipStream_t stream) {
    (void)in_sizes; (void)n_in; (void)out_size; (void)ws_size;
    const float* x     = (const float*)d_in[0];
    const int*   ei    = (const int*)d_in[1];
    const int*   batch = (const int*)d_in[2];
    const float* W0a   = (const float*)d_in[3];
    const float* W0b   = (const float*)d_in[4];
    const float* g0    = (const float*)d_in[5];
    const float* b0    = (const float*)d_in[6];
    const float* W1a   = (const float*)d_in[7];
    const float* W1b   = (const float*)d_in[8];
    const float* g1    = (const float*)d_in[9];
    const float* b1    = (const float*)d_in[10];
    const float* Wm0   = (const float*)d_in[11];
    const float* bm0   = (const float*)d_in[12];
    const float* gm    = (const float*)d_in[13];
    const float* bm    = (const float*)d_in[14];
    const float* Wm1   = (const float*)d_in[15];
    const float* bm1   = (const float*)d_in[16];
    const float* Wfc1  = (const float*)d_in[17];
    const float* bfc1  = (const float*)d_in[18];
    const float* Wfc2  = (const float*)d_in[19];
    const float* bfc2  = (const float*)d_in[20];
    const float* protos= (const float*)d_in[21];
    const float* Wlast = (const float*)d_in[22];
    const int* src = ei;
    const int* dst = ei + NE;
    float* out = (float*)d_out;

    // f32 region
    float* nodef = (float*)d_ws;                    // N*128 (node_feature, f32)
    float* abuf  = nodef + (size_t)NND * DIM;       // N*128 (noisy)
    float* lam   = abuf + (size_t)NND * DIM;        // N*2
    float* assn  = lam + (size_t)NND * 2;           // N*2
    float* cs    = assn + (size_t)NND * 2;          // 1024
    float* kpart = cs + 1024;                       // NOISY_BLOCKS*2
    float* adjp  = kpart + NOISY_BLOCKS * 2;        // ADJ_BLOCKS*4
    float* sscr  = adjp + ADJ_BLOCKS * 4;           // SROWS*256
    float* gpart = sscr + (size_t)SROWS * 256;      // NG*EMB_SPLIT*DIM
    // bf16 region
    ushort* aggH = (ushort*)(gpart + NG * EMB_SPLIT * DIM);  // N*128
    ushort* xnfH = aggH + (size_t)NND * DIM;                 // N*128 (x bf16)
    ushort* tBH  = xnfH + (size_t)NND * DIM;                 // N*128 (a1)
    ushort* tAH  = tBH + (size_t)NND * DIM;                  // N*128
    ushort* ndH  = tAH + (size_t)NND * DIM;                  // N*128
    ushort* t5H  = ndH + (size_t)NND * DIM;                  // N*64
    // int region
    int* deg    = (int*)(t5H + (size_t)NND * HID);
    int* offv   = deg + NND;
    int* cursor = offv + NND + 1;
    int* elist  = cursor + NND;
    int* gstart = elist + NE;
    int* bsum   = gstart + NG + 1;
    int* boff   = bsum + NSCB;

    // threefry keys on host: key(42) = (0,42); partitionable fold-like split
    uint32_t kg0 = 0u, kg1 = 0u; threefry2x32(0u, 42u, kg0, kg1);  // ctr (0,0)
    uint32_t kn0 = 0u, kn1 = 1u; threefry2x32(0u, 42u, kn0, kn1);  // ctr (0,1)

    hipMemsetAsync(deg, 0, NND * sizeof(int), stream);

    // CSR (shared by both GIN layers)
    hist_kernel<<<(NE + 255) / 256, 256, 0, stream>>>(dst, deg);
    scan_bsum_kernel<<<NSCB, 256, 0, stream>>>(deg, bsum);
    scan_boff_kernel<<<1, 256, 0, stream>>>(bsum, boff, offv);
    scan_final_kernel<<<NSCB, 256, 0, stream>>>(deg, boff, offv, cursor);
    build_kernel<<<(NE + 255) / 256, 256, 0, stream>>>(src, dst, cursor, elist);

    dim3 g2(SROWS, 2), g1x(SROWS, 1);
    const int CVB = (NND * DIM / 8 + 255) / 256;   // 2500 convert blocks
    const int GAB = NND / 4;                        // gather blocks (wave/node)
    const size_t GIN_LDS = 2u * 128u * 136u * sizeof(ushort);   // 69632 B

    // GIN layer 1: x -> bf16 -> gather -> fused double GEMM
    cvt_kernel<<<CVB, 256, 0, stream>>>(x, xnfH);
    gather_kernel<0><<<GAB, 256, 0, stream>>>(xnfH, offv, elist, aggH, nullptr);
    gin2_kernel<<<SROWS, 256, GIN_LDS, stream>>>(aggH, W0a, W0b, tAH, sscr, NND);
    stats_reduce_kernel<128><<<16, 256, 0, stream>>>(sscr, SROWS, g0, b0, cs + 0, 1);   // affine0

    // GIN layer 2: gather reads tAH applying affine0+relu inline
    gather_kernel<1><<<GAB, 256, 0, stream>>>(tAH, offv, elist, aggH, cs + 0);
    gin2_kernel<<<SROWS, 256, GIN_LDS, stream>>>(aggH, W1a, W1b, tAH, sscr, NND);
    stats_reduce_kernel<128><<<16, 256, 0, stream>>>(sscr, SROWS, g1, b1, cs + 256, 1); // affine1

    // bottleneck MLP: affine1 folded into A-path (PRE=1); affine2+relu (PRE=2)
    mgemm_kernel<128,64,0,1,1,0><<<g1x, 256, 0, stream>>>(tAH, Wm0, bm0, nullptr, t5H, sscr, cs + 256, cs + 384, NND);
    stats_reduce_kernel<64><<<8, 256, 0, stream>>>(sscr, SROWS, gm, bm, cs + 512, 1);   // affine2
    mgemm_kernel<64,128,0,1,2,2><<<g2, 256, 0, stream>>>(t5H, Wm1, bm1, nodef, ndH, sscr, cs + 512, cs + 576, NND); // node_feature
    stats_reduce_kernel<128><<<16, 256, 0, stream>>>(sscr, SROWS, nullptr, nullptr, cs + 640, 0); // raw sums
    mgemm_kernel<128,128,2,0,0,0><<<g2, 256, 0, stream>>>(ndH, Wfc1, bfc1, nullptr, tBH, nullptr, nullptr, nullptr, NND); // a1 bf16

    // assignment + gumbel (bf16 a1)
    assign_kernel<<<(NND + 255) / 256, 256, 0, stream>>>(tBH, Wfc2, bfc2, assn, lam, kg0, kg1);

    // noisy features (into abuf) + kl partials
    noisy_kernel<<<NOISY_BLOCKS, 256, 0, stream>>>(nodef, lam, cs + 640, abuf, kpart, kn0, kn1);

    // graph pooling + head
    gstart_kernel<<<(NND + 255) / 256, 256, 0, stream>>>(batch, gstart);
    graph_emb_part_kernel<<<NG * EMB_SPLIT, 128, 0, stream>>>(abuf, gstart, gpart);
    graph_emb_reduce_kernel<<<NG, 128, 0, stream>>>(gpart, gstart, out + 512);
    head_kernel<<<NG, 64, 0, stream>>>(out + 512, protos, Wlast,
                                       out, out + 256, out + 16898, out + 18178);

    // penalties
    adj_kernel<<<ADJ_BLOCKS, 256, 0, stream>>>(assn, src, dst, adjp);
    final_scalar_kernel<<<1, 256, 0, stream>>>(kpart, adjp, out);
}